// Round 2
// baseline (475.537 us; speedup 1.0000x reference)
//
#include <hip/hip_runtime.h>
#include <hip/hip_fp16.h>
#include <math.h>

#define NEG_SLOPE 0.2f
#define GAT_EPS 1e-16f

__device__ __forceinline__ float elu_f(float x) { return x > 0.f ? x : expm1f(x); }
__device__ __forceinline__ float lrelu_f(float x) { return x > 0.f ? x : NEG_SLOPE * x; }

typedef _Float16 half2v __attribute__((ext_vector_type(2)));

// fp32 accumulate of half2 dot: acc += v.x*a.x + v.y*a.y
__device__ __forceinline__ float fdot2f(unsigned int v, unsigned int a, float acc) {
#if __has_builtin(__builtin_amdgcn_fdot2)
    return __builtin_amdgcn_fdot2(__builtin_bit_cast(half2v, v),
                                  __builtin_bit_cast(half2v, a), acc, false);
#else
    __half2 hv = __builtin_bit_cast(__half2, v);
    __half2 ha = __builtin_bit_cast(__half2, a);
    float2 fv = __half22float2(hv), fa = __half22float2(ha);
    return fmaf(fv.x, fa.x, fmaf(fv.y, fa.y, acc));
#endif
}

__device__ __forceinline__ unsigned int pack_half2(float a, float b) {
    __half2 h = __floats2half2_rn(a, b);
    return __builtin_bit_cast(unsigned int, h);
}

__device__ __forceinline__ float waveReduceSum(float v) {
    #pragma unroll
    for (int off = 32; off > 0; off >>= 1) v += __shfl_xor(v, off, 64);
    return v;
}

// ---------------- init: zero deg/sums/cnts; last block also folds attention vectors ----------------
__global__ void init_kernel(int* deg, float* sums, float* cnts, int N, int G,
        const float* __restrict__ W1, const float* __restrict__ as1, const float* __restrict__ ad1,
        const float* __restrict__ W2, const float* __restrict__ as2, const float* __restrict__ ad2,
        float* __restrict__ wa1, float* __restrict__ wd1,
        float* __restrict__ wa2, float* __restrict__ wd2) {
    int i = blockIdx.x * 256 + threadIdx.x;
    if (i < N) deg[i] = 0;
    if (i < G * 128) sums[i] = 0.f;
    if (i < G) cnts[i] = 0.f;
    if (blockIdx.x == gridDim.x - 1) {
        int t = threadIdx.x;
        if (t < 64) {                      // layer1: h=t>>5, c=t&31
            int h = t >> 5, c = t & 31;
            const float* w = W1 + (h * 32 + c) * 64;
            float sa = 0.f, sd = 0.f;
            for (int o = 0; o < 64; ++o) {
                sa = fmaf(w[o], as1[h * 64 + o], sa);
                sd = fmaf(w[o], ad1[h * 64 + o], sd);
            }
            wa1[t] = sa; wd1[t] = sd;
        } else if (t < 192) {              // layer2: u=t-64, h=u>>6, c=u&63
            int u = t - 64, h = u >> 6, c = u & 63;
            const float* w = W2 + (h * 64 + c) * 128;
            float sa = 0.f, sd = 0.f;
            for (int o = 0; o < 128; ++o) {
                sa = fmaf(w[o], as2[h * 128 + o], sa);
                sd = fmaf(w[o], ad2[h * 128 + o], sd);
            }
            wa2[u] = sa; wd2[u] = sd;
        }
    }
}

// ---------------- CSR build ----------------
__global__ __launch_bounds__(256) void hist_kernel(const int* __restrict__ dst,
                                                   int* __restrict__ deg, int E) {
    int e = blockIdx.x * 256 + threadIdx.x;
    if (e < E) atomicAdd(&deg[dst[e]], 1);
}

__global__ __launch_bounds__(256) void scan_blocks_kernel(const int* __restrict__ deg,
        int* __restrict__ ofs, int* __restrict__ bsum, int N) {
    __shared__ int wtot[4];
    int tid = threadIdx.x, lane = tid & 63, wid = tid >> 6;
    int i = blockIdx.x * 256 + tid;
    int v = (i < N) ? deg[i] : 0;
    int incl = v;
    #pragma unroll
    for (int off = 1; off < 64; off <<= 1) {
        int t = __shfl_up(incl, off, 64);
        if (lane >= off) incl += t;
    }
    if (lane == 63) wtot[wid] = incl;
    __syncthreads();
    int woff = 0;
    #pragma unroll
    for (int w = 0; w < 4; ++w) if (w < wid) woff += wtot[w];
    int excl = incl - v + woff;
    if (i < N) ofs[i] = excl;
    if (tid == 255) bsum[blockIdx.x] = woff + incl;
}

__global__ __launch_bounds__(1024) void scan_bsum_kernel(const int* __restrict__ bsum,
        int* __restrict__ bofs, int* __restrict__ ofsN, int nb) {
    __shared__ int wsum[16];
    int tid = threadIdx.x, lane = tid & 63, wid = tid >> 6;
    int v = (tid < nb) ? bsum[tid] : 0;
    int incl = v;
    #pragma unroll
    for (int off = 1; off < 64; off <<= 1) {
        int t = __shfl_up(incl, off, 64);
        if (lane >= off) incl += t;
    }
    if (lane == 63) wsum[wid] = incl;
    __syncthreads();
    if (wid == 0) {
        int wv = (lane < 16) ? wsum[lane] : 0;
        int winc = wv;
        #pragma unroll
        for (int off = 1; off < 16; off <<= 1) {
            int t = __shfl_up(winc, off, 64);
            if (lane >= off) winc += t;
        }
        if (lane < 16) wsum[lane] = winc - wv;
    }
    __syncthreads();
    int excl = incl - v + wsum[wid];
    if (tid < nb) bofs[tid] = excl;
    if (tid == nb - 1) *ofsN = excl + v;
}

__global__ __launch_bounds__(256) void scan_add_kernel(int* __restrict__ ofs,
        const int* __restrict__ bofs, int* __restrict__ cursor,
        const int* __restrict__ batch, float* __restrict__ cnts, int N) {
    int i = blockIdx.x * 256 + threadIdx.x;
    if (i < N) {
        int v = ofs[i] + bofs[blockIdx.x];
        ofs[i] = v;
        cursor[i] = v;
        // graph node-counts (batch is sorted -> waves are almost always uniform)
        int b = batch[i];
        int b0 = __shfl(b, 0, 64);
        if (__all(b == b0)) {
            unsigned long long m = __ballot(1);
            if ((threadIdx.x & 63) == 0) atomicAdd(&cnts[b], (float)__popcll(m));
        } else {
            atomicAdd(&cnts[b], 1.f);
        }
    }
}

__global__ __launch_bounds__(256) void scatter_kernel(
        const int* __restrict__ src, const int* __restrict__ dst,
        int* __restrict__ cursor, int* __restrict__ sperm, int E) {
    int e = blockIdx.x * 256 + threadIdx.x;
    if (e >= E) return;
    int d = dst[e];
    int pos = atomicAdd(&cursor[d], 1);
    sperm[pos] = src[e];
}

// ---------------- fused fc0 + GAT layer1 transform (8 nodes/block) ----------------
__global__ __launch_bounds__(256) void fused_t1(
        const float* __restrict__ x, const float* __restrict__ w0,
        const float* __restrict__ b0, const float* __restrict__ W1,
        const float* __restrict__ wa1, const float* __restrict__ wd1,
        __half* __restrict__ h1, float* __restrict__ es, float* __restrict__ ed, int N) {
    __shared__ float xs[8 * 16];
    __shared__ float hs[8 * 32];
    int n0 = blockIdx.x * 8;
    int tid = threadIdx.x;
    if (tid < 128) {
        int gi = n0 * 16 + tid;
        xs[tid] = (gi < N * 16) ? x[gi] : 0.f;
    }
    __syncthreads();
    {
        int j = tid >> 5, o = tid & 31;
        float acc = b0[o];
        #pragma unroll
        for (int c = 0; c < 16; ++c) acc = fmaf(xs[j * 16 + c], w0[c * 32 + o], acc);
        hs[j * 32 + o] = elu_f(acc);
    }
    __syncthreads();
    int o = tid & 63, h = (tid >> 6) & 1, nh = tid >> 7;
    float acc[4];
    #pragma unroll
    for (int j = 0; j < 4; ++j) acc[j] = 0.f;
    const float* wp = W1 + h * (32 * 64) + o;
    #pragma unroll
    for (int c = 0; c < 32; ++c) {
        float wv = wp[c * 64];
        #pragma unroll
        for (int j = 0; j < 4; ++j) acc[j] = fmaf(hs[(nh * 4 + j) * 32 + c], wv, acc[j]);
    }
    #pragma unroll
    for (int j = 0; j < 4; ++j) {
        int n = n0 + nh * 4 + j;
        if (n < N) h1[(size_t)n * 128 + 2 * o + h] = __float2half(acc[j]);
    }
    if (tid < 32) {
        int n = tid >> 2, r = tid & 3, hh = r >> 1, isd = r & 1;
        const float* wv = (isd ? wd1 : wa1) + hh * 32;
        float s = 0.f;
        #pragma unroll
        for (int c = 0; c < 32; ++c) s = fmaf(hs[n * 32 + c], wv[c], s);
        int nn = n0 + n;
        if (nn < N) { if (isd) ed[nn * 2 + hh] = s; else es[nn * 2 + hh] = s; }
    }
}

// ---------------- GAT layer2 transform (16 nodes/block: halves W2 refetch) ----------------
__global__ __launch_bounds__(256) void gat_transform2(
        const float* __restrict__ g1, const float* __restrict__ W,
        const float* __restrict__ wa2, const float* __restrict__ wd2,
        __half* __restrict__ h2, float* __restrict__ es, float* __restrict__ ed, int N) {
    __shared__ float xs[16 * 64];
    int n0 = blockIdx.x * 16;
    int tid = threadIdx.x;
    for (int idx = tid; idx < 16 * 64; idx += 256) {
        int gi = n0 * 64 + idx;
        xs[idx] = (gi < N * 64) ? g1[gi] : 0.f;
    }
    __syncthreads();
    int h = tid >> 7, o = tid & 127;
    float acc[16];
    #pragma unroll
    for (int j = 0; j < 16; ++j) acc[j] = 0.f;
    const float* wp = W + h * (64 * 128) + o;
    for (int c = 0; c < 64; ++c) {
        float wv = wp[c * 128];
        #pragma unroll
        for (int j = 0; j < 16; ++j) acc[j] = fmaf(xs[j * 64 + c], wv, acc[j]);
    }
    #pragma unroll
    for (int j = 0; j < 16; ++j) {
        int n = n0 + j;
        if (n < N) h2[(size_t)n * 256 + 2 * o + h] = __float2half(acc[j]);
    }
    if (tid < 64) {
        int n = tid >> 2, r = tid & 3, hh = r >> 1, isd = r & 1;
        const float* wv = (isd ? wd2 : wa2) + hh * 64;
        float s = 0.f;
        #pragma unroll
        for (int c = 0; c < 64; ++c) s = fmaf(xs[n * 64 + c], wv[c], s);
        int nn = n0 + n;
        if (nn < N) { if (isd) ed[nn * 2 + hh] = s; else es[nn * 2 + hh] = s; }
    }
}

// ---------------- aggregation layer1: one wave per dst node ----------------
// Gathers for the first 32 edges are issued BEFORE the softmax phase (addresses
// depend only on sperm); weights applied afterward via shfl broadcast. No LDS.
__global__ __launch_bounds__(256) void gat_agg1(
        const int* __restrict__ ofs, const int* __restrict__ sperm,
        const float* __restrict__ es, const float* __restrict__ ed,
        const unsigned int* __restrict__ h1, const float* __restrict__ b1,
        float* __restrict__ g1, int N) {
    int w = threadIdx.x >> 6;
    int d = blockIdx.x * 4 + w;
    if (d >= N) return;
    int lane = threadIdx.x & 63;
    float2 edv = *reinterpret_cast<const float2*>(ed + (size_t)d * 2);
    int beg = ofs[d], end = ofs[d + 1];
    int deg = end - beg;
    int jmax = deg < 64 ? deg : 64;

    int s_f = 0;
    int i0 = beg + lane;
    if (i0 < end) s_f = sperm[i0];

    // early-issue gathers (overlap with softmax latency)
    unsigned int vva[16], vvb[16];
    int ka = jmax < 16 ? jmax : 16;
    int kb = jmax <= 16 ? 0 : ((jmax - 16) < 16 ? (jmax - 16) : 16);
    #pragma unroll
    for (int k = 0; k < 16; ++k) if (k < ka)
        vva[k] = h1[(size_t)__shfl(s_f, k, 64) * 64 + lane];
    #pragma unroll
    for (int k = 0; k < 16; ++k) if (k < kb)
        vvb[k] = h1[(size_t)__shfl(s_f, 16 + k, 64) * 64 + lane];

    float ex0 = 0.f, ex1 = 0.f;
    if (i0 < end) {
        float2 esv = *reinterpret_cast<const float2*>(es + (size_t)s_f * 2);
        ex0 = __expf(lrelu_f(esv.x + edv.x));
        ex1 = __expf(lrelu_f(esv.y + edv.y));
    }
    float s0 = ex0, s1 = ex1;
    for (int i = i0 + 64; i < end; i += 64) {
        int s = sperm[i];
        float2 esv = *reinterpret_cast<const float2*>(es + (size_t)s * 2);
        s0 += __expf(lrelu_f(esv.x + edv.x));
        s1 += __expf(lrelu_f(esv.y + edv.y));
    }
    s0 = waveReduceSum(s0);
    s1 = waveReduceSum(s1);
    float r0 = 0.5f / (s0 + GAT_EPS), r1 = 0.5f / (s1 + GAT_EPS);

    float acc = 0.f;
    #pragma unroll
    for (int k = 0; k < 16; ++k) if (k < ka) {
        unsigned int wg = pack_half2(__shfl(ex0, k, 64) * r0, __shfl(ex1, k, 64) * r1);
        acc = fdot2f(vva[k], wg, acc);
    }
    #pragma unroll
    for (int k = 0; k < 16; ++k) if (k < kb) {
        unsigned int wg = pack_half2(__shfl(ex0, 16 + k, 64) * r0, __shfl(ex1, 16 + k, 64) * r1);
        acc = fdot2f(vvb[k], wg, acc);
    }
    for (int j0 = 32; j0 < jmax; j0 += 16) {
        int kc = (jmax - j0) < 16 ? (jmax - j0) : 16;
        #pragma unroll
        for (int k = 0; k < 16; ++k) if (k < kc)
            vva[k] = h1[(size_t)__shfl(s_f, j0 + k, 64) * 64 + lane];
        #pragma unroll
        for (int k = 0; k < 16; ++k) if (k < kc) {
            unsigned int wg = pack_half2(__shfl(ex0, j0 + k, 64) * r0, __shfl(ex1, j0 + k, 64) * r1);
            acc = fdot2f(vva[k], wg, acc);
        }
    }
    for (int i = beg + 64; i < end; ++i) {  // rare: deg > 64
        int s = sperm[i];
        float2 esv = *reinterpret_cast<const float2*>(es + (size_t)s * 2);
        float a0 = __expf(lrelu_f(esv.x + edv.x)) * r0;
        float a1 = __expf(lrelu_f(esv.y + edv.y)) * r1;
        acc = fdot2f(h1[(size_t)s * 64 + lane], pack_half2(a0, a1), acc);
    }
    g1[(size_t)d * 64 + lane] = elu_f(acc + b1[lane]);   // pre-activate for transform2
}

// ---------------- aggregation layer2: one wave per dst node ----------------
__global__ __launch_bounds__(256) void gat_agg2(
        const int* __restrict__ ofs, const int* __restrict__ sperm,
        const float* __restrict__ es, const float* __restrict__ ed,
        const uint2* __restrict__ h2, const float* __restrict__ b2,
        float* __restrict__ g2, int N) {
    int w = threadIdx.x >> 6;
    int d = blockIdx.x * 4 + w;
    if (d >= N) return;
    int lane = threadIdx.x & 63;
    float2 edv = *reinterpret_cast<const float2*>(ed + (size_t)d * 2);
    int beg = ofs[d], end = ofs[d + 1];
    int deg = end - beg;
    int jmax = deg < 64 ? deg : 64;

    int s_f = 0;
    int i0 = beg + lane;
    if (i0 < end) s_f = sperm[i0];

    // early-issue gathers (overlap with softmax latency)
    uint2 vva[16], vvb[16];
    int ka = jmax < 16 ? jmax : 16;
    int kb = jmax <= 16 ? 0 : ((jmax - 16) < 16 ? (jmax - 16) : 16);
    #pragma unroll
    for (int k = 0; k < 16; ++k) if (k < ka)
        vva[k] = h2[(size_t)__shfl(s_f, k, 64) * 64 + lane];
    #pragma unroll
    for (int k = 0; k < 16; ++k) if (k < kb)
        vvb[k] = h2[(size_t)__shfl(s_f, 16 + k, 64) * 64 + lane];

    float ex0 = 0.f, ex1 = 0.f;
    if (i0 < end) {
        float2 esv = *reinterpret_cast<const float2*>(es + (size_t)s_f * 2);
        ex0 = __expf(lrelu_f(esv.x + edv.x));
        ex1 = __expf(lrelu_f(esv.y + edv.y));
    }
    float s0 = ex0, s1 = ex1;
    for (int i = i0 + 64; i < end; i += 64) {
        int s = sperm[i];
        float2 esv = *reinterpret_cast<const float2*>(es + (size_t)s * 2);
        s0 += __expf(lrelu_f(esv.x + edv.x));
        s1 += __expf(lrelu_f(esv.y + edv.y));
    }
    s0 = waveReduceSum(s0);
    s1 = waveReduceSum(s1);
    float r0 = 0.5f / (s0 + GAT_EPS), r1 = 0.5f / (s1 + GAT_EPS);

    float acc0 = 0.f, acc1 = 0.f;   // channels 2*lane, 2*lane+1
    #pragma unroll
    for (int k = 0; k < 16; ++k) if (k < ka) {
        unsigned int wg = pack_half2(__shfl(ex0, k, 64) * r0, __shfl(ex1, k, 64) * r1);
        acc0 = fdot2f(vva[k].x, wg, acc0);
        acc1 = fdot2f(vva[k].y, wg, acc1);
    }
    #pragma unroll
    for (int k = 0; k < 16; ++k) if (k < kb) {
        unsigned int wg = pack_half2(__shfl(ex0, 16 + k, 64) * r0, __shfl(ex1, 16 + k, 64) * r1);
        acc0 = fdot2f(vvb[k].x, wg, acc0);
        acc1 = fdot2f(vvb[k].y, wg, acc1);
    }
    for (int j0 = 32; j0 < jmax; j0 += 16) {
        int kc = (jmax - j0) < 16 ? (jmax - j0) : 16;
        #pragma unroll
        for (int k = 0; k < 16; ++k) if (k < kc)
            vva[k] = h2[(size_t)__shfl(s_f, j0 + k, 64) * 64 + lane];
        #pragma unroll
        for (int k = 0; k < 16; ++k) if (k < kc) {
            unsigned int wg = pack_half2(__shfl(ex0, j0 + k, 64) * r0, __shfl(ex1, j0 + k, 64) * r1);
            acc0 = fdot2f(vva[k].x, wg, acc0);
            acc1 = fdot2f(vva[k].y, wg, acc1);
        }
    }
    for (int i = beg + 64; i < end; ++i) {  // rare: deg > 64
        int s = sperm[i];
        float2 esv = *reinterpret_cast<const float2*>(es + (size_t)s * 2);
        float a0 = __expf(lrelu_f(esv.x + edv.x)) * r0;
        float a1 = __expf(lrelu_f(esv.y + edv.y)) * r1;
        unsigned int ap = pack_half2(a0, a1);
        uint2 v = h2[(size_t)s * 64 + lane];
        acc0 = fdot2f(v.x, ap, acc0);
        acc1 = fdot2f(v.y, ap, acc1);
    }
    float2 bv = reinterpret_cast<const float2*>(b2)[lane];
    g2[(size_t)d * 128 + 2 * lane]     = elu_f(acc0 + bv.x);   // pre-activated for pool
    g2[(size_t)d * 128 + 2 * lane + 1] = elu_f(acc1 + bv.y);
}

// ---------------- pool: sorted-batch run accumulation (g2 pre-activated; cnts from scan_add) ----------------
#define POOL_NPB 128
__global__ __launch_bounds__(256) void pool_kernel(
        const float* __restrict__ g2, const int* __restrict__ batch,
        float* __restrict__ sums, int N) {
    int n0 = blockIdx.x * POOL_NPB;
    int c = threadIdx.x & 127;
    int p = threadIdx.x >> 7;
    int nend = n0 + POOL_NPB; if (nend > N) nend = N;
    int n = n0 + p;
    if (n >= nend) return;
    int cur_b = batch[n];
    float acc = 0.f;
    for (; n < nend; n += 2) {
        int b = batch[n];
        if (b != cur_b) {
            atomicAdd(&sums[(size_t)cur_b * 128 + c], acc);
            acc = 0.f; cur_b = b;
        }
        acc += g2[(size_t)n * 128 + c];
    }
    atomicAdd(&sums[(size_t)cur_b * 128 + c], acc);
}

// ---------------- final: out = (sums/cnt) @ lo_w + lo_b ----------------
__global__ void final_kernel(
        const float* __restrict__ sums, const float* __restrict__ cnts,
        const float* __restrict__ w, const float* __restrict__ b,
        float* __restrict__ out, int G) {
    int g = blockIdx.x;
    int k = threadIdx.x;
    if (k >= 24) return;
    float inv = 1.f / fmaxf(cnts[g], 1.f);
    float acc = b[k];
    #pragma unroll
    for (int c = 0; c < 128; ++c) acc = fmaf(sums[g * 128 + c] * inv, w[c * 24 + k], acc);
    out[g * 24 + k] = acc;
}

extern "C" void kernel_launch(void* const* d_in, const int* in_sizes, int n_in,
                              void* d_out, int out_size, void* d_ws, size_t ws_size,
                              hipStream_t stream) {
    const float* x      = (const float*)d_in[0];
    const int*   ei     = (const int*)d_in[1];
    const int*   batch  = (const int*)d_in[2];
    const float* fc0_w  = (const float*)d_in[3];
    const float* fc0_b  = (const float*)d_in[4];
    const float* W1     = (const float*)d_in[5];
    const float* a_src1 = (const float*)d_in[6];
    const float* a_dst1 = (const float*)d_in[7];
    const float* b1     = (const float*)d_in[8];
    const float* W2     = (const float*)d_in[9];
    const float* a_src2 = (const float*)d_in[10];
    const float* a_dst2 = (const float*)d_in[11];
    const float* b2     = (const float*)d_in[12];
    const float* lo_w   = (const float*)d_in[13];
    const float* lo_b   = (const float*)d_in[14];
    float* out = (float*)d_out;

    const int N = in_sizes[0] / 16;
    const int E = in_sizes[1] / 2;
    const int G = out_size / 24;
    const int* src = ei;
    const int* dst = ei + E;
    const int nb = (N + 255) / 256;

    char* wsb = (char*)d_ws;
    size_t off = 0;
    auto allocf = [&](size_t n) { float* p = (float*)(wsb + off); off += ((n * 4 + 255) & ~(size_t)255); return p; };
    auto alloci = [&](size_t n) { int* p = (int*)(wsb + off); off += ((n * 4 + 255) & ~(size_t)255); return p; };
    auto alloch = [&](size_t n) { __half* p = (__half*)(wsb + off); off += ((n * 2 + 255) & ~(size_t)255); return p; };
    __half* hbuf  = alloch((size_t)N * 256);   // h1 uses N*128 halves; h2 uses N*256 halves
    float*  g1    = allocf((size_t)N * 64);
    float*  g2    = allocf((size_t)N * 128);
    float*  es    = allocf((size_t)N * 2);
    float*  ed    = allocf((size_t)N * 2);
    float*  sums  = allocf((size_t)G * 128);
    float*  cnts  = allocf((size_t)G);
    float*  wa1   = allocf(64);
    float*  wd1   = allocf(64);
    float*  wa2   = allocf(128);
    float*  wd2   = allocf(128);
    int* deg     = alloci((size_t)N);
    int* ofs     = alloci((size_t)N + 1);
    int* cursor  = alloci((size_t)N);
    int* sperm   = alloci((size_t)E);
    int* bsum    = alloci((size_t)nb);
    int* bofs    = alloci((size_t)nb);
    (void)ws_size;

    // init (+ folded attention vectors in last block) + CSR build
    init_kernel<<<(N + 255) / 256, 256, 0, stream>>>(deg, sums, cnts, N, G,
            W1, a_src1, a_dst1, W2, a_src2, a_dst2, wa1, wd1, wa2, wd2);
    hist_kernel<<<(E + 255) / 256, 256, 0, stream>>>(dst, deg, E);
    scan_blocks_kernel<<<nb, 256, 0, stream>>>(deg, ofs, bsum, N);
    scan_bsum_kernel<<<1, 1024, 0, stream>>>(bsum, bofs, ofs + N, nb);
    scan_add_kernel<<<nb, 256, 0, stream>>>(ofs, bofs, cursor, batch, cnts, N);
    scatter_kernel<<<(E + 255) / 256, 256, 0, stream>>>(src, dst, cursor, sperm, E);

    // ---- GAT layer 1 (fc0 fused into transform) ----
    fused_t1<<<(N + 7) / 8, 256, 0, stream>>>(x, fc0_w, fc0_b, W1, wa1, wd1, hbuf, es, ed, N);
    gat_agg1<<<(N + 3) / 4, 256, 0, stream>>>(ofs, sperm, es, ed, (const unsigned int*)hbuf, b1, g1, N);

    // ---- GAT layer 2 ----
    gat_transform2<<<(N + 15) / 16, 256, 0, stream>>>(g1, W2, wa2, wd2, hbuf, es, ed, N);
    gat_agg2<<<(N + 3) / 4, 256, 0, stream>>>(ofs, sperm, es, ed, (const uint2*)hbuf, b2, g2, N);

    // ---- pool + final linear ----
    pool_kernel<<<(N + POOL_NPB - 1) / POOL_NPB, 256, 0, stream>>>(g2, batch, sums, N);
    final_kernel<<<G, 32, 0, stream>>>(sums, cnts, lo_w, lo_b, out, G);
}

// Round 3
// 386.309 us; speedup vs baseline: 1.2310x; 1.2310x over previous
//
#include <hip/hip_runtime.h>
#include <hip/hip_fp16.h>
#include <math.h>

#define NEG_SLOPE 0.2f
#define GAT_EPS 1e-16f

__device__ __forceinline__ float elu_f(float x) { return x > 0.f ? x : expm1f(x); }
__device__ __forceinline__ float lrelu_f(float x) { return x > 0.f ? x : NEG_SLOPE * x; }

typedef _Float16 half2v __attribute__((ext_vector_type(2)));

// fp32 accumulate of half2 dot: acc += v.x*a.x + v.y*a.y
__device__ __forceinline__ float fdot2f(unsigned int v, unsigned int a, float acc) {
#if __has_builtin(__builtin_amdgcn_fdot2)
    return __builtin_amdgcn_fdot2(__builtin_bit_cast(half2v, v),
                                  __builtin_bit_cast(half2v, a), acc, false);
#else
    __half2 hv = __builtin_bit_cast(__half2, v);
    __half2 ha = __builtin_bit_cast(__half2, a);
    float2 fv = __half22float2(hv), fa = __half22float2(ha);
    return fmaf(fv.x, fa.x, fmaf(fv.y, fa.y, acc));
#endif
}

__device__ __forceinline__ unsigned int pack_half2(float a, float b) {
    __half2 h = __floats2half2_rn(a, b);
    return __builtin_bit_cast(unsigned int, h);
}

// reduction within a 32-lane half-wave (xor offsets stay inside the half)
__device__ __forceinline__ float halfReduceSum(float v) {
    #pragma unroll
    for (int off = 16; off > 0; off >>= 1) v += __shfl_xor(v, off, 64);
    return v;
}

// ---------------- init: zero deg/sums/cnts; last block also folds attention vectors ----------------
__global__ void init_kernel(int* deg, float* sums, float* cnts, int N, int G,
        const float* __restrict__ W1, const float* __restrict__ as1, const float* __restrict__ ad1,
        const float* __restrict__ W2, const float* __restrict__ as2, const float* __restrict__ ad2,
        float* __restrict__ wa1, float* __restrict__ wd1,
        float* __restrict__ wa2, float* __restrict__ wd2) {
    int i = blockIdx.x * 256 + threadIdx.x;
    if (i < N) deg[i] = 0;
    if (i < G * 128) sums[i] = 0.f;
    if (i < G) cnts[i] = 0.f;
    if (blockIdx.x == gridDim.x - 1) {
        int t = threadIdx.x;
        if (t < 64) {                      // layer1: h=t>>5, c=t&31
            int h = t >> 5, c = t & 31;
            const float* w = W1 + (h * 32 + c) * 64;
            float sa = 0.f, sd = 0.f;
            for (int o = 0; o < 64; ++o) {
                sa = fmaf(w[o], as1[h * 64 + o], sa);
                sd = fmaf(w[o], ad1[h * 64 + o], sd);
            }
            wa1[t] = sa; wd1[t] = sd;
        } else if (t < 192) {              // layer2: u=t-64, h=u>>6, c=u&63
            int u = t - 64, h = u >> 6, c = u & 63;
            const float* w = W2 + (h * 64 + c) * 128;
            float sa = 0.f, sd = 0.f;
            for (int o = 0; o < 128; ++o) {
                sa = fmaf(w[o], as2[h * 128 + o], sa);
                sd = fmaf(w[o], ad2[h * 128 + o], sd);
            }
            wa2[u] = sa; wd2[u] = sd;
        }
    }
}

// ---------------- CSR build ----------------
__global__ __launch_bounds__(256) void hist_kernel(const int* __restrict__ dst,
                                                   int* __restrict__ deg, int E) {
    int e = blockIdx.x * 256 + threadIdx.x;
    if (e < E) atomicAdd(&deg[dst[e]], 1);
}

__global__ __launch_bounds__(256) void scan_blocks_kernel(const int* __restrict__ deg,
        int* __restrict__ ofs, int* __restrict__ bsum, int N) {
    __shared__ int wtot[4];
    int tid = threadIdx.x, lane = tid & 63, wid = tid >> 6;
    int i = blockIdx.x * 256 + tid;
    int v = (i < N) ? deg[i] : 0;
    int incl = v;
    #pragma unroll
    for (int off = 1; off < 64; off <<= 1) {
        int t = __shfl_up(incl, off, 64);
        if (lane >= off) incl += t;
    }
    if (lane == 63) wtot[wid] = incl;
    __syncthreads();
    int woff = 0;
    #pragma unroll
    for (int w = 0; w < 4; ++w) if (w < wid) woff += wtot[w];
    int excl = incl - v + woff;
    if (i < N) ofs[i] = excl;
    if (tid == 255) bsum[blockIdx.x] = woff + incl;
}

__global__ __launch_bounds__(1024) void scan_bsum_kernel(const int* __restrict__ bsum,
        int* __restrict__ bofs, int* __restrict__ ofsN, int nb) {
    __shared__ int wsum[16];
    int tid = threadIdx.x, lane = tid & 63, wid = tid >> 6;
    int v = (tid < nb) ? bsum[tid] : 0;
    int incl = v;
    #pragma unroll
    for (int off = 1; off < 64; off <<= 1) {
        int t = __shfl_up(incl, off, 64);
        if (lane >= off) incl += t;
    }
    if (lane == 63) wsum[wid] = incl;
    __syncthreads();
    if (wid == 0) {
        int wv = (lane < 16) ? wsum[lane] : 0;
        int winc = wv;
        #pragma unroll
        for (int off = 1; off < 16; off <<= 1) {
            int t = __shfl_up(winc, off, 64);
            if (lane >= off) winc += t;
        }
        if (lane < 16) wsum[lane] = winc - wv;
    }
    __syncthreads();
    int excl = incl - v + wsum[wid];
    if (tid < nb) bofs[tid] = excl;
    if (tid == nb - 1) *ofsN = excl + v;
}

__global__ __launch_bounds__(256) void scan_add_kernel(int* __restrict__ ofs,
        const int* __restrict__ bofs, int* __restrict__ cursor,
        const int* __restrict__ batch, float* __restrict__ cnts, int N) {
    int i = blockIdx.x * 256 + threadIdx.x;
    if (i < N) {
        int v = ofs[i] + bofs[blockIdx.x];
        ofs[i] = v;
        cursor[i] = v;
        // graph node-counts (batch is sorted -> waves are almost always uniform)
        int b = batch[i];
        int b0 = __shfl(b, 0, 64);
        if (__all(b == b0)) {
            unsigned long long m = __ballot(1);
            if ((threadIdx.x & 63) == 0) atomicAdd(&cnts[b], (float)__popcll(m));
        } else {
            atomicAdd(&cnts[b], 1.f);
        }
    }
}

__global__ __launch_bounds__(256) void scatter_kernel(
        const int* __restrict__ src, const int* __restrict__ dst,
        int* __restrict__ cursor, int* __restrict__ sperm, int E) {
    int e = blockIdx.x * 256 + threadIdx.x;
    if (e >= E) return;
    int d = dst[e];
    int pos = atomicAdd(&cursor[d], 1);
    sperm[pos] = src[e];
}

// ---------------- fused fc0 + GAT layer1 transform (8 nodes/block) ----------------
__global__ __launch_bounds__(256) void fused_t1(
        const float* __restrict__ x, const float* __restrict__ w0,
        const float* __restrict__ b0, const float* __restrict__ W1,
        const float* __restrict__ wa1, const float* __restrict__ wd1,
        __half* __restrict__ h1, float* __restrict__ es, float* __restrict__ ed, int N) {
    __shared__ float xs[8 * 16];
    __shared__ float hs[8 * 32];
    int n0 = blockIdx.x * 8;
    int tid = threadIdx.x;
    if (tid < 128) {
        int gi = n0 * 16 + tid;
        xs[tid] = (gi < N * 16) ? x[gi] : 0.f;
    }
    __syncthreads();
    {
        int j = tid >> 5, o = tid & 31;
        float acc = b0[o];
        #pragma unroll
        for (int c = 0; c < 16; ++c) acc = fmaf(xs[j * 16 + c], w0[c * 32 + o], acc);
        hs[j * 32 + o] = elu_f(acc);
    }
    __syncthreads();
    int o = tid & 63, h = (tid >> 6) & 1, nh = tid >> 7;
    float acc[4];
    #pragma unroll
    for (int j = 0; j < 4; ++j) acc[j] = 0.f;
    const float* wp = W1 + h * (32 * 64) + o;
    #pragma unroll
    for (int c = 0; c < 32; ++c) {
        float wv = wp[c * 64];
        #pragma unroll
        for (int j = 0; j < 4; ++j) acc[j] = fmaf(hs[(nh * 4 + j) * 32 + c], wv, acc[j]);
    }
    #pragma unroll
    for (int j = 0; j < 4; ++j) {
        int n = n0 + nh * 4 + j;
        if (n < N) h1[(size_t)n * 128 + 2 * o + h] = __float2half(acc[j]);
    }
    if (tid < 32) {
        int n = tid >> 2, r = tid & 3, hh = r >> 1, isd = r & 1;
        const float* wv = (isd ? wd1 : wa1) + hh * 32;
        float s = 0.f;
        #pragma unroll
        for (int c = 0; c < 32; ++c) s = fmaf(hs[n * 32 + c], wv[c], s);
        int nn = n0 + n;
        if (nn < N) { if (isd) ed[nn * 2 + hh] = s; else es[nn * 2 + hh] = s; }
    }
}

// ---------------- GAT layer2 transform (8 nodes/block) ----------------
__global__ __launch_bounds__(256) void gat_transform2(
        const float* __restrict__ g1, const float* __restrict__ W,
        const float* __restrict__ wa2, const float* __restrict__ wd2,
        __half* __restrict__ h2, float* __restrict__ es, float* __restrict__ ed, int N) {
    __shared__ float xs[8 * 64];
    int n0 = blockIdx.x * 8;
    int tid = threadIdx.x;
    for (int idx = tid; idx < 8 * 64; idx += 256) {
        int gi = n0 * 64 + idx;
        xs[idx] = (gi < N * 64) ? g1[gi] : 0.f;
    }
    __syncthreads();
    int h = tid >> 7, o = tid & 127;
    float acc[8];
    #pragma unroll
    for (int j = 0; j < 8; ++j) acc[j] = 0.f;
    const float* wp = W + h * (64 * 128) + o;
    for (int c = 0; c < 64; ++c) {
        float wv = wp[c * 128];
        #pragma unroll
        for (int j = 0; j < 8; ++j) acc[j] = fmaf(xs[j * 64 + c], wv, acc[j]);
    }
    #pragma unroll
    for (int j = 0; j < 8; ++j) {
        int n = n0 + j;
        if (n < N) h2[(size_t)n * 256 + 2 * o + h] = __float2half(acc[j]);
    }
    if (tid < 32) {
        int n = tid >> 2, r = tid & 3, hh = r >> 1, isd = r & 1;
        const float* wv = (isd ? wd2 : wa2) + hh * 64;
        float s = 0.f;
        #pragma unroll
        for (int c = 0; c < 64; ++c) s = fmaf(xs[n * 64 + c], wv[c], s);
        int nn = n0 + n;
        if (nn < N) { if (isd) ed[nn * 2 + hh] = s; else es[nn * 2 + hh] = s; }
    }
}

// ---------------- aggregation layer1: one HALF-WAVE (32 lanes) per dst node ----------------
// Each lane loads uint2 (8B) per source row; 8-deep batching => 16 rows in
// flight per full wave (2x the 64-lane/node layout). Same total bytes.
__global__ __launch_bounds__(256) void gat_agg1(
        const int* __restrict__ ofs, const int* __restrict__ sperm,
        const float* __restrict__ es, const float* __restrict__ ed,
        const uint2* __restrict__ h1v, const float* __restrict__ b1,
        float* __restrict__ g1, int N) {
    __shared__ uint2 meta[8][32];
    int half = threadIdx.x >> 5;          // 0..7
    int d = blockIdx.x * 8 + half;
    if (d >= N) return;
    int lane = threadIdx.x & 31;
    float2 edv = *reinterpret_cast<const float2*>(ed + (size_t)d * 2);
    int beg = ofs[d], end = ofs[d + 1];
    int deg = end - beg;
    int jmax = deg < 32 ? deg : 32;

    int s_f = 0;
    float ex0 = 0.f, ex1 = 0.f;
    int i0 = beg + lane;
    if (i0 < end) {
        s_f = sperm[i0];
        float2 esv = *reinterpret_cast<const float2*>(es + (size_t)s_f * 2);
        ex0 = __expf(lrelu_f(esv.x + edv.x));
        ex1 = __expf(lrelu_f(esv.y + edv.y));
    }
    float s0 = ex0, s1 = ex1;
    for (int i = i0 + 32; i < end; i += 32) {  // rare: deg > 32
        int s = sperm[i];
        float2 esv = *reinterpret_cast<const float2*>(es + (size_t)s * 2);
        s0 += __expf(lrelu_f(esv.x + edv.x));
        s1 += __expf(lrelu_f(esv.y + edv.y));
    }
    s0 = halfReduceSum(s0);
    s1 = halfReduceSum(s1);
    float r0 = 0.5f / (s0 + GAT_EPS), r1 = 0.5f / (s1 + GAT_EPS);
    if (lane < jmax)
        meta[half][lane] = make_uint2((unsigned int)s_f, pack_half2(ex0 * r0, ex1 * r1));
    // half-wave-internal LDS write->read; compiler inserts lgkmcnt wait, no barrier needed

    // lane covers channels 2*lane, 2*lane+1 (both heads interleaved in h1)
    float acc0 = 0.f, acc1 = 0.f;
    int j = 0;
    for (; j + 8 <= jmax; j += 8) {
        uint2 mm[8]; uint2 vv[8];
        #pragma unroll
        for (int k = 0; k < 8; ++k) mm[k] = meta[half][j + k];
        #pragma unroll
        for (int k = 0; k < 8; ++k) vv[k] = h1v[(size_t)mm[k].x * 32 + lane];
        #pragma unroll
        for (int k = 0; k < 8; ++k) {
            acc0 = fdot2f(vv[k].x, mm[k].y, acc0);
            acc1 = fdot2f(vv[k].y, mm[k].y, acc1);
        }
    }
    for (; j + 4 <= jmax; j += 4) {
        uint2 mm[4]; uint2 vv[4];
        #pragma unroll
        for (int k = 0; k < 4; ++k) mm[k] = meta[half][j + k];
        #pragma unroll
        for (int k = 0; k < 4; ++k) vv[k] = h1v[(size_t)mm[k].x * 32 + lane];
        #pragma unroll
        for (int k = 0; k < 4; ++k) {
            acc0 = fdot2f(vv[k].x, mm[k].y, acc0);
            acc1 = fdot2f(vv[k].y, mm[k].y, acc1);
        }
    }
    for (; j < jmax; ++j) {
        uint2 m = meta[half][j];
        uint2 v = h1v[(size_t)m.x * 32 + lane];
        acc0 = fdot2f(v.x, m.y, acc0);
        acc1 = fdot2f(v.y, m.y, acc1);
    }
    for (int i = beg + 32; i < end; ++i) {  // rare: deg > 32
        int s = sperm[i];
        float2 esv = *reinterpret_cast<const float2*>(es + (size_t)s * 2);
        float a0 = __expf(lrelu_f(esv.x + edv.x)) * r0;
        float a1 = __expf(lrelu_f(esv.y + edv.y)) * r1;
        unsigned int ap = pack_half2(a0, a1);
        uint2 v = h1v[(size_t)s * 32 + lane];
        acc0 = fdot2f(v.x, ap, acc0);
        acc1 = fdot2f(v.y, ap, acc1);
    }
    float2 bv = reinterpret_cast<const float2*>(b1)[lane];
    float2 o2 = make_float2(elu_f(acc0 + bv.x), elu_f(acc1 + bv.y));
    *reinterpret_cast<float2*>(g1 + (size_t)d * 64 + 2 * lane) = o2;  // pre-activated
}

// ---------------- aggregation layer2: one HALF-WAVE per dst node, uint4 (16B) loads ----------------
__global__ __launch_bounds__(256) void gat_agg2(
        const int* __restrict__ ofs, const int* __restrict__ sperm,
        const float* __restrict__ es, const float* __restrict__ ed,
        const uint4* __restrict__ h2v, const float* __restrict__ b2,
        float* __restrict__ g2, int N) {
    __shared__ uint2 meta[8][32];
    int half = threadIdx.x >> 5;
    int d = blockIdx.x * 8 + half;
    if (d >= N) return;
    int lane = threadIdx.x & 31;
    float2 edv = *reinterpret_cast<const float2*>(ed + (size_t)d * 2);
    int beg = ofs[d], end = ofs[d + 1];
    int deg = end - beg;
    int jmax = deg < 32 ? deg : 32;

    int s_f = 0;
    float ex0 = 0.f, ex1 = 0.f;
    int i0 = beg + lane;
    if (i0 < end) {
        s_f = sperm[i0];
        float2 esv = *reinterpret_cast<const float2*>(es + (size_t)s_f * 2);
        ex0 = __expf(lrelu_f(esv.x + edv.x));
        ex1 = __expf(lrelu_f(esv.y + edv.y));
    }
    float s0 = ex0, s1 = ex1;
    for (int i = i0 + 32; i < end; i += 32) {  // rare: deg > 32
        int s = sperm[i];
        float2 esv = *reinterpret_cast<const float2*>(es + (size_t)s * 2);
        s0 += __expf(lrelu_f(esv.x + edv.x));
        s1 += __expf(lrelu_f(esv.y + edv.y));
    }
    s0 = halfReduceSum(s0);
    s1 = halfReduceSum(s1);
    float r0 = 0.5f / (s0 + GAT_EPS), r1 = 0.5f / (s1 + GAT_EPS);
    if (lane < jmax)
        meta[half][lane] = make_uint2((unsigned int)s_f, pack_half2(ex0 * r0, ex1 * r1));

    // lane covers channels 4*lane .. 4*lane+3 (heads interleaved in h2)
    float acc0 = 0.f, acc1 = 0.f, acc2 = 0.f, acc3 = 0.f;
    int j = 0;
    for (; j + 8 <= jmax; j += 8) {
        uint2 mm[8]; uint4 vv[8];
        #pragma unroll
        for (int k = 0; k < 8; ++k) mm[k] = meta[half][j + k];
        #pragma unroll
        for (int k = 0; k < 8; ++k) vv[k] = h2v[(size_t)mm[k].x * 32 + lane];
        #pragma unroll
        for (int k = 0; k < 8; ++k) {
            acc0 = fdot2f(vv[k].x, mm[k].y, acc0);
            acc1 = fdot2f(vv[k].y, mm[k].y, acc1);
            acc2 = fdot2f(vv[k].z, mm[k].y, acc2);
            acc3 = fdot2f(vv[k].w, mm[k].y, acc3);
        }
    }
    for (; j + 4 <= jmax; j += 4) {
        uint2 mm[4]; uint4 vv[4];
        #pragma unroll
        for (int k = 0; k < 4; ++k) mm[k] = meta[half][j + k];
        #pragma unroll
        for (int k = 0; k < 4; ++k) vv[k] = h2v[(size_t)mm[k].x * 32 + lane];
        #pragma unroll
        for (int k = 0; k < 4; ++k) {
            acc0 = fdot2f(vv[k].x, mm[k].y, acc0);
            acc1 = fdot2f(vv[k].y, mm[k].y, acc1);
            acc2 = fdot2f(vv[k].z, mm[k].y, acc2);
            acc3 = fdot2f(vv[k].w, mm[k].y, acc3);
        }
    }
    for (; j < jmax; ++j) {
        uint2 m = meta[half][j];
        uint4 v = h2v[(size_t)m.x * 32 + lane];
        acc0 = fdot2f(v.x, m.y, acc0);
        acc1 = fdot2f(v.y, m.y, acc1);
        acc2 = fdot2f(v.z, m.y, acc2);
        acc3 = fdot2f(v.w, m.y, acc3);
    }
    for (int i = beg + 32; i < end; ++i) {  // rare: deg > 32
        int s = sperm[i];
        float2 esv = *reinterpret_cast<const float2*>(es + (size_t)s * 2);
        float a0 = __expf(lrelu_f(esv.x + edv.x)) * r0;
        float a1 = __expf(lrelu_f(esv.y + edv.y)) * r1;
        unsigned int ap = pack_half2(a0, a1);
        uint4 v = h2v[(size_t)s * 32 + lane];
        acc0 = fdot2f(v.x, ap, acc0);
        acc1 = fdot2f(v.y, ap, acc1);
        acc2 = fdot2f(v.z, ap, acc2);
        acc3 = fdot2f(v.w, ap, acc3);
    }
    float4 bv = reinterpret_cast<const float4*>(b2)[lane];
    float4 o4;
    o4.x = elu_f(acc0 + bv.x);
    o4.y = elu_f(acc1 + bv.y);
    o4.z = elu_f(acc2 + bv.z);
    o4.w = elu_f(acc3 + bv.w);
    *reinterpret_cast<float4*>(g2 + (size_t)d * 128 + 4 * lane) = o4;  // pre-activated
}

// ---------------- pool: sorted-batch run accumulation (g2 pre-activated; cnts from scan_add) ----------------
#define POOL_NPB 128
__global__ __launch_bounds__(256) void pool_kernel(
        const float* __restrict__ g2, const int* __restrict__ batch,
        float* __restrict__ sums, int N) {
    int n0 = blockIdx.x * POOL_NPB;
    int c = threadIdx.x & 127;
    int p = threadIdx.x >> 7;
    int nend = n0 + POOL_NPB; if (nend > N) nend = N;
    int n = n0 + p;
    if (n >= nend) return;
    int cur_b = batch[n];
    float acc = 0.f;
    for (; n < nend; n += 2) {
        int b = batch[n];
        if (b != cur_b) {
            atomicAdd(&sums[(size_t)cur_b * 128 + c], acc);
            acc = 0.f; cur_b = b;
        }
        acc += g2[(size_t)n * 128 + c];
    }
    atomicAdd(&sums[(size_t)cur_b * 128 + c], acc);
}

// ---------------- final: out = (sums/cnt) @ lo_w + lo_b ----------------
__global__ void final_kernel(
        const float* __restrict__ sums, const float* __restrict__ cnts,
        const float* __restrict__ w, const float* __restrict__ b,
        float* __restrict__ out, int G) {
    int g = blockIdx.x;
    int k = threadIdx.x;
    if (k >= 24) return;
    float inv = 1.f / fmaxf(cnts[g], 1.f);
    float acc = b[k];
    #pragma unroll
    for (int c = 0; c < 128; ++c) acc = fmaf(sums[g * 128 + c] * inv, w[c * 24 + k], acc);
    out[g * 24 + k] = acc;
}

extern "C" void kernel_launch(void* const* d_in, const int* in_sizes, int n_in,
                              void* d_out, int out_size, void* d_ws, size_t ws_size,
                              hipStream_t stream) {
    const float* x      = (const float*)d_in[0];
    const int*   ei     = (const int*)d_in[1];
    const int*   batch  = (const int*)d_in[2];
    const float* fc0_w  = (const float*)d_in[3];
    const float* fc0_b  = (const float*)d_in[4];
    const float* W1     = (const float*)d_in[5];
    const float* a_src1 = (const float*)d_in[6];
    const float* a_dst1 = (const float*)d_in[7];
    const float* b1     = (const float*)d_in[8];
    const float* W2     = (const float*)d_in[9];
    const float* a_src2 = (const float*)d_in[10];
    const float* a_dst2 = (const float*)d_in[11];
    const float* b2     = (const float*)d_in[12];
    const float* lo_w   = (const float*)d_in[13];
    const float* lo_b   = (const float*)d_in[14];
    float* out = (float*)d_out;

    const int N = in_sizes[0] / 16;
    const int E = in_sizes[1] / 2;
    const int G = out_size / 24;
    const int* src = ei;
    const int* dst = ei + E;
    const int nb = (N + 255) / 256;

    char* wsb = (char*)d_ws;
    size_t off = 0;
    auto allocf = [&](size_t n) { float* p = (float*)(wsb + off); off += ((n * 4 + 255) & ~(size_t)255); return p; };
    auto alloci = [&](size_t n) { int* p = (int*)(wsb + off); off += ((n * 4 + 255) & ~(size_t)255); return p; };
    auto alloch = [&](size_t n) { __half* p = (__half*)(wsb + off); off += ((n * 2 + 255) & ~(size_t)255); return p; };
    __half* hbuf  = alloch((size_t)N * 256);   // h1 uses N*128 halves; h2 uses N*256 halves
    float*  g1    = allocf((size_t)N * 64);
    float*  g2    = allocf((size_t)N * 128);
    float*  es    = allocf((size_t)N * 2);
    float*  ed    = allocf((size_t)N * 2);
    float*  sums  = allocf((size_t)G * 128);
    float*  cnts  = allocf((size_t)G);
    float*  wa1   = allocf(64);
    float*  wd1   = allocf(64);
    float*  wa2   = allocf(128);
    float*  wd2   = allocf(128);
    int* deg     = alloci((size_t)N);
    int* ofs     = alloci((size_t)N + 1);
    int* cursor  = alloci((size_t)N);
    int* sperm   = alloci((size_t)E);
    int* bsum    = alloci((size_t)nb);
    int* bofs    = alloci((size_t)nb);
    (void)ws_size;

    // init (+ folded attention vectors in last block) + CSR build
    init_kernel<<<(N + 255) / 256, 256, 0, stream>>>(deg, sums, cnts, N, G,
            W1, a_src1, a_dst1, W2, a_src2, a_dst2, wa1, wd1, wa2, wd2);
    hist_kernel<<<(E + 255) / 256, 256, 0, stream>>>(dst, deg, E);
    scan_blocks_kernel<<<nb, 256, 0, stream>>>(deg, ofs, bsum, N);
    scan_bsum_kernel<<<1, 1024, 0, stream>>>(bsum, bofs, ofs + N, nb);
    scan_add_kernel<<<nb, 256, 0, stream>>>(ofs, bofs, cursor, batch, cnts, N);
    scatter_kernel<<<(E + 255) / 256, 256, 0, stream>>>(src, dst, cursor, sperm, E);

    // ---- GAT layer 1 (fc0 fused into transform) ----
    fused_t1<<<(N + 7) / 8, 256, 0, stream>>>(x, fc0_w, fc0_b, W1, wa1, wd1, hbuf, es, ed, N);
    gat_agg1<<<(N + 7) / 8, 256, 0, stream>>>(ofs, sperm, es, ed, (const uint2*)hbuf, b1, g1, N);

    // ---- GAT layer 2 ----
    gat_transform2<<<(N + 7) / 8, 256, 0, stream>>>(g1, W2, wa2, wd2, hbuf, es, ed, N);
    gat_agg2<<<(N + 7) / 8, 256, 0, stream>>>(ofs, sperm, es, ed, (const uint4*)hbuf, b2, g2, N);

    // ---- pool + final linear ----
    pool_kernel<<<(N + POOL_NPB - 1) / POOL_NPB, 256, 0, stream>>>(g2, batch, sums, N);
    final_kernel<<<G, 32, 0, stream>>>(sums, cnts, lo_w, lo_b, out, G);
}

// Round 5
// 364.758 us; speedup vs baseline: 1.3037x; 1.0591x over previous
//
#include <hip/hip_runtime.h>
#include <hip/hip_fp16.h>
#include <math.h>

#define NEG_SLOPE 0.2f
#define GAT_EPS 1e-16f

__device__ __forceinline__ float elu_f(float x) { return x > 0.f ? x : expm1f(x); }
__device__ __forceinline__ float lrelu_f(float x) { return x > 0.f ? x : NEG_SLOPE * x; }

typedef _Float16 half2v __attribute__((ext_vector_type(2)));
typedef _Float16 half8 __attribute__((ext_vector_type(8)));
typedef float f32x4 __attribute__((ext_vector_type(4)));

// fp32 accumulate of half2 dot: acc += v.x*a.x + v.y*a.y
__device__ __forceinline__ float fdot2f(unsigned int v, unsigned int a, float acc) {
#if __has_builtin(__builtin_amdgcn_fdot2)
    return __builtin_amdgcn_fdot2(__builtin_bit_cast(half2v, v),
                                  __builtin_bit_cast(half2v, a), acc, false);
#else
    __half2 hv = __builtin_bit_cast(__half2, v);
    __half2 ha = __builtin_bit_cast(__half2, a);
    float2 fv = __half22float2(hv), fa = __half22float2(ha);
    return fmaf(fv.x, fa.x, fmaf(fv.y, fa.y, acc));
#endif
}

__device__ __forceinline__ unsigned int pack_half2(float a, float b) {
    __half2 h = __floats2half2_rn(a, b);
    return __builtin_bit_cast(unsigned int, h);
}

// reduction within a 32-lane half-wave (xor offsets stay inside the half)
__device__ __forceinline__ float halfReduceSum(float v) {
    #pragma unroll
    for (int off = 16; off > 0; off >>= 1) v += __shfl_xor(v, off, 64);
    return v;
}

// ---------------- init: zero deg/sums/cnts; block1 builds W2T fp16; last block folds attn vectors ----------------
__global__ void init_kernel(int* deg, float* sums, float* cnts, int N, int G,
        const float* __restrict__ W1, const float* __restrict__ as1, const float* __restrict__ ad1,
        const float* __restrict__ W2, const float* __restrict__ as2, const float* __restrict__ ad2,
        float* __restrict__ wa1, float* __restrict__ wd1,
        float* __restrict__ wa2, float* __restrict__ wd2,
        __half* __restrict__ w2t) {
    int i = blockIdx.x * 256 + threadIdx.x;
    if (i < N) deg[i] = 0;
    if (i < G * 128) sums[i] = 0.f;
    if (i < G) cnts[i] = 0.f;
    if (blockIdx.x == 1) {
        // W2T[c2][k] = W2[h=c2&1][k][o=c2>>1], fp16, [256][64]
        for (int idx = threadIdx.x; idx < 16384; idx += 256) {
            int c2 = idx >> 6, k = idx & 63;
            w2t[idx] = __float2half(W2[(c2 & 1) * 8192 + k * 128 + (c2 >> 1)]);
        }
    }
    if (blockIdx.x == gridDim.x - 1) {
        int t = threadIdx.x;
        if (t < 64) {                      // layer1: h=t>>5, c=t&31
            int h = t >> 5, c = t & 31;
            const float* w = W1 + (h * 32 + c) * 64;
            float sa = 0.f, sd = 0.f;
            for (int o = 0; o < 64; ++o) {
                sa = fmaf(w[o], as1[h * 64 + o], sa);
                sd = fmaf(w[o], ad1[h * 64 + o], sd);
            }
            wa1[t] = sa; wd1[t] = sd;
        } else if (t < 192) {              // layer2: u=t-64, h=u>>6, c=u&63
            int u = t - 64, h = u >> 6, c = u & 63;
            const float* w = W2 + (h * 64 + c) * 128;
            float sa = 0.f, sd = 0.f;
            for (int o = 0; o < 128; ++o) {
                sa = fmaf(w[o], as2[h * 128 + o], sa);
                sd = fmaf(w[o], ad2[h * 128 + o], sd);
            }
            wa2[u] = sa; wd2[u] = sd;
        }
    }
}

// ---------------- CSR build ----------------
__global__ __launch_bounds__(256) void hist_kernel(const int* __restrict__ dst,
                                                   int* __restrict__ deg, int E) {
    int e = blockIdx.x * 256 + threadIdx.x;
    if (e < E) atomicAdd(&deg[dst[e]], 1);
}

__global__ __launch_bounds__(256) void scan_blocks_kernel(const int* __restrict__ deg,
        int* __restrict__ ofs, int* __restrict__ bsum, int N) {
    __shared__ int wtot[4];
    int tid = threadIdx.x, lane = tid & 63, wid = tid >> 6;
    int i = blockIdx.x * 256 + tid;
    int v = (i < N) ? deg[i] : 0;
    int incl = v;
    #pragma unroll
    for (int off = 1; off < 64; off <<= 1) {
        int t = __shfl_up(incl, off, 64);
        if (lane >= off) incl += t;
    }
    if (lane == 63) wtot[wid] = incl;
    __syncthreads();
    int woff = 0;
    #pragma unroll
    for (int w = 0; w < 4; ++w) if (w < wid) woff += wtot[w];
    int excl = incl - v + woff;
    if (i < N) ofs[i] = excl;
    if (tid == 255) bsum[blockIdx.x] = woff + incl;
}

__global__ __launch_bounds__(1024) void scan_bsum_kernel(const int* __restrict__ bsum,
        int* __restrict__ bofs, int* __restrict__ ofsN, int nb) {
    __shared__ int wsum[16];
    int tid = threadIdx.x, lane = tid & 63, wid = tid >> 6;
    int v = (tid < nb) ? bsum[tid] : 0;
    int incl = v;
    #pragma unroll
    for (int off = 1; off < 64; off <<= 1) {
        int t = __shfl_up(incl, off, 64);
        if (lane >= off) incl += t;
    }
    if (lane == 63) wsum[wid] = incl;
    __syncthreads();
    if (wid == 0) {
        int wv = (lane < 16) ? wsum[lane] : 0;
        int winc = wv;
        #pragma unroll
        for (int off = 1; off < 16; off <<= 1) {
            int t = __shfl_up(winc, off, 64);
            if (lane >= off) winc += t;
        }
        if (lane < 16) wsum[lane] = winc - wv;
    }
    __syncthreads();
    int excl = incl - v + wsum[wid];
    if (tid < nb) bofs[tid] = excl;
    if (tid == nb - 1) *ofsN = excl + v;
}

__global__ __launch_bounds__(256) void scan_add_kernel(int* __restrict__ ofs,
        const int* __restrict__ bofs, int* __restrict__ cursor,
        const int* __restrict__ batch, float* __restrict__ cnts, int N) {
    int i = blockIdx.x * 256 + threadIdx.x;
    if (i < N) {
        int v = ofs[i] + bofs[blockIdx.x];
        ofs[i] = v;
        cursor[i] = v;
        // graph node-counts (batch is sorted -> waves are almost always uniform)
        int b = batch[i];
        int b0 = __shfl(b, 0, 64);
        if (__all(b == b0)) {
            unsigned long long m = __ballot(1);
            if ((threadIdx.x & 63) == 0) atomicAdd(&cnts[b], (float)__popcll(m));
        } else {
            atomicAdd(&cnts[b], 1.f);
        }
    }
}

__global__ __launch_bounds__(256) void scatter_kernel(
        const int* __restrict__ src, const int* __restrict__ dst,
        int* __restrict__ cursor, int* __restrict__ sperm, int E) {
    int e = blockIdx.x * 256 + threadIdx.x;
    if (e >= E) return;
    int d = dst[e];
    int pos = atomicAdd(&cursor[d], 1);
    sperm[pos] = src[e];
}

// ---------------- fused fc0 + GAT layer1 transform (8 nodes/block) ----------------
__global__ __launch_bounds__(256) void fused_t1(
        const float* __restrict__ x, const float* __restrict__ w0,
        const float* __restrict__ b0, const float* __restrict__ W1,
        const float* __restrict__ wa1, const float* __restrict__ wd1,
        __half* __restrict__ h1, float* __restrict__ es, float* __restrict__ ed, int N) {
    __shared__ float xs[8 * 16];
    __shared__ float hs[8 * 32];
    int n0 = blockIdx.x * 8;
    int tid = threadIdx.x;
    if (tid < 128) {
        int gi = n0 * 16 + tid;
        xs[tid] = (gi < N * 16) ? x[gi] : 0.f;
    }
    __syncthreads();
    {
        int j = tid >> 5, o = tid & 31;
        float acc = b0[o];
        #pragma unroll
        for (int c = 0; c < 16; ++c) acc = fmaf(xs[j * 16 + c], w0[c * 32 + o], acc);
        hs[j * 32 + o] = elu_f(acc);
    }
    __syncthreads();
    int o = tid & 63, h = (tid >> 6) & 1, nh = tid >> 7;
    float acc[4];
    #pragma unroll
    for (int j = 0; j < 4; ++j) acc[j] = 0.f;
    const float* wp = W1 + h * (32 * 64) + o;
    #pragma unroll
    for (int c = 0; c < 32; ++c) {
        float wv = wp[c * 64];
        #pragma unroll
        for (int j = 0; j < 4; ++j) acc[j] = fmaf(hs[(nh * 4 + j) * 32 + c], wv, acc[j]);
    }
    #pragma unroll
    for (int j = 0; j < 4; ++j) {
        int n = n0 + nh * 4 + j;
        if (n < N) h1[(size_t)n * 128 + 2 * o + h] = __float2half(acc[j]);
    }
    if (tid < 32) {
        int n = tid >> 2, r = tid & 3, hh = r >> 1, isd = r & 1;
        const float* wv = (isd ? wd1 : wa1) + hh * 32;
        float s = 0.f;
        #pragma unroll
        for (int c = 0; c < 32; ++c) s = fmaf(hs[n * 32 + c], wv[c], s);
        int nn = n0 + n;
        if (nn < N) { if (isd) ed[nn * 2 + hh] = s; else es[nn * 2 + hh] = s; }
    }
}

// ---------------- GAT layer2 transform: MFMA GEMM [N x 64] @ [64 x 256] ----------------
// 64 nodes/block, 4 waves x 16 nodes. B (W2T) staged in LDS with XOR swizzle;
// D restaged through LDS for coalesced stores.
__global__ __launch_bounds__(256) void t2_mfma(
        const __half* __restrict__ g1h,   // [Npad][64] fp16
        const __half* __restrict__ w2t,   // [256][64] fp16
        __half* __restrict__ h2, int N) {
    __shared__ __half sbuf[16384];   // 32KB: B during GEMM, then D for store
    int tid = threadIdx.x;
    {   // stage B: 2048 uint4, XOR-swizzled (row = 128B = 8 uint4)
        const uint4* srcv = reinterpret_cast<const uint4*>(w2t);
        #pragma unroll
        for (int i = 0; i < 8; ++i) {
            int idx = tid + i * 256;
            int row = idx >> 3;
            int byteoff = (idx * 16) ^ ((row & 7) << 4);
            *reinterpret_cast<uint4*>(reinterpret_cast<char*>(sbuf) + byteoff) = srcv[idx];
        }
    }
    __syncthreads();
    int w = tid >> 6, lane = tid & 63;
    int r = lane & 15, kg = lane >> 4;
    int nodei = blockIdx.x * 64 + w * 16 + r;
    const half8* ap = reinterpret_cast<const half8*>(
        reinterpret_cast<const _Float16*>(g1h) + (size_t)nodei * 64 + kg * 8);

    f32x4 acc[16];
    #pragma unroll
    for (int nf = 0; nf < 16; ++nf) acc[nf] = f32x4{0.f, 0.f, 0.f, 0.f};
    half8 az = {};
    #pragma unroll
    for (int ks = 0; ks < 2; ++ks) {
        half8 a = (nodei < N) ? ap[ks * 4] : az;   // +32 halves per kstep
        #pragma unroll
        for (int nf = 0; nf < 16; ++nf) {
            int brow = nf * 16 + r;
            int bbyte = (brow * 128 + ks * 64 + kg * 16) ^ ((brow & 7) << 4);
            half8 b = *reinterpret_cast<const half8*>(reinterpret_cast<const char*>(sbuf) + bbyte);
            acc[nf] = __builtin_amdgcn_mfma_f32_16x16x32_f16(a, b, acc[nf], 0, 0, 0);
        }
    }
    __syncthreads();   // all waves done reading B
    // D -> sbuf as [64 nodes][256 ch] fp16 (D layout: col=lane&15, row=kg*4+q)
    #pragma unroll
    for (int nf = 0; nf < 16; ++nf) {
        int col = nf * 16 + r;
        #pragma unroll
        for (int q = 0; q < 4; ++q) {
            int nloc = w * 16 + kg * 4 + q;
            sbuf[nloc * 256 + col] = __float2half(acc[nf][q]);
        }
    }
    __syncthreads();
    {   // coalesced store: 2048 uint4 (32 uint4 per node row)
        const uint4* sv = reinterpret_cast<const uint4*>(sbuf);
        #pragma unroll
        for (int i = 0; i < 8; ++i) {
            int idx = tid + i * 256;
            int nloc = idx >> 5;
            int n = blockIdx.x * 64 + nloc;
            if (n < N)
                reinterpret_cast<uint4*>(h2)[(size_t)n * 32 + (idx & 31)] = sv[idx];
        }
    }
}

// ---------------- aggregation layer1: one HALF-WAVE (32 lanes) per dst node ----------------
// Outputs g1 as fp16 (GEMM A operand) and layer-2 attention scalars es2/ed2
// (computed from fp32 pre-pack values == old fp32 path numerics).
__global__ __launch_bounds__(256) void gat_agg1(
        const int* __restrict__ ofs, const int* __restrict__ sperm,
        const float* __restrict__ es, const float* __restrict__ ed,
        const uint2* __restrict__ h1v, const float* __restrict__ b1,
        const float* __restrict__ wa2, const float* __restrict__ wd2,
        unsigned int* __restrict__ g1h, float* __restrict__ es2, float* __restrict__ ed2, int N) {
    __shared__ uint2 meta[8][32];
    int half = threadIdx.x >> 5;          // 0..7
    int d = blockIdx.x * 8 + half;
    if (d >= N) return;
    int lane = threadIdx.x & 31;
    float2 edv = *reinterpret_cast<const float2*>(ed + (size_t)d * 2);
    int beg = ofs[d], end = ofs[d + 1];
    int deg = end - beg;
    int jmax = deg < 32 ? deg : 32;

    int s_f = 0;
    float ex0 = 0.f, ex1 = 0.f;
    int i0 = beg + lane;
    if (i0 < end) {
        s_f = sperm[i0];
        float2 esv = *reinterpret_cast<const float2*>(es + (size_t)s_f * 2);
        ex0 = __expf(lrelu_f(esv.x + edv.x));
        ex1 = __expf(lrelu_f(esv.y + edv.y));
    }
    float s0 = ex0, s1 = ex1;
    for (int i = i0 + 32; i < end; i += 32) {  // rare: deg > 32
        int s = sperm[i];
        float2 esv = *reinterpret_cast<const float2*>(es + (size_t)s * 2);
        s0 += __expf(lrelu_f(esv.x + edv.x));
        s1 += __expf(lrelu_f(esv.y + edv.y));
    }
    s0 = halfReduceSum(s0);
    s1 = halfReduceSum(s1);
    float r0 = 0.5f / (s0 + GAT_EPS), r1 = 0.5f / (s1 + GAT_EPS);
    if (lane < jmax)
        meta[half][lane] = make_uint2((unsigned int)s_f, pack_half2(ex0 * r0, ex1 * r1));
    // half-wave-internal LDS write->read; compiler inserts lgkmcnt wait, no barrier needed

    // lane covers channels 2*lane, 2*lane+1 (both heads interleaved in h1)
    float acc0 = 0.f, acc1 = 0.f;
    int j = 0;
    for (; j + 16 <= jmax; j += 16) {
        uint2 vv[16];
        #pragma unroll
        for (int k = 0; k < 16; ++k) vv[k] = h1v[(size_t)meta[half][j + k].x * 32 + lane];
        #pragma unroll
        for (int k = 0; k < 16; ++k) {
            unsigned int my = meta[half][j + k].y;
            acc0 = fdot2f(vv[k].x, my, acc0);
            acc1 = fdot2f(vv[k].y, my, acc1);
        }
    }
    for (; j + 8 <= jmax; j += 8) {
        uint2 vv[8];
        #pragma unroll
        for (int k = 0; k < 8; ++k) vv[k] = h1v[(size_t)meta[half][j + k].x * 32 + lane];
        #pragma unroll
        for (int k = 0; k < 8; ++k) {
            unsigned int my = meta[half][j + k].y;
            acc0 = fdot2f(vv[k].x, my, acc0);
            acc1 = fdot2f(vv[k].y, my, acc1);
        }
    }
    for (; j < jmax; ++j) {
        uint2 m = meta[half][j];
        uint2 v = h1v[(size_t)m.x * 32 + lane];
        acc0 = fdot2f(v.x, m.y, acc0);
        acc1 = fdot2f(v.y, m.y, acc1);
    }
    for (int i = beg + 32; i < end; ++i) {  // rare: deg > 32
        int s = sperm[i];
        float2 esv = *reinterpret_cast<const float2*>(es + (size_t)s * 2);
        float a0 = __expf(lrelu_f(esv.x + edv.x)) * r0;
        float a1 = __expf(lrelu_f(esv.y + edv.y)) * r1;
        unsigned int ap = pack_half2(a0, a1);
        uint2 v = h1v[(size_t)s * 32 + lane];
        acc0 = fdot2f(v.x, ap, acc0);
        acc1 = fdot2f(v.y, ap, acc1);
    }
    float2 bv = reinterpret_cast<const float2*>(b1)[lane];
    float o0f = elu_f(acc0 + bv.x);
    float o1f = elu_f(acc1 + bv.y);
    g1h[(size_t)d * 32 + lane] = pack_half2(o0f, o1f);   // fp16, pre-activated
    // layer-2 attention scalars from fp32 values (same numerics as fp32 g1 path)
    float p0 = fmaf(o0f, wa2[2 * lane],      o1f * wa2[2 * lane + 1]);
    float p1 = fmaf(o0f, wa2[64 + 2 * lane], o1f * wa2[64 + 2 * lane + 1]);
    float q0 = fmaf(o0f, wd2[2 * lane],      o1f * wd2[2 * lane + 1]);
    float q1 = fmaf(o0f, wd2[64 + 2 * lane], o1f * wd2[64 + 2 * lane + 1]);
    p0 = halfReduceSum(p0);
    p1 = halfReduceSum(p1);
    q0 = halfReduceSum(q0);
    q1 = halfReduceSum(q1);
    if (lane == 0) {
        es2[(size_t)d * 2]     = p0;
        es2[(size_t)d * 2 + 1] = p1;
        ed2[(size_t)d * 2]     = q0;
        ed2[(size_t)d * 2 + 1] = q1;
    }
}

// ---------------- aggregation layer2: one HALF-WAVE per dst node, uint4 (16B) loads ----------------
__global__ __launch_bounds__(256) void gat_agg2(
        const int* __restrict__ ofs, const int* __restrict__ sperm,
        const float* __restrict__ es, const float* __restrict__ ed,
        const uint4* __restrict__ h2v, const float* __restrict__ b2,
        float* __restrict__ g2, int N) {
    __shared__ uint2 meta[8][32];
    int half = threadIdx.x >> 5;
    int d = blockIdx.x * 8 + half;
    if (d >= N) return;
    int lane = threadIdx.x & 31;
    float2 edv = *reinterpret_cast<const float2*>(ed + (size_t)d * 2);
    int beg = ofs[d], end = ofs[d + 1];
    int deg = end - beg;
    int jmax = deg < 32 ? deg : 32;

    int s_f = 0;
    float ex0 = 0.f, ex1 = 0.f;
    int i0 = beg + lane;
    if (i0 < end) {
        s_f = sperm[i0];
        float2 esv = *reinterpret_cast<const float2*>(es + (size_t)s_f * 2);
        ex0 = __expf(lrelu_f(esv.x + edv.x));
        ex1 = __expf(lrelu_f(esv.y + edv.y));
    }
    float s0 = ex0, s1 = ex1;
    for (int i = i0 + 32; i < end; i += 32) {  // rare: deg > 32
        int s = sperm[i];
        float2 esv = *reinterpret_cast<const float2*>(es + (size_t)s * 2);
        s0 += __expf(lrelu_f(esv.x + edv.x));
        s1 += __expf(lrelu_f(esv.y + edv.y));
    }
    s0 = halfReduceSum(s0);
    s1 = halfReduceSum(s1);
    float r0 = 0.5f / (s0 + GAT_EPS), r1 = 0.5f / (s1 + GAT_EPS);
    if (lane < jmax)
        meta[half][lane] = make_uint2((unsigned int)s_f, pack_half2(ex0 * r0, ex1 * r1));

    // lane covers channels 4*lane .. 4*lane+3 (heads interleaved in h2)
    float acc0 = 0.f, acc1 = 0.f, acc2 = 0.f, acc3 = 0.f;
    int j = 0;
    for (; j + 16 <= jmax; j += 16) {
        uint4 vv[16];
        #pragma unroll
        for (int k = 0; k < 16; ++k) vv[k] = h2v[(size_t)meta[half][j + k].x * 32 + lane];
        #pragma unroll
        for (int k = 0; k < 16; ++k) {
            unsigned int my = meta[half][j + k].y;
            acc0 = fdot2f(vv[k].x, my, acc0);
            acc1 = fdot2f(vv[k].y, my, acc1);
            acc2 = fdot2f(vv[k].z, my, acc2);
            acc3 = fdot2f(vv[k].w, my, acc3);
        }
    }
    for (; j + 8 <= jmax; j += 8) {
        uint4 vv[8];
        #pragma unroll
        for (int k = 0; k < 8; ++k) vv[k] = h2v[(size_t)meta[half][j + k].x * 32 + lane];
        #pragma unroll
        for (int k = 0; k < 8; ++k) {
            unsigned int my = meta[half][j + k].y;
            acc0 = fdot2f(vv[k].x, my, acc0);
            acc1 = fdot2f(vv[k].y, my, acc1);
            acc2 = fdot2f(vv[k].z, my, acc2);
            acc3 = fdot2f(vv[k].w, my, acc3);
        }
    }
    for (; j < jmax; ++j) {
        uint2 m = meta[half][j];
        uint4 v = h2v[(size_t)m.x * 32 + lane];
        acc0 = fdot2f(v.x, m.y, acc0);
        acc1 = fdot2f(v.y, m.y, acc1);
        acc2 = fdot2f(v.z, m.y, acc2);
        acc3 = fdot2f(v.w, m.y, acc3);
    }
    for (int i = beg + 32; i < end; ++i) {  // rare: deg > 32
        int s = sperm[i];
        float2 esv = *reinterpret_cast<const float2*>(es + (size_t)s * 2);
        float a0 = __expf(lrelu_f(esv.x + edv.x)) * r0;
        float a1 = __expf(lrelu_f(esv.y + edv.y)) * r1;
        unsigned int ap = pack_half2(a0, a1);
        uint4 v = h2v[(size_t)s * 32 + lane];
        acc0 = fdot2f(v.x, ap, acc0);
        acc1 = fdot2f(v.y, ap, acc1);
        acc2 = fdot2f(v.z, ap, acc2);
        acc3 = fdot2f(v.w, ap, acc3);
    }
    float4 bv = reinterpret_cast<const float4*>(b2)[lane];
    float4 o4;
    o4.x = elu_f(acc0 + bv.x);
    o4.y = elu_f(acc1 + bv.y);
    o4.z = elu_f(acc2 + bv.z);
    o4.w = elu_f(acc3 + bv.w);
    *reinterpret_cast<float4*>(g2 + (size_t)d * 128 + 4 * lane) = o4;  // pre-activated
}

// ---------------- pool: sorted-batch run accumulation (g2 pre-activated; cnts from scan_add) ----------------
#define POOL_NPB 128
__global__ __launch_bounds__(256) void pool_kernel(
        const float* __restrict__ g2, const int* __restrict__ batch,
        float* __restrict__ sums, int N) {
    int n0 = blockIdx.x * POOL_NPB;
    int c = threadIdx.x & 127;
    int p = threadIdx.x >> 7;
    int nend = n0 + POOL_NPB; if (nend > N) nend = N;
    int n = n0 + p;
    if (n >= nend) return;
    int cur_b = batch[n];
    float acc = 0.f;
    for (; n < nend; n += 2) {
        int b = batch[n];
        if (b != cur_b) {
            atomicAdd(&sums[(size_t)cur_b * 128 + c], acc);
            acc = 0.f; cur_b = b;
        }
        acc += g2[(size_t)n * 128 + c];
    }
    atomicAdd(&sums[(size_t)cur_b * 128 + c], acc);
}

// ---------------- final: out = (sums/cnt) @ lo_w + lo_b ----------------
__global__ void final_kernel(
        const float* __restrict__ sums, const float* __restrict__ cnts,
        const float* __restrict__ w, const float* __restrict__ b,
        float* __restrict__ out, int G) {
    int g = blockIdx.x;
    int k = threadIdx.x;
    if (k >= 24) return;
    float inv = 1.f / fmaxf(cnts[g], 1.f);
    float acc = b[k];
    #pragma unroll
    for (int c = 0; c < 128; ++c) acc = fmaf(sums[g * 128 + c] * inv, w[c * 24 + k], acc);
    out[g * 24 + k] = acc;
}

extern "C" void kernel_launch(void* const* d_in, const int* in_sizes, int n_in,
                              void* d_out, int out_size, void* d_ws, size_t ws_size,
                              hipStream_t stream) {
    const float* x      = (const float*)d_in[0];
    const int*   ei     = (const int*)d_in[1];
    const int*   batch  = (const int*)d_in[2];
    const float* fc0_w  = (const float*)d_in[3];
    const float* fc0_b  = (const float*)d_in[4];
    const float* W1     = (const float*)d_in[5];
    const float* a_src1 = (const float*)d_in[6];
    const float* a_dst1 = (const float*)d_in[7];
    const float* b1     = (const float*)d_in[8];
    const float* W2     = (const float*)d_in[9];
    const float* a_src2 = (const float*)d_in[10];
    const float* a_dst2 = (const float*)d_in[11];
    const float* b2     = (const float*)d_in[12];
    const float* lo_w   = (const float*)d_in[13];
    const float* lo_b   = (const float*)d_in[14];
    float* out = (float*)d_out;

    const int N = in_sizes[0] / 16;
    const int E = in_sizes[1] / 2;
    const int G = out_size / 24;
    const int* src = ei;
    const int* dst = ei + E;
    const int nb = (N + 255) / 256;

    char* wsb = (char*)d_ws;
    size_t off = 0;
    auto allocf = [&](size_t n) { float* p = (float*)(wsb + off); off += ((n * 4 + 255) & ~(size_t)255); return p; };
    auto alloci = [&](size_t n) { int* p = (int*)(wsb + off); off += ((n * 4 + 255) & ~(size_t)255); return p; };
    auto alloch = [&](size_t n) { __half* p = (__half*)(wsb + off); off += ((n * 2 + 255) & ~(size_t)255); return p; };
    __half* hbuf  = alloch((size_t)N * 256);        // h1 uses N*128 halves; h2 uses N*256 halves
    __half* g1h   = alloch((size_t)(N + 64) * 64);  // fp16 g1 (padded for 64-node GEMM blocks)
    __half* w2t   = alloch(16384);                  // W2 transposed [256][64] fp16
    float*  g2    = allocf((size_t)N * 128);
    float*  es    = allocf((size_t)N * 2);
    float*  ed    = allocf((size_t)N * 2);
    float*  es2   = allocf((size_t)N * 2);
    float*  ed2   = allocf((size_t)N * 2);
    float*  sums  = allocf((size_t)G * 128);
    float*  cnts  = allocf((size_t)G);
    float*  wa1   = allocf(64);
    float*  wd1   = allocf(64);
    float*  wa2   = allocf(128);
    float*  wd2   = allocf(128);
    int* deg     = alloci((size_t)N);
    int* ofs     = alloci((size_t)N + 1);
    int* cursor  = alloci((size_t)N);
    int* sperm   = alloci((size_t)E);
    int* bsum    = alloci((size_t)nb);
    int* bofs    = alloci((size_t)nb);
    (void)ws_size;

    // init (+ W2T build + folded attention vectors) + CSR build
    init_kernel<<<(N + 255) / 256, 256, 0, stream>>>(deg, sums, cnts, N, G,
            W1, a_src1, a_dst1, W2, a_src2, a_dst2, wa1, wd1, wa2, wd2, w2t);
    hist_kernel<<<(E + 255) / 256, 256, 0, stream>>>(dst, deg, E);
    scan_blocks_kernel<<<nb, 256, 0, stream>>>(deg, ofs, bsum, N);
    scan_bsum_kernel<<<1, 1024, 0, stream>>>(bsum, bofs, ofs + N, nb);
    scan_add_kernel<<<nb, 256, 0, stream>>>(ofs, bofs, cursor, batch, cnts, N);
    scatter_kernel<<<(E + 255) / 256, 256, 0, stream>>>(src, dst, cursor, sperm, E);

    // ---- GAT layer 1 (fc0 fused into transform; layer-2 attn scalars fused into agg) ----
    fused_t1<<<(N + 7) / 8, 256, 0, stream>>>(x, fc0_w, fc0_b, W1, wa1, wd1, hbuf, es, ed, N);
    gat_agg1<<<(N + 7) / 8, 256, 0, stream>>>(ofs, sperm, es, ed, (const uint2*)hbuf, b1,
            wa2, wd2, (unsigned int*)g1h, es2, ed2, N);

    // ---- GAT layer 2 (MFMA transform) ----
    t2_mfma<<<(N + 63) / 64, 256, 0, stream>>>(g1h, w2t, hbuf, N);
    gat_agg2<<<(N + 7) / 8, 256, 0, stream>>>(ofs, sperm, es2, ed2, (const uint4*)hbuf, b2, g2, N);

    // ---- pool + final linear ----
    pool_kernel<<<(N + POOL_NPB - 1) / POOL_NPB, 256, 0, stream>>>(g2, batch, sums, N);
    final_kernel<<<G, 32, 0, stream>>>(sums, cnts, lo_w, lo_b, out, G);
}

// Round 6
// 338.824 us; speedup vs baseline: 1.4035x; 1.0765x over previous
//
#include <hip/hip_runtime.h>
#include <hip/hip_fp16.h>
#include <math.h>

#define NEG_SLOPE 0.2f
#define GAT_EPS 1e-16f

__device__ __forceinline__ float elu_f(float x) { return x > 0.f ? x : expm1f(x); }
__device__ __forceinline__ float lrelu_f(float x) { return x > 0.f ? x : NEG_SLOPE * x; }

typedef _Float16 half2v __attribute__((ext_vector_type(2)));
typedef _Float16 half8 __attribute__((ext_vector_type(8)));
typedef float f32x4 __attribute__((ext_vector_type(4)));

// fp32 accumulate of half2 dot: acc += v.x*a.x + v.y*a.y
__device__ __forceinline__ float fdot2f(unsigned int v, unsigned int a, float acc) {
#if __has_builtin(__builtin_amdgcn_fdot2)
    return __builtin_amdgcn_fdot2(__builtin_bit_cast(half2v, v),
                                  __builtin_bit_cast(half2v, a), acc, false);
#else
    __half2 hv = __builtin_bit_cast(__half2, v);
    __half2 ha = __builtin_bit_cast(__half2, a);
    float2 fv = __half22float2(hv), fa = __half22float2(ha);
    return fmaf(fv.x, fa.x, fmaf(fv.y, fa.y, acc));
#endif
}

__device__ __forceinline__ unsigned int pack_half2(float a, float b) {
    __half2 h = __floats2half2_rn(a, b);
    return __builtin_bit_cast(unsigned int, h);
}

// reduction within a 32-lane half-wave (xor offsets stay inside the half)
__device__ __forceinline__ float halfReduceSum(float v) {
    #pragma unroll
    for (int off = 16; off > 0; off >>= 1) v += __shfl_xor(v, off, 64);
    return v;
}
// reduction within a 16-lane quarter-wave
__device__ __forceinline__ float quarterReduceSum(float v) {
    #pragma unroll
    for (int off = 8; off > 0; off >>= 1) v += __shfl_xor(v, off, 64);
    return v;
}

// ---------------- init: zero deg/sums/cnts; block1 builds W2T fp16; last block folds attn vectors ----------------
__global__ void init_kernel(int* deg, float* sums, float* cnts, int N, int G,
        const float* __restrict__ W1, const float* __restrict__ as1, const float* __restrict__ ad1,
        const float* __restrict__ W2, const float* __restrict__ as2, const float* __restrict__ ad2,
        float* __restrict__ wa1, float* __restrict__ wd1,
        float* __restrict__ wa2, float* __restrict__ wd2,
        __half* __restrict__ w2t) {
    int i = blockIdx.x * 256 + threadIdx.x;
    if (i < N) deg[i] = 0;
    if (i < G * 128) sums[i] = 0.f;
    if (i < G) cnts[i] = 0.f;
    if (blockIdx.x == 1) {
        // W2T[c2][k] = W2[h=c2&1][k][o=c2>>1], fp16, [256][64]
        for (int idx = threadIdx.x; idx < 16384; idx += 256) {
            int c2 = idx >> 6, k = idx & 63;
            w2t[idx] = __float2half(W2[(c2 & 1) * 8192 + k * 128 + (c2 >> 1)]);
        }
    }
    if (blockIdx.x == gridDim.x - 1) {
        int t = threadIdx.x;
        if (t < 64) {                      // layer1: h=t>>5, c=t&31
            int h = t >> 5, c = t & 31;
            const float* w = W1 + (h * 32 + c) * 64;
            float sa = 0.f, sd = 0.f;
            for (int o = 0; o < 64; ++o) {
                sa = fmaf(w[o], as1[h * 64 + o], sa);
                sd = fmaf(w[o], ad1[h * 64 + o], sd);
            }
            wa1[t] = sa; wd1[t] = sd;
        } else if (t < 192) {              // layer2: u=t-64, h=u>>6, c=u&63
            int u = t - 64, h = u >> 6, c = u & 63;
            const float* w = W2 + (h * 64 + c) * 128;
            float sa = 0.f, sd = 0.f;
            for (int o = 0; o < 128; ++o) {
                sa = fmaf(w[o], as2[h * 128 + o], sa);
                sd = fmaf(w[o], ad2[h * 128 + o], sd);
            }
            wa2[u] = sa; wd2[u] = sd;
        }
    }
}

// ---------------- CSR build ----------------
__global__ __launch_bounds__(256) void hist_kernel(const int* __restrict__ dst,
                                                   int* __restrict__ deg, int E) {
    int e = blockIdx.x * 256 + threadIdx.x;
    if (e < E) atomicAdd(&deg[dst[e]], 1);
}

__global__ __launch_bounds__(256) void scan_blocks_kernel(const int* __restrict__ deg,
        int* __restrict__ ofs, int* __restrict__ bsum, int N) {
    __shared__ int wtot[4];
    int tid = threadIdx.x, lane = tid & 63, wid = tid >> 6;
    int i = blockIdx.x * 256 + tid;
    int v = (i < N) ? deg[i] : 0;
    int incl = v;
    #pragma unroll
    for (int off = 1; off < 64; off <<= 1) {
        int t = __shfl_up(incl, off, 64);
        if (lane >= off) incl += t;
    }
    if (lane == 63) wtot[wid] = incl;
    __syncthreads();
    int woff = 0;
    #pragma unroll
    for (int w = 0; w < 4; ++w) if (w < wid) woff += wtot[w];
    int excl = incl - v + woff;
    if (i < N) ofs[i] = excl;
    if (tid == 255) bsum[blockIdx.x] = woff + incl;
}

__global__ __launch_bounds__(1024) void scan_bsum_kernel(const int* __restrict__ bsum,
        int* __restrict__ bofs, int* __restrict__ ofsN, int nb) {
    __shared__ int wsum[16];
    int tid = threadIdx.x, lane = tid & 63, wid = tid >> 6;
    int v = (tid < nb) ? bsum[tid] : 0;
    int incl = v;
    #pragma unroll
    for (int off = 1; off < 64; off <<= 1) {
        int t = __shfl_up(incl, off, 64);
        if (lane >= off) incl += t;
    }
    if (lane == 63) wsum[wid] = incl;
    __syncthreads();
    if (wid == 0) {
        int wv = (lane < 16) ? wsum[lane] : 0;
        int winc = wv;
        #pragma unroll
        for (int off = 1; off < 16; off <<= 1) {
            int t = __shfl_up(winc, off, 64);
            if (lane >= off) winc += t;
        }
        if (lane < 16) wsum[lane] = winc - wv;
    }
    __syncthreads();
    int excl = incl - v + wsum[wid];
    if (tid < nb) bofs[tid] = excl;
    if (tid == nb - 1) *ofsN = excl + v;
}

__global__ __launch_bounds__(256) void scan_add_kernel(int* __restrict__ ofs,
        const int* __restrict__ bofs, int* __restrict__ cursor,
        const int* __restrict__ batch, float* __restrict__ cnts, int N) {
    int i = blockIdx.x * 256 + threadIdx.x;
    if (i < N) {
        int v = ofs[i] + bofs[blockIdx.x];
        ofs[i] = v;
        cursor[i] = v;
        // graph node-counts (batch is sorted -> waves are almost always uniform)
        int b = batch[i];
        int b0 = __shfl(b, 0, 64);
        if (__all(b == b0)) {
            unsigned long long m = __ballot(1);
            if ((threadIdx.x & 63) == 0) atomicAdd(&cnts[b], (float)__popcll(m));
        } else {
            atomicAdd(&cnts[b], 1.f);
        }
    }
}

__global__ __launch_bounds__(256) void scatter_kernel(
        const int* __restrict__ src, const int* __restrict__ dst,
        int* __restrict__ cursor, int* __restrict__ sperm, int E) {
    int e = blockIdx.x * 256 + threadIdx.x;
    if (e >= E) return;
    int d = dst[e];
    int pos = atomicAdd(&cursor[d], 1);
    sperm[pos] = src[e];
}

// ---------------- fused fc0 + GAT layer1 transform (8 nodes/block; W1 staged in LDS) ----------------
__global__ __launch_bounds__(256) void fused_t1(
        const float* __restrict__ x, const float* __restrict__ w0,
        const float* __restrict__ b0, const float* __restrict__ W1,
        const float* __restrict__ wa1, const float* __restrict__ wd1,
        __half* __restrict__ h1, float* __restrict__ es, float* __restrict__ ed, int N) {
    __shared__ float xs[8 * 16];
    __shared__ float hs[8 * 32];
    __shared__ float ws[4096];       // W1 (2*32*64 floats = 16KB)
    int n0 = blockIdx.x * 8;
    int tid = threadIdx.x;
    {   // stage W1 once per block (coalesced float4)
        const float4* wv4 = reinterpret_cast<const float4*>(W1);
        float4* ws4 = reinterpret_cast<float4*>(ws);
        #pragma unroll
        for (int i = 0; i < 4; ++i) ws4[tid + i * 256] = wv4[tid + i * 256];
    }
    if (tid < 128) {
        int gi = n0 * 16 + tid;
        xs[tid] = (gi < N * 16) ? x[gi] : 0.f;
    }
    __syncthreads();
    {
        int j = tid >> 5, o = tid & 31;
        float acc = b0[o];
        #pragma unroll
        for (int c = 0; c < 16; ++c) acc = fmaf(xs[j * 16 + c], w0[c * 32 + o], acc);
        hs[j * 32 + o] = elu_f(acc);
    }
    __syncthreads();
    int o = tid & 63, h = (tid >> 6) & 1, nh = tid >> 7;
    float acc[4];
    #pragma unroll
    for (int j = 0; j < 4; ++j) acc[j] = 0.f;
    const float* wp = ws + h * 2048 + o;
    #pragma unroll
    for (int c = 0; c < 32; ++c) {
        float wv = wp[c * 64];
        #pragma unroll
        for (int j = 0; j < 4; ++j) acc[j] = fmaf(hs[(nh * 4 + j) * 32 + c], wv, acc[j]);
    }
    #pragma unroll
    for (int j = 0; j < 4; ++j) {
        int n = n0 + nh * 4 + j;
        if (n < N) h1[(size_t)n * 128 + 2 * o + h] = __float2half(acc[j]);
    }
    if (tid < 32) {
        int n = tid >> 2, r = tid & 3, hh = r >> 1, isd = r & 1;
        const float* wv = (isd ? wd1 : wa1) + hh * 32;
        float s = 0.f;
        #pragma unroll
        for (int c = 0; c < 32; ++c) s = fmaf(hs[n * 32 + c], wv[c], s);
        int nn = n0 + n;
        if (nn < N) { if (isd) ed[nn * 2 + hh] = s; else es[nn * 2 + hh] = s; }
    }
}

// ---------------- GAT layer2 transform: MFMA GEMM [N x 64] @ [64 x 256] ----------------
__global__ __launch_bounds__(256) void t2_mfma(
        const __half* __restrict__ g1h,   // [Npad][64] fp16
        const __half* __restrict__ w2t,   // [256][64] fp16
        __half* __restrict__ h2, int N) {
    __shared__ __half sbuf[16384];   // 32KB: B during GEMM, then D for store
    int tid = threadIdx.x;
    {   // stage B: 2048 uint4, XOR-swizzled (row = 128B = 8 uint4)
        const uint4* srcv = reinterpret_cast<const uint4*>(w2t);
        #pragma unroll
        for (int i = 0; i < 8; ++i) {
            int idx = tid + i * 256;
            int row = idx >> 3;
            int byteoff = (idx * 16) ^ ((row & 7) << 4);
            *reinterpret_cast<uint4*>(reinterpret_cast<char*>(sbuf) + byteoff) = srcv[idx];
        }
    }
    __syncthreads();
    int w = tid >> 6, lane = tid & 63;
    int r = lane & 15, kg = lane >> 4;
    int nodei = blockIdx.x * 64 + w * 16 + r;
    const half8* ap = reinterpret_cast<const half8*>(
        reinterpret_cast<const _Float16*>(g1h) + (size_t)nodei * 64 + kg * 8);

    f32x4 acc[16];
    #pragma unroll
    for (int nf = 0; nf < 16; ++nf) acc[nf] = f32x4{0.f, 0.f, 0.f, 0.f};
    half8 az = {};
    #pragma unroll
    for (int ks = 0; ks < 2; ++ks) {
        half8 a = (nodei < N) ? ap[ks * 4] : az;   // +32 halves per kstep
        #pragma unroll
        for (int nf = 0; nf < 16; ++nf) {
            int brow = nf * 16 + r;
            int bbyte = (brow * 128 + ks * 64 + kg * 16) ^ ((brow & 7) << 4);
            half8 b = *reinterpret_cast<const half8*>(reinterpret_cast<const char*>(sbuf) + bbyte);
            acc[nf] = __builtin_amdgcn_mfma_f32_16x16x32_f16(a, b, acc[nf], 0, 0, 0);
        }
    }
    __syncthreads();   // all waves done reading B
    // D -> sbuf as [64 nodes][256 ch] fp16 (D layout: col=lane&15, row=kg*4+q)
    #pragma unroll
    for (int nf = 0; nf < 16; ++nf) {
        int col = nf * 16 + r;
        #pragma unroll
        for (int q = 0; q < 4; ++q) {
            int nloc = w * 16 + kg * 4 + q;
            sbuf[nloc * 256 + col] = __float2half(acc[nf][q]);
        }
    }
    __syncthreads();
    {   // coalesced store: 2048 uint4 (32 uint4 per node row)
        const uint4* sv = reinterpret_cast<const uint4*>(sbuf);
        #pragma unroll
        for (int i = 0; i < 8; ++i) {
            int idx = tid + i * 256;
            int nloc = idx >> 5;
            int n = blockIdx.x * 64 + nloc;
            if (n < N)
                reinterpret_cast<uint4*>(h2)[(size_t)n * 32 + (idx & 31)] = sv[idx];
        }
    }
}

// ---------------- aggregation layer1: one QUARTER-WAVE (16 lanes) per dst node, uint4 loads ----------------
// h1 row = 256B = 16 lanes x 16B -> one load per row per lane; 32 rows in flight/wave at 8-deep.
__global__ __launch_bounds__(256) void gat_agg1(
        const int* __restrict__ ofs, const int* __restrict__ sperm,
        const float* __restrict__ es, const float* __restrict__ ed,
        const uint4* __restrict__ h1v, const float* __restrict__ b1,
        const float* __restrict__ wa2, const float* __restrict__ wd2,
        uint2* __restrict__ g1h, float* __restrict__ es2, float* __restrict__ ed2, int N) {
    __shared__ uint2 meta[16][32];
    int q = threadIdx.x >> 4;            // 0..15
    int d = blockIdx.x * 16 + q;
    int lane = threadIdx.x & 15;
    bool active = d < N;                 // uniform per quarter
    if (!active) return;                 // no block-wide barrier in this kernel
    float2 edv = *reinterpret_cast<const float2*>(ed + (size_t)d * 2);
    int beg = ofs[d], end = ofs[d + 1];
    int deg = end - beg;
    int jmax = deg < 32 ? deg : 32;

    int s0i = 0, s1i = 0;
    float ex00 = 0.f, ex01 = 0.f, ex10 = 0.f, ex11 = 0.f;
    int i0 = beg + lane, i1 = beg + lane + 16;
    if (i0 < end) {
        s0i = sperm[i0];
        float2 e = *reinterpret_cast<const float2*>(es + (size_t)s0i * 2);
        ex00 = __expf(lrelu_f(e.x + edv.x));
        ex01 = __expf(lrelu_f(e.y + edv.y));
    }
    if (i1 < end) {
        s1i = sperm[i1];
        float2 e = *reinterpret_cast<const float2*>(es + (size_t)s1i * 2);
        ex10 = __expf(lrelu_f(e.x + edv.x));
        ex11 = __expf(lrelu_f(e.y + edv.y));
    }
    float s0 = ex00 + ex10, s1 = ex01 + ex11;
    for (int i = i0 + 32; i < end; i += 16) {   // rare: deg > 32
        int s = sperm[i];
        float2 e = *reinterpret_cast<const float2*>(es + (size_t)s * 2);
        s0 += __expf(lrelu_f(e.x + edv.x));
        s1 += __expf(lrelu_f(e.y + edv.y));
    }
    s0 = quarterReduceSum(s0);
    s1 = quarterReduceSum(s1);
    float r0 = 0.5f / (s0 + GAT_EPS), r1 = 0.5f / (s1 + GAT_EPS);
    if (lane < jmax)
        meta[q][lane] = make_uint2((unsigned int)s0i, pack_half2(ex00 * r0, ex01 * r1));
    if (lane + 16 < jmax)
        meta[q][lane + 16] = make_uint2((unsigned int)s1i, pack_half2(ex10 * r0, ex11 * r1));
    // quarter-internal LDS write->read within one wave; compiler inserts lgkmcnt wait

    // lane covers channels 4*lane .. 4*lane+3 (heads interleaved in h1)
    float a0 = 0.f, a1 = 0.f, a2 = 0.f, a3 = 0.f;
    int j = 0;
    for (; j + 8 <= jmax; j += 8) {
        uint4 vv[8];
        #pragma unroll
        for (int k = 0; k < 8; ++k) vv[k] = h1v[(size_t)meta[q][j + k].x * 16 + lane];
        #pragma unroll
        for (int k = 0; k < 8; ++k) {
            unsigned int my = meta[q][j + k].y;
            a0 = fdot2f(vv[k].x, my, a0);
            a1 = fdot2f(vv[k].y, my, a1);
            a2 = fdot2f(vv[k].z, my, a2);
            a3 = fdot2f(vv[k].w, my, a3);
        }
    }
    for (; j + 4 <= jmax; j += 4) {
        uint4 vv[4];
        #pragma unroll
        for (int k = 0; k < 4; ++k) vv[k] = h1v[(size_t)meta[q][j + k].x * 16 + lane];
        #pragma unroll
        for (int k = 0; k < 4; ++k) {
            unsigned int my = meta[q][j + k].y;
            a0 = fdot2f(vv[k].x, my, a0);
            a1 = fdot2f(vv[k].y, my, a1);
            a2 = fdot2f(vv[k].z, my, a2);
            a3 = fdot2f(vv[k].w, my, a3);
        }
    }
    for (; j < jmax; ++j) {
        uint2 m = meta[q][j];
        uint4 v = h1v[(size_t)m.x * 16 + lane];
        a0 = fdot2f(v.x, m.y, a0);
        a1 = fdot2f(v.y, m.y, a1);
        a2 = fdot2f(v.z, m.y, a2);
        a3 = fdot2f(v.w, m.y, a3);
    }
    for (int i = beg + 32; i < end; ++i) {      // rare: deg > 32
        int s = sperm[i];
        float2 e = *reinterpret_cast<const float2*>(es + (size_t)s * 2);
        float w0 = __expf(lrelu_f(e.x + edv.x)) * r0;
        float w1 = __expf(lrelu_f(e.y + edv.y)) * r1;
        unsigned int ap = pack_half2(w0, w1);
        uint4 v = h1v[(size_t)s * 16 + lane];
        a0 = fdot2f(v.x, ap, a0);
        a1 = fdot2f(v.y, ap, a1);
        a2 = fdot2f(v.z, ap, a2);
        a3 = fdot2f(v.w, ap, a3);
    }
    float4 bv = reinterpret_cast<const float4*>(b1)[lane];
    float o0 = elu_f(a0 + bv.x);
    float o1 = elu_f(a1 + bv.y);
    float o2 = elu_f(a2 + bv.z);
    float o3 = elu_f(a3 + bv.w);
    g1h[(size_t)d * 16 + lane] = make_uint2(pack_half2(o0, o1), pack_half2(o2, o3));
    // layer-2 attention scalars (fp32, same numerics as fp32 g1 path)
    float4 wa0 = reinterpret_cast<const float4*>(wa2)[lane];
    float4 wa1v = reinterpret_cast<const float4*>(wa2)[16 + lane];
    float4 wd0 = reinterpret_cast<const float4*>(wd2)[lane];
    float4 wd1v = reinterpret_cast<const float4*>(wd2)[16 + lane];
    float p0 = o0 * wa0.x + o1 * wa0.y + o2 * wa0.z + o3 * wa0.w;
    float p1 = o0 * wa1v.x + o1 * wa1v.y + o2 * wa1v.z + o3 * wa1v.w;
    float q0 = o0 * wd0.x + o1 * wd0.y + o2 * wd0.z + o3 * wd0.w;
    float q1 = o0 * wd1v.x + o1 * wd1v.y + o2 * wd1v.z + o3 * wd1v.w;
    p0 = quarterReduceSum(p0);
    p1 = quarterReduceSum(p1);
    q0 = quarterReduceSum(q0);
    q1 = quarterReduceSum(q1);
    if (lane == 0) {
        es2[(size_t)d * 2]     = p0;
        es2[(size_t)d * 2 + 1] = p1;
        ed2[(size_t)d * 2]     = q0;
        ed2[(size_t)d * 2 + 1] = q1;
    }
}

// ---------------- aggregation layer2 + fused block-level pool (run-length, ~1-2 atomics/block/ch) ----------------
__global__ __launch_bounds__(256) void gat_agg2(
        const int* __restrict__ ofs, const int* __restrict__ sperm,
        const float* __restrict__ es, const float* __restrict__ ed,
        const uint4* __restrict__ h2v, const float* __restrict__ b2,
        const int* __restrict__ batch, float* __restrict__ sums, int N) {
    __shared__ uint2 meta[8][32];
    __shared__ float louts[8 * 128];
    __shared__ int lbat[8];
    int half = threadIdx.x >> 5;
    int d = blockIdx.x * 8 + half;
    int lane = threadIdx.x & 31;
    bool active = d < N;                 // uniform per half; NO early return (barrier below)
    int beg = 0, end = 0;
    if (active) {
        beg = ofs[d]; end = ofs[d + 1];
        if (lane == 0) lbat[half] = batch[d];
    } else if (lane == 0) {
        lbat[half] = -1;
    }
    float2 edv = active ? *reinterpret_cast<const float2*>(ed + (size_t)d * 2)
                        : make_float2(0.f, 0.f);
    int deg = end - beg;
    int jmax = deg < 32 ? deg : 32;

    int s_f = 0;
    float ex0 = 0.f, ex1 = 0.f;
    int i0 = beg + lane;
    if (i0 < end) {
        s_f = sperm[i0];
        float2 esv = *reinterpret_cast<const float2*>(es + (size_t)s_f * 2);
        ex0 = __expf(lrelu_f(esv.x + edv.x));
        ex1 = __expf(lrelu_f(esv.y + edv.y));
    }
    float s0 = ex0, s1 = ex1;
    for (int i = i0 + 32; i < end; i += 32) {  // rare: deg > 32
        int s = sperm[i];
        float2 esv = *reinterpret_cast<const float2*>(es + (size_t)s * 2);
        s0 += __expf(lrelu_f(esv.x + edv.x));
        s1 += __expf(lrelu_f(esv.y + edv.y));
    }
    s0 = halfReduceSum(s0);
    s1 = halfReduceSum(s1);
    float r0 = 0.5f / (s0 + GAT_EPS), r1 = 0.5f / (s1 + GAT_EPS);
    if (lane < jmax)
        meta[half][lane] = make_uint2((unsigned int)s_f, pack_half2(ex0 * r0, ex1 * r1));

    // lane covers channels 4*lane .. 4*lane+3 (heads interleaved in h2)
    float acc0 = 0.f, acc1 = 0.f, acc2 = 0.f, acc3 = 0.f;
    int j = 0;
    for (; j + 8 <= jmax; j += 8) {
        uint4 vv[8];
        #pragma unroll
        for (int k = 0; k < 8; ++k) vv[k] = h2v[(size_t)meta[half][j + k].x * 32 + lane];
        #pragma unroll
        for (int k = 0; k < 8; ++k) {
            unsigned int my = meta[half][j + k].y;
            acc0 = fdot2f(vv[k].x, my, acc0);
            acc1 = fdot2f(vv[k].y, my, acc1);
            acc2 = fdot2f(vv[k].z, my, acc2);
            acc3 = fdot2f(vv[k].w, my, acc3);
        }
    }
    for (; j + 4 <= jmax; j += 4) {
        uint4 vv[4];
        #pragma unroll
        for (int k = 0; k < 4; ++k) vv[k] = h2v[(size_t)meta[half][j + k].x * 32 + lane];
        #pragma unroll
        for (int k = 0; k < 4; ++k) {
            unsigned int my = meta[half][j + k].y;
            acc0 = fdot2f(vv[k].x, my, acc0);
            acc1 = fdot2f(vv[k].y, my, acc1);
            acc2 = fdot2f(vv[k].z, my, acc2);
            acc3 = fdot2f(vv[k].w, my, acc3);
        }
    }
    for (; j < jmax; ++j) {
        uint2 m = meta[half][j];
        uint4 v = h2v[(size_t)m.x * 32 + lane];
        acc0 = fdot2f(v.x, m.y, acc0);
        acc1 = fdot2f(v.y, m.y, acc1);
        acc2 = fdot2f(v.z, m.y, acc2);
        acc3 = fdot2f(v.w, m.y, acc3);
    }
    for (int i = beg + 32; i < end; ++i) {  // rare: deg > 32
        int s = sperm[i];
        float2 esv = *reinterpret_cast<const float2*>(es + (size_t)s * 2);
        float a0 = __expf(lrelu_f(esv.x + edv.x)) * r0;
        float a1 = __expf(lrelu_f(esv.y + edv.y)) * r1;
        unsigned int ap = pack_half2(a0, a1);
        uint4 v = h2v[(size_t)s * 32 + lane];
        acc0 = fdot2f(v.x, ap, acc0);
        acc1 = fdot2f(v.y, ap, acc1);
        acc2 = fdot2f(v.z, ap, acc2);
        acc3 = fdot2f(v.w, ap, acc3);
    }
    float4 bv = reinterpret_cast<const float4*>(b2)[lane];
    float4 o4;
    o4.x = active ? elu_f(acc0 + bv.x) : 0.f;
    o4.y = active ? elu_f(acc1 + bv.y) : 0.f;
    o4.z = active ? elu_f(acc2 + bv.z) : 0.f;
    o4.w = active ? elu_f(acc3 + bv.w) : 0.f;
    *reinterpret_cast<float4*>(louts + half * 128 + 4 * lane) = o4;
    __syncthreads();
    // run-length merge of the block's 8 nodes (batch sorted -> 1-2 runs/block)
    if (threadIdx.x < 128) {
        int c = threadIdx.x;
        int cur = lbat[0];
        float a = 0.f;
        #pragma unroll
        for (int n = 0; n < 8; ++n) {
            int b = lbat[n];
            if (b != cur) {
                if (cur >= 0) atomicAdd(&sums[(size_t)cur * 128 + c], a);
                a = 0.f; cur = b;
            }
            a += louts[n * 128 + c];
        }
        if (cur >= 0) atomicAdd(&sums[(size_t)cur * 128 + c], a);
    }
}

// ---------------- final: out = (sums/cnt) @ lo_w + lo_b ----------------
__global__ void final_kernel(
        const float* __restrict__ sums, const float* __restrict__ cnts,
        const float* __restrict__ w, const float* __restrict__ b,
        float* __restrict__ out, int G) {
    int g = blockIdx.x;
    int k = threadIdx.x;
    if (k >= 24) return;
    float inv = 1.f / fmaxf(cnts[g], 1.f);
    float acc = b[k];
    #pragma unroll
    for (int c = 0; c < 128; ++c) acc = fmaf(sums[g * 128 + c] * inv, w[c * 24 + k], acc);
    out[g * 24 + k] = acc;
}

extern "C" void kernel_launch(void* const* d_in, const int* in_sizes, int n_in,
                              void* d_out, int out_size, void* d_ws, size_t ws_size,
                              hipStream_t stream) {
    const float* x      = (const float*)d_in[0];
    const int*   ei     = (const int*)d_in[1];
    const int*   batch  = (const int*)d_in[2];
    const float* fc0_w  = (const float*)d_in[3];
    const float* fc0_b  = (const float*)d_in[4];
    const float* W1     = (const float*)d_in[5];
    const float* a_src1 = (const float*)d_in[6];
    const float* a_dst1 = (const float*)d_in[7];
    const float* b1     = (const float*)d_in[8];
    const float* W2     = (const float*)d_in[9];
    const float* a_src2 = (const float*)d_in[10];
    const float* a_dst2 = (const float*)d_in[11];
    const float* b2     = (const float*)d_in[12];
    const float* lo_w   = (const float*)d_in[13];
    const float* lo_b   = (const float*)d_in[14];
    float* out = (float*)d_out;

    const int N = in_sizes[0] / 16;
    const int E = in_sizes[1] / 2;
    const int G = out_size / 24;
    const int* src = ei;
    const int* dst = ei + E;
    const int nb = (N + 255) / 256;

    char* wsb = (char*)d_ws;
    size_t off = 0;
    auto allocf = [&](size_t n) { float* p = (float*)(wsb + off); off += ((n * 4 + 255) & ~(size_t)255); return p; };
    auto alloci = [&](size_t n) { int* p = (int*)(wsb + off); off += ((n * 4 + 255) & ~(size_t)255); return p; };
    auto alloch = [&](size_t n) { __half* p = (__half*)(wsb + off); off += ((n * 2 + 255) & ~(size_t)255); return p; };
    __half* hbuf  = alloch((size_t)N * 256);        // h1 uses N*128 halves; h2 uses N*256 halves
    __half* g1h   = alloch((size_t)(N + 64) * 64);  // fp16 g1 (padded for 64-node GEMM blocks)
    __half* w2t   = alloch(16384);                  // W2 transposed [256][64] fp16
    float*  es    = allocf((size_t)N * 2);
    float*  ed    = allocf((size_t)N * 2);
    float*  es2   = allocf((size_t)N * 2);
    float*  ed2   = allocf((size_t)N * 2);
    float*  sums  = allocf((size_t)G * 128);
    float*  cnts  = allocf((size_t)G);
    float*  wa1   = allocf(64);
    float*  wd1   = allocf(64);
    float*  wa2   = allocf(128);
    float*  wd2   = allocf(128);
    int* deg     = alloci((size_t)N);
    int* ofs     = alloci((size_t)N + 1);
    int* cursor  = alloci((size_t)N);
    int* sperm   = alloci((size_t)E);
    int* bsum    = alloci((size_t)nb);
    int* bofs    = alloci((size_t)nb);
    (void)ws_size;

    // init (+ W2T build + folded attention vectors) + CSR build
    init_kernel<<<(N + 255) / 256, 256, 0, stream>>>(deg, sums, cnts, N, G,
            W1, a_src1, a_dst1, W2, a_src2, a_dst2, wa1, wd1, wa2, wd2, w2t);
    hist_kernel<<<(E + 255) / 256, 256, 0, stream>>>(dst, deg, E);
    scan_blocks_kernel<<<nb, 256, 0, stream>>>(deg, ofs, bsum, N);
    scan_bsum_kernel<<<1, 1024, 0, stream>>>(bsum, bofs, ofs + N, nb);
    scan_add_kernel<<<nb, 256, 0, stream>>>(ofs, bofs, cursor, batch, cnts, N);
    scatter_kernel<<<(E + 255) / 256, 256, 0, stream>>>(src, dst, cursor, sperm, E);

    // ---- GAT layer 1 (fc0 fused into transform; layer-2 attn scalars fused into agg) ----
    fused_t1<<<(N + 7) / 8, 256, 0, stream>>>(x, fc0_w, fc0_b, W1, wa1, wd1, hbuf, es, ed, N);
    gat_agg1<<<(N + 15) / 16, 256, 0, stream>>>(ofs, sperm, es, ed, (const uint4*)hbuf, b1,
            wa2, wd2, (uint2*)g1h, es2, ed2, N);

    // ---- GAT layer 2 (MFMA transform; pool fused into aggregation via block run-length) ----
    t2_mfma<<<(N + 63) / 64, 256, 0, stream>>>(g1h, w2t, hbuf, N);
    gat_agg2<<<(N + 7) / 8, 256, 0, stream>>>(ofs, sperm, es2, ed2, (const uint4*)hbuf, b2,
            batch, sums, N);

    // ---- final linear ----
    final_kernel<<<G, 32, 0, stream>>>(sums, cnts, lo_w, lo_b, out, G);
}

// Round 8
// 329.714 us; speedup vs baseline: 1.4423x; 1.0276x over previous
//
#include <hip/hip_runtime.h>
#include <hip/hip_fp16.h>
#include <math.h>

#define NEG_SLOPE 0.2f
#define GAT_EPS 1e-16f

__device__ __forceinline__ float elu_f(float x) { return x > 0.f ? x : expm1f(x); }
__device__ __forceinline__ float lrelu_f(float x) { return x > 0.f ? x : NEG_SLOPE * x; }

typedef _Float16 half2v __attribute__((ext_vector_type(2)));
typedef _Float16 half8 __attribute__((ext_vector_type(8)));
typedef float f32x4 __attribute__((ext_vector_type(4)));
typedef float f32x2 __attribute__((ext_vector_type(2)));

// fp32 accumulate of half2 dot: acc += v.x*a.x + v.y*a.y
__device__ __forceinline__ float fdot2f(unsigned int v, unsigned int a, float acc) {
#if __has_builtin(__builtin_amdgcn_fdot2)
    return __builtin_amdgcn_fdot2(__builtin_bit_cast(half2v, v),
                                  __builtin_bit_cast(half2v, a), acc, false);
#else
    __half2 hv = __builtin_bit_cast(__half2, v);
    __half2 ha = __builtin_bit_cast(__half2, a);
    float2 fv = __half22float2(hv), fa = __half22float2(ha);
    return fmaf(fv.x, fa.x, fmaf(fv.y, fa.y, acc));
#endif
}

__device__ __forceinline__ unsigned int pack_half2(float a, float b) {
    __half2 h = __floats2half2_rn(a, b);
    return __builtin_bit_cast(unsigned int, h);
}

// ---- fp8 e4m3 (gfx950 HW converts; slow software fallback for other targets) ----
#if __has_builtin(__builtin_amdgcn_cvt_pk_fp8_f32) && __has_builtin(__builtin_amdgcn_cvt_pk_f32_fp8)
#define HW_FP8 1
#endif

__device__ __forceinline__ unsigned int pack_fp8x4(float a, float b, float c, float d) {
#ifdef HW_FP8
    int r = 0;
    r = __builtin_amdgcn_cvt_pk_fp8_f32(a, b, r, false);
    r = __builtin_amdgcn_cvt_pk_fp8_f32(c, d, r, true);
    return (unsigned int)r;
#else
    auto enc = [](float x) -> unsigned int {
        if (x != x) return 0x7f;
        float ax = fabsf(x);
        unsigned int s = x < 0.f ? 0x80u : 0u;
        if (ax < 0.001953125f) {  // subnormal: m * 2^-9
            int m = (int)(ax * 512.f + 0.5f);
            if (m > 7) m = 7;
            return s | (unsigned int)m;
        }
        if (ax >= 448.f) return s | 0x7e;  // clamp to max finite
        int e; float fr = frexpf(ax, &e);  // ax = fr*2^e, fr in [0.5,1)
        int m = (int)(fr * 16.f + 0.5f);   // 8..16
        if (m == 16) { m = 8; e += 1; }
        return s | ((unsigned int)(e + 6) << 3) | (unsigned int)(m - 8);
    };
    return enc(a) | (enc(b) << 8) | (enc(c) << 16) | (enc(d) << 24);
#endif
}

template <bool HI>
__device__ __forceinline__ f32x2 fp8x2_to_f32(unsigned int v) {
#ifdef HW_FP8
    return __builtin_amdgcn_cvt_pk_f32_fp8((int)v, HI);   // HI is a constant expression
#else
    auto dec = [](unsigned int b) -> float {
        float s = (b & 0x80) ? -1.f : 1.f;
        int e = (b >> 3) & 0xF, m = b & 7;
        if (e == 0) return s * (float)m * 0.001953125f;
        return s * (8.f + (float)m) * exp2f((float)(e - 10));
    };
    unsigned int sh = HI ? 16 : 0;
    f32x2 r;
    r[0] = dec((v >> sh) & 0xFF);
    r[1] = dec((v >> (sh + 8)) & 0xFF);
    return r;
#endif
}

// reduction within a 32-lane half-wave (xor offsets stay inside the half)
__device__ __forceinline__ float halfReduceSum(float v) {
    #pragma unroll
    for (int off = 16; off > 0; off >>= 1) v += __shfl_xor(v, off, 64);
    return v;
}
// reduction within a 16-lane quarter-wave
__device__ __forceinline__ float quarterReduceSum(float v) {
    #pragma unroll
    for (int off = 8; off > 0; off >>= 1) v += __shfl_xor(v, off, 64);
    return v;
}

// ---------------- init: zero deg/sums/cnts; block1 builds W2T fp16; last block folds attn vectors ----------------
__global__ void init_kernel(int* deg, float* sums, float* cnts, int N, int G,
        const float* __restrict__ W1, const float* __restrict__ as1, const float* __restrict__ ad1,
        const float* __restrict__ W2, const float* __restrict__ as2, const float* __restrict__ ad2,
        float* __restrict__ wa1, float* __restrict__ wd1,
        float* __restrict__ wa2, float* __restrict__ wd2,
        __half* __restrict__ w2t) {
    int i = blockIdx.x * 256 + threadIdx.x;
    if (i < N) deg[i] = 0;
    if (i < G * 128) sums[i] = 0.f;
    if (i < G) cnts[i] = 0.f;
    if (blockIdx.x == 1) {
        // W2T[c2][k] = W2[h=c2&1][k][o=c2>>1], fp16, [256][64]
        for (int idx = threadIdx.x; idx < 16384; idx += 256) {
            int c2 = idx >> 6, k = idx & 63;
            w2t[idx] = __float2half(W2[(c2 & 1) * 8192 + k * 128 + (c2 >> 1)]);
        }
    }
    if (blockIdx.x == gridDim.x - 1) {
        int t = threadIdx.x;
        if (t < 64) {                      // layer1: h=t>>5, c=t&31
            int h = t >> 5, c = t & 31;
            const float* w = W1 + (h * 32 + c) * 64;
            float sa = 0.f, sd = 0.f;
            for (int o = 0; o < 64; ++o) {
                sa = fmaf(w[o], as1[h * 64 + o], sa);
                sd = fmaf(w[o], ad1[h * 64 + o], sd);
            }
            wa1[t] = sa; wd1[t] = sd;
        } else if (t < 192) {              // layer2: u=t-64, h=u>>6, c=u&63
            int u = t - 64, h = u >> 6, c = u & 63;
            const float* w = W2 + (h * 64 + c) * 128;
            float sa = 0.f, sd = 0.f;
            for (int o = 0; o < 128; ++o) {
                sa = fmaf(w[o], as2[h * 128 + o], sa);
                sd = fmaf(w[o], ad2[h * 128 + o], sd);
            }
            wa2[u] = sa; wd2[u] = sd;
        }
    }
}

// ---------------- CSR build ----------------
__global__ __launch_bounds__(256) void hist_kernel(const int* __restrict__ dst,
                                                   int* __restrict__ deg, int E) {
    int e = blockIdx.x * 256 + threadIdx.x;
    if (e < E) atomicAdd(&deg[dst[e]], 1);
}

__global__ __launch_bounds__(256) void scan_blocks_kernel(const int* __restrict__ deg,
        int* __restrict__ ofs, int* __restrict__ bsum, int N) {
    __shared__ int wtot[4];
    int tid = threadIdx.x, lane = tid & 63, wid = tid >> 6;
    int i = blockIdx.x * 256 + tid;
    int v = (i < N) ? deg[i] : 0;
    int incl = v;
    #pragma unroll
    for (int off = 1; off < 64; off <<= 1) {
        int t = __shfl_up(incl, off, 64);
        if (lane >= off) incl += t;
    }
    if (lane == 63) wtot[wid] = incl;
    __syncthreads();
    int woff = 0;
    #pragma unroll
    for (int w = 0; w < 4; ++w) if (w < wid) woff += wtot[w];
    int excl = incl - v + woff;
    if (i < N) ofs[i] = excl;
    if (tid == 255) bsum[blockIdx.x] = woff + incl;
}

__global__ __launch_bounds__(1024) void scan_bsum_kernel(const int* __restrict__ bsum,
        int* __restrict__ bofs, int* __restrict__ ofsN, int nb) {
    __shared__ int wsum[16];
    int tid = threadIdx.x, lane = tid & 63, wid = tid >> 6;
    int v = (tid < nb) ? bsum[tid] : 0;
    int incl = v;
    #pragma unroll
    for (int off = 1; off < 64; off <<= 1) {
        int t = __shfl_up(incl, off, 64);
        if (lane >= off) incl += t;
    }
    if (lane == 63) wsum[wid] = incl;
    __syncthreads();
    if (wid == 0) {
        int wv = (lane < 16) ? wsum[lane] : 0;
        int winc = wv;
        #pragma unroll
        for (int off = 1; off < 16; off <<= 1) {
            int t = __shfl_up(winc, off, 64);
            if (lane >= off) winc += t;
        }
        if (lane < 16) wsum[lane] = winc - wv;
    }
    __syncthreads();
    int excl = incl - v + wsum[wid];
    if (tid < nb) bofs[tid] = excl;
    if (tid == nb - 1) *ofsN = excl + v;
}

__global__ __launch_bounds__(256) void scan_add_kernel(int* __restrict__ ofs,
        const int* __restrict__ bofs, int* __restrict__ cursor,
        const int* __restrict__ batch, float* __restrict__ cnts, int N) {
    int i = blockIdx.x * 256 + threadIdx.x;
    if (i < N) {
        int v = ofs[i] + bofs[blockIdx.x];
        ofs[i] = v;
        cursor[i] = v;
        // graph node-counts (batch is sorted -> waves are almost always uniform)
        int b = batch[i];
        int b0 = __shfl(b, 0, 64);
        if (__all(b == b0)) {
            unsigned long long m = __ballot(1);
            if ((threadIdx.x & 63) == 0) atomicAdd(&cnts[b], (float)__popcll(m));
        } else {
            atomicAdd(&cnts[b], 1.f);
        }
    }
}

__global__ __launch_bounds__(256) void scatter_kernel(
        const int* __restrict__ src, const int* __restrict__ dst,
        int* __restrict__ cursor, int* __restrict__ sperm, int E) {
    int e = blockIdx.x * 256 + threadIdx.x;
    if (e >= E) return;
    int d = dst[e];
    int pos = atomicAdd(&cursor[d], 1);
    sperm[pos] = src[e];
}

// ---------------- fused fc0 + GAT layer1 transform (8 nodes/block; W1 staged in LDS) ----------------
__global__ __launch_bounds__(256) void fused_t1(
        const float* __restrict__ x, const float* __restrict__ w0,
        const float* __restrict__ b0, const float* __restrict__ W1,
        const float* __restrict__ wa1, const float* __restrict__ wd1,
        __half* __restrict__ h1, float* __restrict__ es, float* __restrict__ ed, int N) {
    __shared__ float xs[8 * 16];
    __shared__ float hs[8 * 32];
    __shared__ float ws[4096];       // W1 (2*32*64 floats = 16KB)
    int n0 = blockIdx.x * 8;
    int tid = threadIdx.x;
    {   // stage W1 once per block (coalesced float4)
        const float4* wv4 = reinterpret_cast<const float4*>(W1);
        float4* ws4 = reinterpret_cast<float4*>(ws);
        #pragma unroll
        for (int i = 0; i < 4; ++i) ws4[tid + i * 256] = wv4[tid + i * 256];
    }
    if (tid < 128) {
        int gi = n0 * 16 + tid;
        xs[tid] = (gi < N * 16) ? x[gi] : 0.f;
    }
    __syncthreads();
    {
        int j = tid >> 5, o = tid & 31;
        float acc = b0[o];
        #pragma unroll
        for (int c = 0; c < 16; ++c) acc = fmaf(xs[j * 16 + c], w0[c * 32 + o], acc);
        hs[j * 32 + o] = elu_f(acc);
    }
    __syncthreads();
    int o = tid & 63, h = (tid >> 6) & 1, nh = tid >> 7;
    float acc[4];
    #pragma unroll
    for (int j = 0; j < 4; ++j) acc[j] = 0.f;
    const float* wp = ws + h * 2048 + o;
    #pragma unroll
    for (int c = 0; c < 32; ++c) {
        float wv = wp[c * 64];
        #pragma unroll
        for (int j = 0; j < 4; ++j) acc[j] = fmaf(hs[(nh * 4 + j) * 32 + c], wv, acc[j]);
    }
    #pragma unroll
    for (int j = 0; j < 4; ++j) {
        int n = n0 + nh * 4 + j;
        if (n < N) h1[(size_t)n * 128 + 2 * o + h] = __float2half(acc[j]);
    }
    if (tid < 32) {
        int n = tid >> 2, r = tid & 3, hh = r >> 1, isd = r & 1;
        const float* wv = (isd ? wd1 : wa1) + hh * 32;
        float s = 0.f;
        #pragma unroll
        for (int c = 0; c < 32; ++c) s = fmaf(hs[n * 32 + c], wv[c], s);
        int nn = n0 + n;
        if (nn < N) { if (isd) ed[nn * 2 + hh] = s; else es[nn * 2 + hh] = s; }
    }
}

// ---------------- GAT layer2 transform: MFMA GEMM [N x 64] @ [64 x 256], fp8 output ----------------
// Output h8[node][pos] fp8, PERMUTED: pos = r*16+nf holds channel col = nf*16+r.
// This lets each thread store its D-fragment directly as coalesced dwordx4 (no LDS restage).
__global__ __launch_bounds__(256) void t2_mfma(
        const __half* __restrict__ g1h,   // [Npad][64] fp16
        const __half* __restrict__ w2t,   // [256][64] fp16
        unsigned char* __restrict__ h8, int N) {
    __shared__ __half sbuf[16384];   // 32KB: B operand, XOR-swizzled
    int tid = threadIdx.x;
    {   // stage B: 2048 uint4, XOR-swizzled (row = 128B = 8 uint4)
        const uint4* srcv = reinterpret_cast<const uint4*>(w2t);
        #pragma unroll
        for (int i = 0; i < 8; ++i) {
            int idx = tid + i * 256;
            int row = idx >> 3;
            int byteoff = (idx * 16) ^ ((row & 7) << 4);
            *reinterpret_cast<uint4*>(reinterpret_cast<char*>(sbuf) + byteoff) = srcv[idx];
        }
    }
    __syncthreads();
    int w = tid >> 6, lane = tid & 63;
    int r = lane & 15, kg = lane >> 4;
    int nodei = blockIdx.x * 64 + w * 16 + r;
    const half8* ap = reinterpret_cast<const half8*>(
        reinterpret_cast<const _Float16*>(g1h) + (size_t)nodei * 64 + kg * 8);

    f32x4 acc[16];
    #pragma unroll
    for (int nf = 0; nf < 16; ++nf) acc[nf] = f32x4{0.f, 0.f, 0.f, 0.f};
    half8 az = {};
    #pragma unroll
    for (int ks = 0; ks < 2; ++ks) {
        half8 a = (nodei < N) ? ap[ks * 4] : az;   // +32 halves per kstep
        #pragma unroll
        for (int nf = 0; nf < 16; ++nf) {
            int brow = nf * 16 + r;
            int bbyte = (brow * 128 + ks * 64 + kg * 16) ^ ((brow & 7) << 4);
            half8 b = *reinterpret_cast<const half8*>(reinterpret_cast<const char*>(sbuf) + bbyte);
            acc[nf] = __builtin_amdgcn_mfma_f32_16x16x32_f16(a, b, acc[nf], 0, 0, 0);
        }
    }
    // direct store: D frag (col = nf*16+r, row/node = w*16+kg*4+q) -> permuted fp8 row
    // bytes [r*16, r*16+16) of node's 256B row; 16 lanes cover the row -> coalesced.
    #pragma unroll
    for (int q = 0; q < 4; ++q) {
        int n = blockIdx.x * 64 + w * 16 + kg * 4 + q;
        if (n < N) {
            uint4 pk;
            pk.x = pack_fp8x4(acc[0][q],  acc[1][q],  acc[2][q],  acc[3][q]);
            pk.y = pack_fp8x4(acc[4][q],  acc[5][q],  acc[6][q],  acc[7][q]);
            pk.z = pack_fp8x4(acc[8][q],  acc[9][q],  acc[10][q], acc[11][q]);
            pk.w = pack_fp8x4(acc[12][q], acc[13][q], acc[14][q], acc[15][q]);
            *reinterpret_cast<uint4*>(h8 + (size_t)n * 256 + r * 16) = pk;
        }
    }
}

// ---------------- aggregation layer1: one QUARTER-WAVE (16 lanes) per dst node, uint4 loads ----------------
__global__ __launch_bounds__(256) void gat_agg1(
        const int* __restrict__ ofs, const int* __restrict__ sperm,
        const float* __restrict__ es, const float* __restrict__ ed,
        const uint4* __restrict__ h1v, const float* __restrict__ b1,
        const float* __restrict__ wa2, const float* __restrict__ wd2,
        uint2* __restrict__ g1h, float* __restrict__ es2, float* __restrict__ ed2, int N) {
    __shared__ uint2 meta[16][32];
    int q = threadIdx.x >> 4;            // 0..15
    int d = blockIdx.x * 16 + q;
    int lane = threadIdx.x & 15;
    bool active = d < N;                 // uniform per quarter
    if (!active) return;                 // no block-wide barrier in this kernel
    float2 edv = *reinterpret_cast<const float2*>(ed + (size_t)d * 2);
    int beg = ofs[d], end = ofs[d + 1];
    int deg = end - beg;
    int jmax = deg < 32 ? deg : 32;

    int s0i = 0, s1i = 0;
    float ex00 = 0.f, ex01 = 0.f, ex10 = 0.f, ex11 = 0.f;
    int i0 = beg + lane, i1 = beg + lane + 16;
    if (i0 < end) {
        s0i = sperm[i0];
        float2 e = *reinterpret_cast<const float2*>(es + (size_t)s0i * 2);
        ex00 = __expf(lrelu_f(e.x + edv.x));
        ex01 = __expf(lrelu_f(e.y + edv.y));
    }
    if (i1 < end) {
        s1i = sperm[i1];
        float2 e = *reinterpret_cast<const float2*>(es + (size_t)s1i * 2);
        ex10 = __expf(lrelu_f(e.x + edv.x));
        ex11 = __expf(lrelu_f(e.y + edv.y));
    }
    float s0 = ex00 + ex10, s1 = ex01 + ex11;
    for (int i = i0 + 32; i < end; i += 16) {   // rare: deg > 32
        int s = sperm[i];
        float2 e = *reinterpret_cast<const float2*>(es + (size_t)s * 2);
        s0 += __expf(lrelu_f(e.x + edv.x));
        s1 += __expf(lrelu_f(e.y + edv.y));
    }
    s0 = quarterReduceSum(s0);
    s1 = quarterReduceSum(s1);
    float r0 = 0.5f / (s0 + GAT_EPS), r1 = 0.5f / (s1 + GAT_EPS);
    if (lane < jmax)
        meta[q][lane] = make_uint2((unsigned int)s0i, pack_half2(ex00 * r0, ex01 * r1));
    if (lane + 16 < jmax)
        meta[q][lane + 16] = make_uint2((unsigned int)s1i, pack_half2(ex10 * r0, ex11 * r1));
    // quarter-internal LDS write->read within one wave; compiler inserts lgkmcnt wait

    // lane covers channels 4*lane .. 4*lane+3 (heads interleaved in h1)
    float a0 = 0.f, a1 = 0.f, a2 = 0.f, a3 = 0.f;
    int j = 0;
    for (; j + 8 <= jmax; j += 8) {
        uint4 vv[8];
        #pragma unroll
        for (int k = 0; k < 8; ++k) vv[k] = h1v[(size_t)meta[q][j + k].x * 16 + lane];
        #pragma unroll
        for (int k = 0; k < 8; ++k) {
            unsigned int my = meta[q][j + k].y;
            a0 = fdot2f(vv[k].x, my, a0);
            a1 = fdot2f(vv[k].y, my, a1);
            a2 = fdot2f(vv[k].z, my, a2);
            a3 = fdot2f(vv[k].w, my, a3);
        }
    }
    for (; j + 4 <= jmax; j += 4) {
        uint4 vv[4];
        #pragma unroll
        for (int k = 0; k < 4; ++k) vv[k] = h1v[(size_t)meta[q][j + k].x * 16 + lane];
        #pragma unroll
        for (int k = 0; k < 4; ++k) {
            unsigned int my = meta[q][j + k].y;
            a0 = fdot2f(vv[k].x, my, a0);
            a1 = fdot2f(vv[k].y, my, a1);
            a2 = fdot2f(vv[k].z, my, a2);
            a3 = fdot2f(vv[k].w, my, a3);
        }
    }
    for (; j < jmax; ++j) {
        uint2 m = meta[q][j];
        uint4 v = h1v[(size_t)m.x * 16 + lane];
        a0 = fdot2f(v.x, m.y, a0);
        a1 = fdot2f(v.y, m.y, a1);
        a2 = fdot2f(v.z, m.y, a2);
        a3 = fdot2f(v.w, m.y, a3);
    }
    for (int i = beg + 32; i < end; ++i) {      // rare: deg > 32
        int s = sperm[i];
        float2 e = *reinterpret_cast<const float2*>(es + (size_t)s * 2);
        float w0 = __expf(lrelu_f(e.x + edv.x)) * r0;
        float w1 = __expf(lrelu_f(e.y + edv.y)) * r1;
        unsigned int ap = pack_half2(w0, w1);
        uint4 v = h1v[(size_t)s * 16 + lane];
        a0 = fdot2f(v.x, ap, a0);
        a1 = fdot2f(v.y, ap, a1);
        a2 = fdot2f(v.z, ap, a2);
        a3 = fdot2f(v.w, ap, a3);
    }
    float4 bv = reinterpret_cast<const float4*>(b1)[lane];
    float o0 = elu_f(a0 + bv.x);
    float o1 = elu_f(a1 + bv.y);
    float o2 = elu_f(a2 + bv.z);
    float o3 = elu_f(a3 + bv.w);
    g1h[(size_t)d * 16 + lane] = make_uint2(pack_half2(o0, o1), pack_half2(o2, o3));
    // layer-2 attention scalars (fp32, same numerics as fp32 g1 path)
    float4 wa0 = reinterpret_cast<const float4*>(wa2)[lane];
    float4 wa1v = reinterpret_cast<const float4*>(wa2)[16 + lane];
    float4 wd0 = reinterpret_cast<const float4*>(wd2)[lane];
    float4 wd1v = reinterpret_cast<const float4*>(wd2)[16 + lane];
    float p0 = o0 * wa0.x + o1 * wa0.y + o2 * wa0.z + o3 * wa0.w;
    float p1 = o0 * wa1v.x + o1 * wa1v.y + o2 * wa1v.z + o3 * wa1v.w;
    float q0 = o0 * wd0.x + o1 * wd0.y + o2 * wd0.z + o3 * wd0.w;
    float q1 = o0 * wd1v.x + o1 * wd1v.y + o2 * wd1v.z + o3 * wd1v.w;
    p0 = quarterReduceSum(p0);
    p1 = quarterReduceSum(p1);
    q0 = quarterReduceSum(q0);
    q1 = quarterReduceSum(q1);
    if (lane == 0) {
        es2[(size_t)d * 2]     = p0;
        es2[(size_t)d * 2 + 1] = p1;
        ed2[(size_t)d * 2]     = q0;
        ed2[(size_t)d * 2 + 1] = q1;
    }
}

// ---------------- aggregation layer2 (fp8 h2, permuted rows) + fused block-level pool ----------------
// Row layout: pos p holds channel col = (p&15)*16 + (p>>4). Lane reads p = 8*lane..8*lane+7:
//   r = lane>>1 (all 8), nf_i = (lane&1)*8+i, col_i = nf_i*16+r, head = (lane>>1)&1 (fixed!),
//   o_i = col_i>>1 = nf_i*8 + (lane>>2). Head-combine partner = lane^2.
__global__ __launch_bounds__(256) void gat_agg2(
        const int* __restrict__ ofs, const int* __restrict__ sperm,
        const float* __restrict__ es, const float* __restrict__ ed,
        const uint2* __restrict__ h8v, const float* __restrict__ b2,
        const int* __restrict__ batch, float* __restrict__ sums, int N) {
    __shared__ uint2 meta[8][32];
    __shared__ float louts[8 * 128];
    __shared__ int lbat[8];
    int half = threadIdx.x >> 5;
    int d = blockIdx.x * 8 + half;
    int lane = threadIdx.x & 31;
    bool active = d < N;                 // uniform per half; NO early return (barrier below)
    int beg = 0, end = 0;
    if (active) {
        beg = ofs[d]; end = ofs[d + 1];
        if (lane == 0) lbat[half] = batch[d];
    } else if (lane == 0) {
        lbat[half] = -1;
    }
    float2 edv = active ? *reinterpret_cast<const float2*>(ed + (size_t)d * 2)
                        : make_float2(0.f, 0.f);
    int deg = end - beg;
    int jmax = deg < 32 ? deg : 32;

    int s_f = 0;
    float ex0 = 0.f, ex1 = 0.f;
    int i0 = beg + lane;
    if (i0 < end) {
        s_f = sperm[i0];
        float2 esv = *reinterpret_cast<const float2*>(es + (size_t)s_f * 2);
        ex0 = __expf(lrelu_f(esv.x + edv.x));
        ex1 = __expf(lrelu_f(esv.y + edv.y));
    }
    float s0 = ex0, s1 = ex1;
    for (int i = i0 + 32; i < end; i += 32) {  // rare: deg > 32
        int s = sperm[i];
        float2 esv = *reinterpret_cast<const float2*>(es + (size_t)s * 2);
        s0 += __expf(lrelu_f(esv.x + edv.x));
        s1 += __expf(lrelu_f(esv.y + edv.y));
    }
    s0 = halfReduceSum(s0);
    s1 = halfReduceSum(s1);
    float r0 = 0.5f / (s0 + GAT_EPS), r1 = 0.5f / (s1 + GAT_EPS);
    if (lane < jmax)
        meta[half][lane] = make_uint2((unsigned int)s_f, pack_half2(ex0 * r0, ex1 * r1));

    int head = (lane >> 1) & 1;          // fixed per lane under the permuted layout
    float acc[8];
    #pragma unroll
    for (int i = 0; i < 8; ++i) acc[i] = 0.f;

    int j = 0;
    for (; j + 8 <= jmax; j += 8) {
        uint2 vv[8];
        #pragma unroll
        for (int k = 0; k < 8; ++k) vv[k] = h8v[(size_t)meta[half][j + k].x * 32 + lane];
        #pragma unroll
        for (int k = 0; k < 8; ++k) {
            __half2 ah = __builtin_bit_cast(__half2, meta[half][j + k].y);
            float2 af = __half22float2(ah);
            float av = head ? af.y : af.x;
            f32x2 f01 = fp8x2_to_f32<false>(vv[k].x);
            f32x2 f23 = fp8x2_to_f32<true>(vv[k].x);
            f32x2 f45 = fp8x2_to_f32<false>(vv[k].y);
            f32x2 f67 = fp8x2_to_f32<true>(vv[k].y);
            acc[0] = fmaf(av, f01[0], acc[0]);
            acc[1] = fmaf(av, f01[1], acc[1]);
            acc[2] = fmaf(av, f23[0], acc[2]);
            acc[3] = fmaf(av, f23[1], acc[3]);
            acc[4] = fmaf(av, f45[0], acc[4]);
            acc[5] = fmaf(av, f45[1], acc[5]);
            acc[6] = fmaf(av, f67[0], acc[6]);
            acc[7] = fmaf(av, f67[1], acc[7]);
        }
    }
    for (; j < jmax; ++j) {
        uint2 v = h8v[(size_t)meta[half][j].x * 32 + lane];
        __half2 ah = __builtin_bit_cast(__half2, meta[half][j].y);
        float2 af = __half22float2(ah);
        float av = head ? af.y : af.x;
        f32x2 f01 = fp8x2_to_f32<false>(v.x);
        f32x2 f23 = fp8x2_to_f32<true>(v.x);
        f32x2 f45 = fp8x2_to_f32<false>(v.y);
        f32x2 f67 = fp8x2_to_f32<true>(v.y);
        acc[0] = fmaf(av, f01[0], acc[0]);
        acc[1] = fmaf(av, f01[1], acc[1]);
        acc[2] = fmaf(av, f23[0], acc[2]);
        acc[3] = fmaf(av, f23[1], acc[3]);
        acc[4] = fmaf(av, f45[0], acc[4]);
        acc[5] = fmaf(av, f45[1], acc[5]);
        acc[6] = fmaf(av, f67[0], acc[6]);
        acc[7] = fmaf(av, f67[1], acc[7]);
    }
    for (int i = beg + 32; i < end; ++i) {  // rare: deg > 32
        int s = sperm[i];
        float2 esv = *reinterpret_cast<const float2*>(es + (size_t)s * 2);
        float a0 = __expf(lrelu_f(esv.x + edv.x)) * r0;
        float a1 = __expf(lrelu_f(esv.y + edv.y)) * r1;
        float av = head ? a1 : a0;
        uint2 v = h8v[(size_t)s * 32 + lane];
        f32x2 f01 = fp8x2_to_f32<false>(v.x);
        f32x2 f23 = fp8x2_to_f32<true>(v.x);
        f32x2 f45 = fp8x2_to_f32<false>(v.y);
        f32x2 f67 = fp8x2_to_f32<true>(v.y);
        acc[0] = fmaf(av, f01[0], acc[0]);
        acc[1] = fmaf(av, f01[1], acc[1]);
        acc[2] = fmaf(av, f23[0], acc[2]);
        acc[3] = fmaf(av, f23[1], acc[3]);
        acc[4] = fmaf(av, f45[0], acc[4]);
        acc[5] = fmaf(av, f45[1], acc[5]);
        acc[6] = fmaf(av, f67[0], acc[6]);
        acc[7] = fmaf(av, f67[1], acc[7]);
    }
    // head-combine: lane^2 holds the other head of the same o-channels
    #pragma unroll
    for (int i = 0; i < 8; ++i) acc[i] += __shfl_xor(acc[i], 2, 64);
    if (head == 0) {
        int jch = lane >> 2;             // 0..7
        int nfb = (lane & 1) * 8;
        #pragma unroll
        for (int i = 0; i < 8; ++i) {
            int o = (nfb + i) * 8 + jch;
            louts[half * 128 + o] = active ? elu_f(acc[i] + b2[o]) : 0.f;
        }
    }
    __syncthreads();
    // run-length merge of the block's 8 nodes (batch sorted -> 1-2 runs/block)
    if (threadIdx.x < 128) {
        int c = threadIdx.x;
        int cur = lbat[0];
        float a = 0.f;
        #pragma unroll
        for (int n = 0; n < 8; ++n) {
            int b = lbat[n];
            if (b != cur) {
                if (cur >= 0) atomicAdd(&sums[(size_t)cur * 128 + c], a);
                a = 0.f; cur = b;
            }
            a += louts[n * 128 + c];
        }
        if (cur >= 0) atomicAdd(&sums[(size_t)cur * 128 + c], a);
    }
}

// ---------------- final: out = (sums/cnt) @ lo_w + lo_b ----------------
__global__ void final_kernel(
        const float* __restrict__ sums, const float* __restrict__ cnts,
        const float* __restrict__ w, const float* __restrict__ b,
        float* __restrict__ out, int G) {
    int g = blockIdx.x;
    int k = threadIdx.x;
    if (k >= 24) return;
    float inv = 1.f / fmaxf(cnts[g], 1.f);
    float acc = b[k];
    #pragma unroll
    for (int c = 0; c < 128; ++c) acc = fmaf(sums[g * 128 + c] * inv, w[c * 24 + k], acc);
    out[g * 24 + k] = acc;
}

extern "C" void kernel_launch(void* const* d_in, const int* in_sizes, int n_in,
                              void* d_out, int out_size, void* d_ws, size_t ws_size,
                              hipStream_t stream) {
    const float* x      = (const float*)d_in[0];
    const int*   ei     = (const int*)d_in[1];
    const int*   batch  = (const int*)d_in[2];
    const float* fc0_w  = (const float*)d_in[3];
    const float* fc0_b  = (const float*)d_in[4];
    const float* W1     = (const float*)d_in[5];
    const float* a_src1 = (const float*)d_in[6];
    const float* a_dst1 = (const float*)d_in[7];
    const float* b1     = (const float*)d_in[8];
    const float* W2     = (const float*)d_in[9];
    const float* a_src2 = (const float*)d_in[10];
    const float* a_dst2 = (const float*)d_in[11];
    const float* b2     = (const float*)d_in[12];
    const float* lo_w   = (const float*)d_in[13];
    const float* lo_b   = (const float*)d_in[14];
    float* out = (float*)d_out;

    const int N = in_sizes[0] / 16;
    const int E = in_sizes[1] / 2;
    const int G = out_size / 24;
    const int* src = ei;
    const int* dst = ei + E;
    const int nb = (N + 255) / 256;

    char* wsb = (char*)d_ws;
    size_t off = 0;
    auto allocf = [&](size_t n) { float* p = (float*)(wsb + off); off += ((n * 4 + 255) & ~(size_t)255); return p; };
    auto alloci = [&](size_t n) { int* p = (int*)(wsb + off); off += ((n * 4 + 255) & ~(size_t)255); return p; };
    auto alloch = [&](size_t n) { __half* p = (__half*)(wsb + off); off += ((n * 2 + 255) & ~(size_t)255); return p; };
    __half* hbuf  = alloch((size_t)N * 256);        // h1: N*128 halves; h8 (fp8): first N*256 bytes
    __half* g1h   = alloch((size_t)(N + 64) * 64);  // fp16 g1 (padded for 64-node GEMM blocks)
    __half* w2t   = alloch(16384);                  // W2 transposed [256][64] fp16
    float*  es    = allocf((size_t)N * 2);
    float*  ed    = allocf((size_t)N * 2);
    float*  es2   = allocf((size_t)N * 2);
    float*  ed2   = allocf((size_t)N * 2);
    float*  sums  = allocf((size_t)G * 128);
    float*  cnts  = allocf((size_t)G);
    float*  wa1   = allocf(64);
    float*  wd1   = allocf(64);
    float*  wa2   = allocf(128);
    float*  wd2   = allocf(128);
    int* deg     = alloci((size_t)N);
    int* ofs     = alloci((size_t)N + 1);
    int* cursor  = alloci((size_t)N);
    int* sperm   = alloci((size_t)E);
    int* bsum    = alloci((size_t)nb);
    int* bofs    = alloci((size_t)nb);
    (void)ws_size;

    // init (+ W2T build + folded attention vectors) + CSR build
    init_kernel<<<(N + 255) / 256, 256, 0, stream>>>(deg, sums, cnts, N, G,
            W1, a_src1, a_dst1, W2, a_src2, a_dst2, wa1, wd1, wa2, wd2, w2t);
    hist_kernel<<<(E + 255) / 256, 256, 0, stream>>>(dst, deg, E);
    scan_blocks_kernel<<<nb, 256, 0, stream>>>(deg, ofs, bsum, N);
    scan_bsum_kernel<<<1, 1024, 0, stream>>>(bsum, bofs, ofs + N, nb);
    scan_add_kernel<<<nb, 256, 0, stream>>>(ofs, bofs, cursor, batch, cnts, N);
    scatter_kernel<<<(E + 255) / 256, 256, 0, stream>>>(src, dst, cursor, sperm, E);

    // ---- GAT layer 1 (fc0 fused into transform; layer-2 attn scalars fused into agg) ----
    fused_t1<<<(N + 7) / 8, 256, 0, stream>>>(x, fc0_w, fc0_b, W1, wa1, wd1, hbuf, es, ed, N);
    gat_agg1<<<(N + 15) / 16, 256, 0, stream>>>(ofs, sperm, es, ed, (const uint4*)hbuf, b1,
            wa2, wd2, (uint2*)g1h, es2, ed2, N);

    // ---- GAT layer 2 (MFMA transform -> fp8 permuted h2; pool fused into aggregation) ----
    t2_mfma<<<(N + 63) / 64, 256, 0, stream>>>(g1h, w2t, (unsigned char*)hbuf, N);
    gat_agg2<<<(N + 7) / 8, 256, 0, stream>>>(ofs, sperm, es2, ed2, (const uint2*)hbuf, b2,
            batch, sums, N);

    // ---- final linear ----
    final_kernel<<<G, 32, 0, stream>>>(sums, cnts, lo_w, lo_b, out, G);
}

// Round 9
// 300.448 us; speedup vs baseline: 1.5828x; 1.0974x over previous
//
#include <hip/hip_runtime.h>
#include <hip/hip_fp16.h>
#include <math.h>

#define NEG_SLOPE 0.2f
#define GAT_EPS 1e-16f
#define EPB 4096   // edges per block in bucket passes

__device__ __forceinline__ float elu_f(float x) { return x > 0.f ? x : expm1f(x); }
__device__ __forceinline__ float lrelu_f(float x) { return x > 0.f ? x : NEG_SLOPE * x; }

typedef _Float16 half2v __attribute__((ext_vector_type(2)));
typedef _Float16 half8 __attribute__((ext_vector_type(8)));
typedef float f32x4 __attribute__((ext_vector_type(4)));
typedef float f32x2 __attribute__((ext_vector_type(2)));

// fp32 accumulate of half2 dot: acc += v.x*a.x + v.y*a.y
__device__ __forceinline__ float fdot2f(unsigned int v, unsigned int a, float acc) {
#if __has_builtin(__builtin_amdgcn_fdot2)
    return __builtin_amdgcn_fdot2(__builtin_bit_cast(half2v, v),
                                  __builtin_bit_cast(half2v, a), acc, false);
#else
    __half2 hv = __builtin_bit_cast(__half2, v);
    __half2 ha = __builtin_bit_cast(__half2, a);
    float2 fv = __half22float2(hv), fa = __half22float2(ha);
    return fmaf(fv.x, fa.x, fmaf(fv.y, fa.y, acc));
#endif
}

__device__ __forceinline__ unsigned int pack_half2(float a, float b) {
    __half2 h = __floats2half2_rn(a, b);
    return __builtin_bit_cast(unsigned int, h);
}

// ---- fp8 e4m3 (gfx950 HW converts; slow software fallback for other targets) ----
#if __has_builtin(__builtin_amdgcn_cvt_pk_fp8_f32) && __has_builtin(__builtin_amdgcn_cvt_pk_f32_fp8)
#define HW_FP8 1
#endif

__device__ __forceinline__ unsigned int pack_fp8x4(float a, float b, float c, float d) {
#ifdef HW_FP8
    int r = 0;
    r = __builtin_amdgcn_cvt_pk_fp8_f32(a, b, r, false);
    r = __builtin_amdgcn_cvt_pk_fp8_f32(c, d, r, true);
    return (unsigned int)r;
#else
    auto enc = [](float x) -> unsigned int {
        if (x != x) return 0x7f;
        float ax = fabsf(x);
        unsigned int s = x < 0.f ? 0x80u : 0u;
        if (ax < 0.001953125f) {
            int m = (int)(ax * 512.f + 0.5f);
            if (m > 7) m = 7;
            return s | (unsigned int)m;
        }
        if (ax >= 448.f) return s | 0x7e;
        int e; float fr = frexpf(ax, &e);
        int m = (int)(fr * 16.f + 0.5f);
        if (m == 16) { m = 8; e += 1; }
        return s | ((unsigned int)(e + 6) << 3) | (unsigned int)(m - 8);
    };
    return enc(a) | (enc(b) << 8) | (enc(c) << 16) | (enc(d) << 24);
#endif
}

template <bool HI>
__device__ __forceinline__ f32x2 fp8x2_to_f32(unsigned int v) {
#ifdef HW_FP8
    return __builtin_amdgcn_cvt_pk_f32_fp8((int)v, HI);
#else
    auto dec = [](unsigned int b) -> float {
        float s = (b & 0x80) ? -1.f : 1.f;
        int e = (b >> 3) & 0xF, m = b & 7;
        if (e == 0) return s * (float)m * 0.001953125f;
        return s * (8.f + (float)m) * exp2f((float)(e - 10));
    };
    unsigned int sh = HI ? 16 : 0;
    f32x2 r;
    r[0] = dec((v >> sh) & 0xFF);
    r[1] = dec((v >> (sh + 8)) & 0xFF);
    return r;
#endif
}

__device__ __forceinline__ float halfReduceSum(float v) {
    #pragma unroll
    for (int off = 16; off > 0; off >>= 1) v += __shfl_xor(v, off, 64);
    return v;
}
__device__ __forceinline__ float quarterReduceSum(float v) {
    #pragma unroll
    for (int off = 8; off > 0; off >>= 1) v += __shfl_xor(v, off, 64);
    return v;
}

// ---------------- init: zero sums/cnts; block1 builds W2T fp16; last block folds attn vectors ----------------
__global__ void init_kernel(float* sums, float* cnts, int N, int G,
        const float* __restrict__ W1, const float* __restrict__ as1, const float* __restrict__ ad1,
        const float* __restrict__ W2, const float* __restrict__ as2, const float* __restrict__ ad2,
        float* __restrict__ wa1, float* __restrict__ wd1,
        float* __restrict__ wa2, float* __restrict__ wd2,
        __half* __restrict__ w2t) {
    int i = blockIdx.x * 256 + threadIdx.x;
    if (i < G * 128) sums[i] = 0.f;
    if (i < G) cnts[i] = 0.f;
    if (blockIdx.x == 1) {
        // W2T[c2][k] = W2[h=c2&1][k][o=c2>>1], fp16, [256][64]
        for (int idx = threadIdx.x; idx < 16384; idx += 256) {
            int c2 = idx >> 6, k = idx & 63;
            w2t[idx] = __float2half(W2[(c2 & 1) * 8192 + k * 128 + (c2 >> 1)]);
        }
    }
    if (blockIdx.x == gridDim.x - 1) {
        int t = threadIdx.x;
        if (t < 64) {                      // layer1: h=t>>5, c=t&31
            int h = t >> 5, c = t & 31;
            const float* w = W1 + (h * 32 + c) * 64;
            float sa = 0.f, sd = 0.f;
            for (int o = 0; o < 64; ++o) {
                sa = fmaf(w[o], as1[h * 64 + o], sa);
                sd = fmaf(w[o], ad1[h * 64 + o], sd);
            }
            wa1[t] = sa; wd1[t] = sd;
        } else if (t < 192) {              // layer2: u=t-64, h=u>>6, c=u&63
            int u = t - 64, h = u >> 6, c = u & 63;
            const float* w = W2 + (h * 64 + c) * 128;
            float sa = 0.f, sd = 0.f;
            for (int o = 0; o < 128; ++o) {
                sa = fmaf(w[o], as2[h * 128 + o], sa);
                sd = fmaf(w[o], ad2[h * 128 + o], sd);
            }
            wa2[u] = sa; wd2[u] = sd;
        }
    }
}

// ---------------- CSR build: LDS-binned two-level counting sort (no global atomics) ----------------
// Coarse bucket = dst>>8 (NB = ceil(N/256) <= 256 buckets).

// pass A: per-block LDS histogram of coarse buckets
__global__ __launch_bounds__(256) void bucket_hist(
        const int* __restrict__ dst, int* __restrict__ bhist,
        int NB, int nbl, int E) {
    __shared__ int lh[256];
    int tid = threadIdx.x;
    lh[tid] = 0;
    __syncthreads();
    int base = blockIdx.x * EPB;
    int lim = E - base; if (lim > EPB) lim = EPB;
    for (int k = tid; k < lim; k += 256)
        atomicAdd(&lh[(unsigned)dst[base + k] >> 8], 1);
    __syncthreads();
    if (tid < NB) bhist[(size_t)tid * nbl + blockIdx.x] = lh[tid];   // bin-major
}

// pass B (1 block, 1024 thr): bucket starts + per-(bin,block) base offsets (in place)
__global__ __launch_bounds__(1024) void bucket_scan(
        int* __restrict__ bhist, int* __restrict__ bstart,
        int* __restrict__ ofsN, int NB, int nbl, int E) {
    __shared__ int stot[256];
    __shared__ int sbs[256];
    int tid = threadIdx.x, lane = tid & 63, wid = tid >> 6;
    if (tid < 256) {                       // bucket totals
        int t = 0;
        if (tid < NB) {
            const int* p = bhist + (size_t)tid * nbl;
            for (int b = 0; b < nbl; ++b) t += p[b];
        }
        stot[tid] = t;
    }
    __syncthreads();
    if (tid < 64) {                        // exclusive scan of 256 totals (wave 0)
        int carry = 0;
        for (int c = 0; c < 256; c += 64) {
            int v = stot[c + lane];
            int incl = v;
            #pragma unroll
            for (int off = 1; off < 64; off <<= 1) {
                int t = __shfl_up(incl, off, 64);
                if (lane >= off) incl += t;
            }
            sbs[c + lane] = incl - v + carry;
            carry += __shfl(incl, 63, 64);
        }
    }
    __syncthreads();
    if (tid < NB) bstart[tid] = sbs[tid];
    if (tid == 0) { bstart[NB] = E; *ofsN = E; }
    // per-bucket exclusive scan over blocks, + bucket start (in place)
    for (int bin = wid; bin < NB; bin += 16) {
        int carry = sbs[bin];
        int* p = bhist + (size_t)bin * nbl;
        for (int c = 0; c < nbl; c += 64) {
            int idx = c + lane;
            int v = (idx < nbl) ? p[idx] : 0;
            int incl = v;
            #pragma unroll
            for (int off = 1; off < 64; off <<= 1) {
                int t = __shfl_up(incl, off, 64);
                if (lane >= off) incl += t;
            }
            if (idx < nbl) p[idx] = incl - v + carry;
            carry += __shfl(incl, 63, 64);
        }
    }
}

// pass C: scatter (src,dst) pairs into coarse-bucket-grouped ebuf via LDS cursors
__global__ __launch_bounds__(256) void bucket_scatter(
        const int* __restrict__ src, const int* __restrict__ dst,
        const int* __restrict__ bhist, uint2* __restrict__ ebuf,
        int NB, int nbl, int E) {
    __shared__ int lc[256];
    int tid = threadIdx.x;
    if (tid < NB) lc[tid] = bhist[(size_t)tid * nbl + blockIdx.x];
    __syncthreads();
    int base = blockIdx.x * EPB;
    int lim = E - base; if (lim > EPB) lim = EPB;
    for (int k = tid; k < lim; k += 256) {
        int d = dst[base + k];
        int s = src[base + k];
        int pos = atomicAdd(&lc[(unsigned)d >> 8], 1);
        ebuf[pos] = make_uint2((unsigned)s, (unsigned)d);
    }
}

// pass D: one block per bucket -> fine hist (deg), scan (ofs), LDS-cursor scatter (sperm), cnts
__global__ __launch_bounds__(256) void bucket_csr(
        const uint2* __restrict__ ebuf, const int* __restrict__ bstart,
        const int* __restrict__ batch, float* __restrict__ cnts,
        int* __restrict__ ofs, int* __restrict__ sperm, int N) {
    __shared__ int fh[256];
    __shared__ int wtot[4];
    __shared__ int lc[256];
    int bin = blockIdx.x;
    int tid = threadIdx.x, lane = tid & 63, wid = tid >> 6;
    int ebeg = bstart[bin], eend = bstart[bin + 1];
    fh[tid] = 0;
    __syncthreads();
    for (int i = ebeg + tid; i < eend; i += 256)
        atomicAdd(&fh[ebuf[i].y & 255], 1);
    __syncthreads();
    // exclusive scan of fh (256 values, 4 waves)
    int v = fh[tid];
    int incl = v;
    #pragma unroll
    for (int off = 1; off < 64; off <<= 1) {
        int t = __shfl_up(incl, off, 64);
        if (lane >= off) incl += t;
    }
    if (lane == 63) wtot[wid] = incl;
    __syncthreads();
    int woff = 0;
    #pragma unroll
    for (int w = 0; w < 4; ++w) if (w < wid) woff += wtot[w];
    int excl = incl - v + woff;
    int d = (bin << 8) + tid;
    if (d < N) ofs[d] = ebeg + excl;
    lc[tid] = excl;
    // graph node-counts (batch sorted; ballot trick, contiguous node range)
    if (d < N) {
        int b = batch[d];
        int b0 = __shfl(b, 0, 64);
        if (__all(b == b0)) {
            unsigned long long m = __ballot(1);
            if (lane == 0) atomicAdd(&cnts[b], (float)__popcll(m));
        } else {
            atomicAdd(&cnts[b], 1.f);
        }
    }
    __syncthreads();
    for (int i = ebeg + tid; i < eend; i += 256) {
        uint2 e = ebuf[i];
        int pos = atomicAdd(&lc[e.y & 255], 1);
        sperm[ebeg + pos] = (int)e.x;
    }
}

// ---------------- fused fc0 + GAT layer1 transform (8 nodes/block; W1 staged in LDS) ----------------
__global__ __launch_bounds__(256) void fused_t1(
        const float* __restrict__ x, const float* __restrict__ w0,
        const float* __restrict__ b0, const float* __restrict__ W1,
        const float* __restrict__ wa1, const float* __restrict__ wd1,
        __half* __restrict__ h1, float* __restrict__ es, float* __restrict__ ed, int N) {
    __shared__ float xs[8 * 16];
    __shared__ float hs[8 * 32];
    __shared__ float ws[4096];       // W1 (2*32*64 floats = 16KB)
    int n0 = blockIdx.x * 8;
    int tid = threadIdx.x;
    {   // stage W1 once per block (coalesced float4)
        const float4* wv4 = reinterpret_cast<const float4*>(W1);
        float4* ws4 = reinterpret_cast<float4*>(ws);
        #pragma unroll
        for (int i = 0; i < 4; ++i) ws4[tid + i * 256] = wv4[tid + i * 256];
    }
    if (tid < 128) {
        int gi = n0 * 16 + tid;
        xs[tid] = (gi < N * 16) ? x[gi] : 0.f;
    }
    __syncthreads();
    {
        int j = tid >> 5, o = tid & 31;
        float acc = b0[o];
        #pragma unroll
        for (int c = 0; c < 16; ++c) acc = fmaf(xs[j * 16 + c], w0[c * 32 + o], acc);
        hs[j * 32 + o] = elu_f(acc);
    }
    __syncthreads();
    int o = tid & 63, h = (tid >> 6) & 1, nh = tid >> 7;
    float acc[4];
    #pragma unroll
    for (int j = 0; j < 4; ++j) acc[j] = 0.f;
    const float* wp = ws + h * 2048 + o;
    #pragma unroll
    for (int c = 0; c < 32; ++c) {
        float wv = wp[c * 64];
        #pragma unroll
        for (int j = 0; j < 4; ++j) acc[j] = fmaf(hs[(nh * 4 + j) * 32 + c], wv, acc[j]);
    }
    #pragma unroll
    for (int j = 0; j < 4; ++j) {
        int n = n0 + nh * 4 + j;
        if (n < N) h1[(size_t)n * 128 + 2 * o + h] = __float2half(acc[j]);
    }
    if (tid < 32) {
        int n = tid >> 2, r = tid & 3, hh = r >> 1, isd = r & 1;
        const float* wv = (isd ? wd1 : wa1) + hh * 32;
        float s = 0.f;
        #pragma unroll
        for (int c = 0; c < 32; ++c) s = fmaf(hs[n * 32 + c], wv[c], s);
        int nn = n0 + n;
        if (nn < N) { if (isd) ed[nn * 2 + hh] = s; else es[nn * 2 + hh] = s; }
    }
}

// ---------------- GAT layer2 transform: MFMA GEMM [N x 64] @ [64 x 256], fp8 output ----------------
// Output h8[node][pos] fp8, PERMUTED: pos = r*16+nf holds channel col = nf*16+r.
__global__ __launch_bounds__(256) void t2_mfma(
        const __half* __restrict__ g1h,   // [Npad][64] fp16
        const __half* __restrict__ w2t,   // [256][64] fp16
        unsigned char* __restrict__ h8, int N) {
    __shared__ __half sbuf[16384];   // 32KB: B operand, XOR-swizzled
    int tid = threadIdx.x;
    {   // stage B: 2048 uint4, XOR-swizzled (row = 128B = 8 uint4)
        const uint4* srcv = reinterpret_cast<const uint4*>(w2t);
        #pragma unroll
        for (int i = 0; i < 8; ++i) {
            int idx = tid + i * 256;
            int row = idx >> 3;
            int byteoff = (idx * 16) ^ ((row & 7) << 4);
            *reinterpret_cast<uint4*>(reinterpret_cast<char*>(sbuf) + byteoff) = srcv[idx];
        }
    }
    __syncthreads();
    int w = tid >> 6, lane = tid & 63;
    int r = lane & 15, kg = lane >> 4;
    int nodei = blockIdx.x * 64 + w * 16 + r;
    const half8* ap = reinterpret_cast<const half8*>(
        reinterpret_cast<const _Float16*>(g1h) + (size_t)nodei * 64 + kg * 8);

    f32x4 acc[16];
    #pragma unroll
    for (int nf = 0; nf < 16; ++nf) acc[nf] = f32x4{0.f, 0.f, 0.f, 0.f};
    half8 az = {};
    #pragma unroll
    for (int ks = 0; ks < 2; ++ks) {
        half8 a = (nodei < N) ? ap[ks * 4] : az;
        #pragma unroll
        for (int nf = 0; nf < 16; ++nf) {
            int brow = nf * 16 + r;
            int bbyte = (brow * 128 + ks * 64 + kg * 16) ^ ((brow & 7) << 4);
            half8 b = *reinterpret_cast<const half8*>(reinterpret_cast<const char*>(sbuf) + bbyte);
            acc[nf] = __builtin_amdgcn_mfma_f32_16x16x32_f16(a, b, acc[nf], 0, 0, 0);
        }
    }
    #pragma unroll
    for (int q = 0; q < 4; ++q) {
        int n = blockIdx.x * 64 + w * 16 + kg * 4 + q;
        if (n < N) {
            uint4 pk;
            pk.x = pack_fp8x4(acc[0][q],  acc[1][q],  acc[2][q],  acc[3][q]);
            pk.y = pack_fp8x4(acc[4][q],  acc[5][q],  acc[6][q],  acc[7][q]);
            pk.z = pack_fp8x4(acc[8][q],  acc[9][q],  acc[10][q], acc[11][q]);
            pk.w = pack_fp8x4(acc[12][q], acc[13][q], acc[14][q], acc[15][q]);
            *reinterpret_cast<uint4*>(h8 + (size_t)n * 256 + r * 16) = pk;
        }
    }
}

// ---------------- aggregation layer1: one QUARTER-WAVE (16 lanes) per dst node, uint4 loads ----------------
__global__ __launch_bounds__(256) void gat_agg1(
        const int* __restrict__ ofs, const int* __restrict__ sperm,
        const float* __restrict__ es, const float* __restrict__ ed,
        const uint4* __restrict__ h1v, const float* __restrict__ b1,
        const float* __restrict__ wa2, const float* __restrict__ wd2,
        uint2* __restrict__ g1h, float* __restrict__ es2, float* __restrict__ ed2, int N) {
    __shared__ uint2 meta[16][32];
    int q = threadIdx.x >> 4;            // 0..15
    int d = blockIdx.x * 16 + q;
    int lane = threadIdx.x & 15;
    bool active = d < N;                 // uniform per quarter
    if (!active) return;                 // no block-wide barrier in this kernel
    float2 edv = *reinterpret_cast<const float2*>(ed + (size_t)d * 2);
    int beg = ofs[d], end = ofs[d + 1];
    int deg = end - beg;
    int jmax = deg < 32 ? deg : 32;

    int s0i = 0, s1i = 0;
    float ex00 = 0.f, ex01 = 0.f, ex10 = 0.f, ex11 = 0.f;
    int i0 = beg + lane, i1 = beg + lane + 16;
    if (i0 < end) {
        s0i = sperm[i0];
        float2 e = *reinterpret_cast<const float2*>(es + (size_t)s0i * 2);
        ex00 = __expf(lrelu_f(e.x + edv.x));
        ex01 = __expf(lrelu_f(e.y + edv.y));
    }
    if (i1 < end) {
        s1i = sperm[i1];
        float2 e = *reinterpret_cast<const float2*>(es + (size_t)s1i * 2);
        ex10 = __expf(lrelu_f(e.x + edv.x));
        ex11 = __expf(lrelu_f(e.y + edv.y));
    }
    float s0 = ex00 + ex10, s1 = ex01 + ex11;
    for (int i = i0 + 32; i < end; i += 16) {   // rare: deg > 32
        int s = sperm[i];
        float2 e = *reinterpret_cast<const float2*>(es + (size_t)s * 2);
        s0 += __expf(lrelu_f(e.x + edv.x));
        s1 += __expf(lrelu_f(e.y + edv.y));
    }
    s0 = quarterReduceSum(s0);
    s1 = quarterReduceSum(s1);
    float r0 = 0.5f / (s0 + GAT_EPS), r1 = 0.5f / (s1 + GAT_EPS);
    if (lane < jmax)
        meta[q][lane] = make_uint2((unsigned int)s0i, pack_half2(ex00 * r0, ex01 * r1));
    if (lane + 16 < jmax)
        meta[q][lane + 16] = make_uint2((unsigned int)s1i, pack_half2(ex10 * r0, ex11 * r1));

    float a0 = 0.f, a1 = 0.f, a2 = 0.f, a3 = 0.f;
    int j = 0;
    for (; j + 8 <= jmax; j += 8) {
        uint4 vv[8];
        #pragma unroll
        for (int k = 0; k < 8; ++k) vv[k] = h1v[(size_t)meta[q][j + k].x * 16 + lane];
        #pragma unroll
        for (int k = 0; k < 8; ++k) {
            unsigned int my = meta[q][j + k].y;
            a0 = fdot2f(vv[k].x, my, a0);
            a1 = fdot2f(vv[k].y, my, a1);
            a2 = fdot2f(vv[k].z, my, a2);
            a3 = fdot2f(vv[k].w, my, a3);
        }
    }
    for (; j + 4 <= jmax; j += 4) {
        uint4 vv[4];
        #pragma unroll
        for (int k = 0; k < 4; ++k) vv[k] = h1v[(size_t)meta[q][j + k].x * 16 + lane];
        #pragma unroll
        for (int k = 0; k < 4; ++k) {
            unsigned int my = meta[q][j + k].y;
            a0 = fdot2f(vv[k].x, my, a0);
            a1 = fdot2f(vv[k].y, my, a1);
            a2 = fdot2f(vv[k].z, my, a2);
            a3 = fdot2f(vv[k].w, my, a3);
        }
    }
    for (; j < jmax; ++j) {
        uint2 m = meta[q][j];
        uint4 v = h1v[(size_t)m.x * 16 + lane];
        a0 = fdot2f(v.x, m.y, a0);
        a1 = fdot2f(v.y, m.y, a1);
        a2 = fdot2f(v.z, m.y, a2);
        a3 = fdot2f(v.w, m.y, a3);
    }
    for (int i = beg + 32; i < end; ++i) {      // rare: deg > 32
        int s = sperm[i];
        float2 e = *reinterpret_cast<const float2*>(es + (size_t)s * 2);
        float w0 = __expf(lrelu_f(e.x + edv.x)) * r0;
        float w1 = __expf(lrelu_f(e.y + edv.y)) * r1;
        unsigned int ap = pack_half2(w0, w1);
        uint4 v = h1v[(size_t)s * 16 + lane];
        a0 = fdot2f(v.x, ap, a0);
        a1 = fdot2f(v.y, ap, a1);
        a2 = fdot2f(v.z, ap, a2);
        a3 = fdot2f(v.w, ap, a3);
    }
    float4 bv = reinterpret_cast<const float4*>(b1)[lane];
    float o0 = elu_f(a0 + bv.x);
    float o1 = elu_f(a1 + bv.y);
    float o2 = elu_f(a2 + bv.z);
    float o3 = elu_f(a3 + bv.w);
    g1h[(size_t)d * 16 + lane] = make_uint2(pack_half2(o0, o1), pack_half2(o2, o3));
    float4 wa0 = reinterpret_cast<const float4*>(wa2)[lane];
    float4 wa1v = reinterpret_cast<const float4*>(wa2)[16 + lane];
    float4 wd0 = reinterpret_cast<const float4*>(wd2)[lane];
    float4 wd1v = reinterpret_cast<const float4*>(wd2)[16 + lane];
    float p0 = o0 * wa0.x + o1 * wa0.y + o2 * wa0.z + o3 * wa0.w;
    float p1 = o0 * wa1v.x + o1 * wa1v.y + o2 * wa1v.z + o3 * wa1v.w;
    float q0 = o0 * wd0.x + o1 * wd0.y + o2 * wd0.z + o3 * wd0.w;
    float q1 = o0 * wd1v.x + o1 * wd1v.y + o2 * wd1v.z + o3 * wd1v.w;
    p0 = quarterReduceSum(p0);
    p1 = quarterReduceSum(p1);
    q0 = quarterReduceSum(q0);
    q1 = quarterReduceSum(q1);
    if (lane == 0) {
        es2[(size_t)d * 2]     = p0;
        es2[(size_t)d * 2 + 1] = p1;
        ed2[(size_t)d * 2]     = q0;
        ed2[(size_t)d * 2 + 1] = q1;
    }
}

// ---------------- aggregation layer2 (fp8 h2, permuted rows) + fused block-level pool ----------------
__global__ __launch_bounds__(256) void gat_agg2(
        const int* __restrict__ ofs, const int* __restrict__ sperm,
        const float* __restrict__ es, const float* __restrict__ ed,
        const uint2* __restrict__ h8v, const float* __restrict__ b2,
        const int* __restrict__ batch, float* __restrict__ sums, int N) {
    __shared__ uint2 meta[8][32];
    __shared__ float louts[8 * 128];
    __shared__ int lbat[8];
    int half = threadIdx.x >> 5;
    int d = blockIdx.x * 8 + half;
    int lane = threadIdx.x & 31;
    bool active = d < N;                 // uniform per half; NO early return (barrier below)
    int beg = 0, end = 0;
    if (active) {
        beg = ofs[d]; end = ofs[d + 1];
        if (lane == 0) lbat[half] = batch[d];
    } else if (lane == 0) {
        lbat[half] = -1;
    }
    float2 edv = active ? *reinterpret_cast<const float2*>(ed + (size_t)d * 2)
                        : make_float2(0.f, 0.f);
    int deg = end - beg;
    int jmax = deg < 32 ? deg : 32;

    int s_f = 0;
    float ex0 = 0.f, ex1 = 0.f;
    int i0 = beg + lane;
    if (i0 < end) {
        s_f = sperm[i0];
        float2 esv = *reinterpret_cast<const float2*>(es + (size_t)s_f * 2);
        ex0 = __expf(lrelu_f(esv.x + edv.x));
        ex1 = __expf(lrelu_f(esv.y + edv.y));
    }
    float s0 = ex0, s1 = ex1;
    for (int i = i0 + 32; i < end; i += 32) {  // rare: deg > 32
        int s = sperm[i];
        float2 esv = *reinterpret_cast<const float2*>(es + (size_t)s * 2);
        s0 += __expf(lrelu_f(esv.x + edv.x));
        s1 += __expf(lrelu_f(esv.y + edv.y));
    }
    s0 = halfReduceSum(s0);
    s1 = halfReduceSum(s1);
    float r0 = 0.5f / (s0 + GAT_EPS), r1 = 0.5f / (s1 + GAT_EPS);
    if (lane < jmax)
        meta[half][lane] = make_uint2((unsigned int)s_f, pack_half2(ex0 * r0, ex1 * r1));

    int head = (lane >> 1) & 1;          // fixed per lane under the permuted layout
    float acc[8];
    #pragma unroll
    for (int i = 0; i < 8; ++i) acc[i] = 0.f;

    int j = 0;
    for (; j + 8 <= jmax; j += 8) {
        uint2 vv[8];
        #pragma unroll
        for (int k = 0; k < 8; ++k) vv[k] = h8v[(size_t)meta[half][j + k].x * 32 + lane];
        #pragma unroll
        for (int k = 0; k < 8; ++k) {
            __half2 ah = __builtin_bit_cast(__half2, meta[half][j + k].y);
            float2 af = __half22float2(ah);
            float av = head ? af.y : af.x;
            f32x2 f01 = fp8x2_to_f32<false>(vv[k].x);
            f32x2 f23 = fp8x2_to_f32<true>(vv[k].x);
            f32x2 f45 = fp8x2_to_f32<false>(vv[k].y);
            f32x2 f67 = fp8x2_to_f32<true>(vv[k].y);
            acc[0] = fmaf(av, f01[0], acc[0]);
            acc[1] = fmaf(av, f01[1], acc[1]);
            acc[2] = fmaf(av, f23[0], acc[2]);
            acc[3] = fmaf(av, f23[1], acc[3]);
            acc[4] = fmaf(av, f45[0], acc[4]);
            acc[5] = fmaf(av, f45[1], acc[5]);
            acc[6] = fmaf(av, f67[0], acc[6]);
            acc[7] = fmaf(av, f67[1], acc[7]);
        }
    }
    for (; j < jmax; ++j) {
        uint2 v = h8v[(size_t)meta[half][j].x * 32 + lane];
        __half2 ah = __builtin_bit_cast(__half2, meta[half][j].y);
        float2 af = __half22float2(ah);
        float av = head ? af.y : af.x;
        f32x2 f01 = fp8x2_to_f32<false>(v.x);
        f32x2 f23 = fp8x2_to_f32<true>(v.x);
        f32x2 f45 = fp8x2_to_f32<false>(v.y);
        f32x2 f67 = fp8x2_to_f32<true>(v.y);
        acc[0] = fmaf(av, f01[0], acc[0]);
        acc[1] = fmaf(av, f01[1], acc[1]);
        acc[2] = fmaf(av, f23[0], acc[2]);
        acc[3] = fmaf(av, f23[1], acc[3]);
        acc[4] = fmaf(av, f45[0], acc[4]);
        acc[5] = fmaf(av, f45[1], acc[5]);
        acc[6] = fmaf(av, f67[0], acc[6]);
        acc[7] = fmaf(av, f67[1], acc[7]);
    }
    for (int i = beg + 32; i < end; ++i) {  // rare: deg > 32
        int s = sperm[i];
        float2 esv = *reinterpret_cast<const float2*>(es + (size_t)s * 2);
        float a0 = __expf(lrelu_f(esv.x + edv.x)) * r0;
        float a1 = __expf(lrelu_f(esv.y + edv.y)) * r1;
        float av = head ? a1 : a0;
        uint2 v = h8v[(size_t)s * 32 + lane];
        f32x2 f01 = fp8x2_to_f32<false>(v.x);
        f32x2 f23 = fp8x2_to_f32<true>(v.x);
        f32x2 f45 = fp8x2_to_f32<false>(v.y);
        f32x2 f67 = fp8x2_to_f32<true>(v.y);
        acc[0] = fmaf(av, f01[0], acc[0]);
        acc[1] = fmaf(av, f01[1], acc[1]);
        acc[2] = fmaf(av, f23[0], acc[2]);
        acc[3] = fmaf(av, f23[1], acc[3]);
        acc[4] = fmaf(av, f45[0], acc[4]);
        acc[5] = fmaf(av, f45[1], acc[5]);
        acc[6] = fmaf(av, f67[0], acc[6]);
        acc[7] = fmaf(av, f67[1], acc[7]);
    }
    // head-combine: lane^2 holds the other head of the same o-channels
    #pragma unroll
    for (int i = 0; i < 8; ++i) acc[i] += __shfl_xor(acc[i], 2, 64);
    if (head == 0) {
        int jch = lane >> 2;             // 0..7
        int nfb = (lane & 1) * 8;
        #pragma unroll
        for (int i = 0; i < 8; ++i) {
            int o = (nfb + i) * 8 + jch;
            louts[half * 128 + o] = active ? elu_f(acc[i] + b2[o]) : 0.f;
        }
    }
    __syncthreads();
    // run-length merge of the block's 8 nodes (batch sorted -> 1-2 runs/block)
    if (threadIdx.x < 128) {
        int c = threadIdx.x;
        int cur = lbat[0];
        float a = 0.f;
        #pragma unroll
        for (int n = 0; n < 8; ++n) {
            int b = lbat[n];
            if (b != cur) {
                if (cur >= 0) atomicAdd(&sums[(size_t)cur * 128 + c], a);
                a = 0.f; cur = b;
            }
            a += louts[n * 128 + c];
        }
        if (cur >= 0) atomicAdd(&sums[(size_t)cur * 128 + c], a);
    }
}

// ---------------- final: out = (sums/cnt) @ lo_w + lo_b ----------------
__global__ void final_kernel(
        const float* __restrict__ sums, const float* __restrict__ cnts,
        const float* __restrict__ w, const float* __restrict__ b,
        float* __restrict__ out, int G) {
    int g = blockIdx.x;
    int k = threadIdx.x;
    if (k >= 24) return;
    float inv = 1.f / fmaxf(cnts[g], 1.f);
    float acc = b[k];
    #pragma unroll
    for (int c = 0; c < 128; ++c) acc = fmaf(sums[g * 128 + c] * inv, w[c * 24 + k], acc);
    out[g * 24 + k] = acc;
}

extern "C" void kernel_launch(void* const* d_in, const int* in_sizes, int n_in,
                              void* d_out, int out_size, void* d_ws, size_t ws_size,
                              hipStream_t stream) {
    const float* x      = (const float*)d_in[0];
    const int*   ei     = (const int*)d_in[1];
    const int*   batch  = (const int*)d_in[2];
    const float* fc0_w  = (const float*)d_in[3];
    const float* fc0_b  = (const float*)d_in[4];
    const float* W1     = (const float*)d_in[5];
    const float* a_src1 = (const float*)d_in[6];
    const float* a_dst1 = (const float*)d_in[7];
    const float* b1     = (const float*)d_in[8];
    const float* W2     = (const float*)d_in[9];
    const float* a_src2 = (const float*)d_in[10];
    const float* a_dst2 = (const float*)d_in[11];
    const float* b2     = (const float*)d_in[12];
    const float* lo_w   = (const float*)d_in[13];
    const float* lo_b   = (const float*)d_in[14];
    float* out = (float*)d_out;

    const int N = in_sizes[0] / 16;
    const int E = in_sizes[1] / 2;
    const int G = out_size / 24;
    const int* src = ei;
    const int* dst = ei + E;
    const int NB  = (N + 255) >> 8;            // coarse buckets (<= 256 for N <= 65536)
    const int nbl = (E + EPB - 1) / EPB;       // bucket-pass blocks

    char* wsb = (char*)d_ws;
    size_t off = 0;
    auto allocf = [&](size_t n) { float* p = (float*)(wsb + off); off += ((n * 4 + 255) & ~(size_t)255); return p; };
    auto alloci = [&](size_t n) { int* p = (int*)(wsb + off); off += ((n * 4 + 255) & ~(size_t)255); return p; };
    auto alloch = [&](size_t n) { __half* p = (__half*)(wsb + off); off += ((n * 2 + 255) & ~(size_t)255); return p; };
    __half* hbuf  = alloch((size_t)N * 256);        // h1: N*128 halves; h8 (fp8): first N*256 bytes
    __half* g1h   = alloch((size_t)(N + 64) * 64);  // fp16 g1 (padded for 64-node GEMM blocks)
    __half* w2t   = alloch(16384);                  // W2 transposed [256][64] fp16
    float*  es    = allocf((size_t)N * 2);
    float*  ed    = allocf((size_t)N * 2);
    float*  es2   = allocf((size_t)N * 2);
    float*  ed2   = allocf((size_t)N * 2);
    float*  sums  = allocf((size_t)G * 128);
    float*  cnts  = allocf((size_t)G);
    float*  wa1   = allocf(64);
    float*  wd1   = allocf(64);
    float*  wa2   = allocf(128);
    float*  wd2   = allocf(128);
    int* ofs     = alloci((size_t)N + 1);
    int* sperm   = alloci((size_t)E);
    int* bhist   = alloci((size_t)NB * nbl);
    int* bstart  = alloci((size_t)NB + 1);
    uint2* ebuf  = (uint2*)alloci((size_t)E * 2);
    (void)ws_size;

    // init (+ W2T build + folded attention vectors)
    init_kernel<<<(N + 255) / 256, 256, 0, stream>>>(sums, cnts, N, G,
            W1, a_src1, a_dst1, W2, a_src2, a_dst2, wa1, wd1, wa2, wd2, w2t);
    // CSR build: all heavy atomics in LDS
    bucket_hist<<<nbl, 256, 0, stream>>>(dst, bhist, NB, nbl, E);
    bucket_scan<<<1, 1024, 0, stream>>>(bhist, bstart, ofs + N, NB, nbl, E);
    bucket_scatter<<<nbl, 256, 0, stream>>>(src, dst, bhist, ebuf, NB, nbl, E);
    bucket_csr<<<NB, 256, 0, stream>>>(ebuf, bstart, batch, cnts, ofs, sperm, N);

    // ---- GAT layer 1 (fc0 fused into transform; layer-2 attn scalars fused into agg) ----
    fused_t1<<<(N + 7) / 8, 256, 0, stream>>>(x, fc0_w, fc0_b, W1, wa1, wd1, hbuf, es, ed, N);
    gat_agg1<<<(N + 15) / 16, 256, 0, stream>>>(ofs, sperm, es, ed, (const uint4*)hbuf, b1,
            wa2, wd2, (uint2*)g1h, es2, ed2, N);

    // ---- GAT layer 2 (MFMA transform -> fp8 permuted h2; pool fused into aggregation) ----
    t2_mfma<<<(N + 63) / 64, 256, 0, stream>>>(g1h, w2t, (unsigned char*)hbuf, N);
    gat_agg2<<<(N + 7) / 8, 256, 0, stream>>>(ofs, sperm, es2, ed2, (const uint2*)hbuf, b2,
            batch, sums, N);

    // ---- final linear ----
    final_kernel<<<G, 32, 0, stream>>>(sums, cnts, lo_w, lo_b, out, G);
}

// Round 10
// 264.786 us; speedup vs baseline: 1.7959x; 1.1347x over previous
//
#include <hip/hip_runtime.h>
#include <hip/hip_fp16.h>
#include <math.h>

#define NEG_SLOPE 0.2f
#define GAT_EPS 1e-16f
#define EPB 8192   // edges per block in bucket passes

__device__ __forceinline__ float elu_f(float x) { return x > 0.f ? x : expm1f(x); }
__device__ __forceinline__ float lrelu_f(float x) { return x > 0.f ? x : NEG_SLOPE * x; }

typedef _Float16 half2v __attribute__((ext_vector_type(2)));
typedef _Float16 half8 __attribute__((ext_vector_type(8)));
typedef float f32x4 __attribute__((ext_vector_type(4)));
typedef float f32x2 __attribute__((ext_vector_type(2)));

// fp32 accumulate of half2 dot: acc += v.x*a.x + v.y*a.y
__device__ __forceinline__ float fdot2f(unsigned int v, unsigned int a, float acc) {
#if __has_builtin(__builtin_amdgcn_fdot2)
    return __builtin_amdgcn_fdot2(__builtin_bit_cast(half2v, v),
                                  __builtin_bit_cast(half2v, a), acc, false);
#else
    __half2 hv = __builtin_bit_cast(__half2, v);
    __half2 ha = __builtin_bit_cast(__half2, a);
    float2 fv = __half22float2(hv), fa = __half22float2(ha);
    return fmaf(fv.x, fa.x, fmaf(fv.y, fa.y, acc));
#endif
}

__device__ __forceinline__ unsigned int pack_half2(float a, float b) {
    __half2 h = __floats2half2_rn(a, b);
    return __builtin_bit_cast(unsigned int, h);
}

// ---- fp8 e4m3 (gfx950 HW converts; slow software fallback for other targets) ----
#if __has_builtin(__builtin_amdgcn_cvt_pk_fp8_f32) && __has_builtin(__builtin_amdgcn_cvt_pk_f32_fp8)
#define HW_FP8 1
#endif

__device__ __forceinline__ unsigned int pack_fp8x4(float a, float b, float c, float d) {
#ifdef HW_FP8
    int r = 0;
    r = __builtin_amdgcn_cvt_pk_fp8_f32(a, b, r, false);
    r = __builtin_amdgcn_cvt_pk_fp8_f32(c, d, r, true);
    return (unsigned int)r;
#else
    auto enc = [](float x) -> unsigned int {
        if (x != x) return 0x7f;
        float ax = fabsf(x);
        unsigned int s = x < 0.f ? 0x80u : 0u;
        if (ax < 0.001953125f) {
            int m = (int)(ax * 512.f + 0.5f);
            if (m > 7) m = 7;
            return s | (unsigned int)m;
        }
        if (ax >= 448.f) return s | 0x7e;
        int e; float fr = frexpf(ax, &e);
        int m = (int)(fr * 16.f + 0.5f);
        if (m == 16) { m = 8; e += 1; }
        return s | ((unsigned int)(e + 6) << 3) | (unsigned int)(m - 8);
    };
    return enc(a) | (enc(b) << 8) | (enc(c) << 16) | (enc(d) << 24);
#endif
}

template <bool HI>
__device__ __forceinline__ f32x2 fp8x2_to_f32(unsigned int v) {
#ifdef HW_FP8
    return __builtin_amdgcn_cvt_pk_f32_fp8((int)v, HI);
#else
    auto dec = [](unsigned int b) -> float {
        float s = (b & 0x80) ? -1.f : 1.f;
        int e = (b >> 3) & 0xF, m = b & 7;
        if (e == 0) return s * (float)m * 0.001953125f;
        return s * (8.f + (float)m) * exp2f((float)(e - 10));
    };
    unsigned int sh = HI ? 16 : 0;
    f32x2 r;
    r[0] = dec((v >> sh) & 0xFF);
    r[1] = dec((v >> (sh + 8)) & 0xFF);
    return r;
#endif
}

// decode 8 fp8 channels (head-interleaved pairs) and accumulate 4 outputs
__device__ __forceinline__ void acc8_fp8(uint2 v, float aw0, float aw1,
        float& a0, float& a1, float& a2, float& a3) {
    f32x2 f01 = fp8x2_to_f32<false>(v.x);
    f32x2 f23 = fp8x2_to_f32<true >(v.x);
    f32x2 f45 = fp8x2_to_f32<false>(v.y);
    f32x2 f67 = fp8x2_to_f32<true >(v.y);
    a0 = fmaf(aw0, f01[0], a0); a0 = fmaf(aw1, f01[1], a0);
    a1 = fmaf(aw0, f23[0], a1); a1 = fmaf(aw1, f23[1], a1);
    a2 = fmaf(aw0, f45[0], a2); a2 = fmaf(aw1, f45[1], a2);
    a3 = fmaf(aw0, f67[0], a3); a3 = fmaf(aw1, f67[1], a3);
}

__device__ __forceinline__ float halfReduceSum(float v) {
    #pragma unroll
    for (int off = 16; off > 0; off >>= 1) v += __shfl_xor(v, off, 64);
    return v;
}
__device__ __forceinline__ float quarterReduceSum(float v) {
    #pragma unroll
    for (int off = 8; off > 0; off >>= 1) v += __shfl_xor(v, off, 64);
    return v;
}

// ---------------- init: zero sums/cnts; block1 builds W2T fp16; last block folds attn vectors ----------------
// fold parallelized: 4 threads/output (L1), 2 threads/output (L2), shfl_xor combine
__global__ void init_kernel(float* sums, float* cnts, int N, int G,
        const float* __restrict__ W1, const float* __restrict__ as1, const float* __restrict__ ad1,
        const float* __restrict__ W2, const float* __restrict__ as2, const float* __restrict__ ad2,
        float* __restrict__ wa1, float* __restrict__ wd1,
        float* __restrict__ wa2, float* __restrict__ wd2,
        __half* __restrict__ w2t) {
    int i = blockIdx.x * 256 + threadIdx.x;
    if (i < G * 128) sums[i] = 0.f;
    if (i < G) cnts[i] = 0.f;
    if (blockIdx.x == 1) {
        // W2T[c2][k] = W2[h=c2&1][k][o=c2>>1], fp16, [256][64]
        for (int idx = threadIdx.x; idx < 16384; idx += 256) {
            int c2 = idx >> 6, k = idx & 63;
            w2t[idx] = __float2half(W2[(c2 & 1) * 8192 + k * 128 + (c2 >> 1)]);
        }
    }
    if (blockIdx.x == gridDim.x - 1) {
        int t = threadIdx.x;
        {   // layer1: idx = t>>2 (0..63), part = t&3 covers 16 of 64 elems
            int idx = t >> 2, part = t & 3;
            int h = idx >> 5, c = idx & 31;
            const float* w = W1 + (h * 32 + c) * 64;
            float sa = 0.f, sd = 0.f;
            #pragma unroll
            for (int o = part * 16; o < part * 16 + 16; ++o) {
                sa = fmaf(w[o], as1[h * 64 + o], sa);
                sd = fmaf(w[o], ad1[h * 64 + o], sd);
            }
            sa += __shfl_xor(sa, 1, 64); sa += __shfl_xor(sa, 2, 64);
            sd += __shfl_xor(sd, 1, 64); sd += __shfl_xor(sd, 2, 64);
            if (part == 0) { wa1[idx] = sa; wd1[idx] = sd; }
        }
        {   // layer2: idx = t>>1 (0..127), part = t&1 covers 64 of 128 elems
            int idx = t >> 1, part = t & 1;
            int h = idx >> 6, c = idx & 63;
            const float* w = W2 + (h * 64 + c) * 128;
            float sa = 0.f, sd = 0.f;
            for (int o = part * 64; o < part * 64 + 64; ++o) {
                sa = fmaf(w[o], as2[h * 128 + o], sa);
                sd = fmaf(w[o], ad2[h * 128 + o], sd);
            }
            sa += __shfl_xor(sa, 1, 64);
            sd += __shfl_xor(sd, 1, 64);
            if (part == 0) { wa2[idx] = sa; wd2[idx] = sd; }
        }
    }
}

// ---------------- CSR build: LDS-binned two-level counting sort (no global atomics) ----------------
// Coarse bucket = dst>>8 (NB = ceil(N/256) <= 256 buckets).

// pass A: per-block LDS histogram of coarse buckets
__global__ __launch_bounds__(256) void bucket_hist(
        const int* __restrict__ dst, int* __restrict__ bhist,
        int NB, int nbl, int E) {
    __shared__ int lh[256];
    int tid = threadIdx.x;
    lh[tid] = 0;
    __syncthreads();
    int base = blockIdx.x * EPB;
    int lim = E - base; if (lim > EPB) lim = EPB;
    for (int k = tid; k < lim; k += 256)
        atomicAdd(&lh[(unsigned)dst[base + k] >> 8], 1);
    __syncthreads();
    if (tid < NB) bhist[(size_t)tid * nbl + blockIdx.x] = lh[tid];   // bin-major
}

// pass B (1 block, 1024 thr): bucket starts + per-(bin,block) base offsets (in place)
__global__ __launch_bounds__(1024) void bucket_scan(
        int* __restrict__ bhist, int* __restrict__ bstart,
        int* __restrict__ ofsN, int NB, int nbl, int E) {
    __shared__ int stot[256];
    __shared__ int sbs[256];
    int tid = threadIdx.x, lane = tid & 63, wid = tid >> 6;
    {   // bucket totals: 4 threads/bucket + shfl combine
        int bin = tid >> 2, part = tid & 3;
        int t = 0;
        if (bin < NB) {
            const int* p = bhist + (size_t)bin * nbl;
            for (int b = part; b < nbl; b += 4) t += p[b];
        }
        t += __shfl_xor(t, 1, 64);
        t += __shfl_xor(t, 2, 64);
        if (part == 0) stot[bin] = t;
    }
    __syncthreads();
    if (tid < 64) {                        // exclusive scan of 256 totals (wave 0)
        int carry = 0;
        for (int c = 0; c < 256; c += 64) {
            int v = stot[c + lane];
            int incl = v;
            #pragma unroll
            for (int off = 1; off < 64; off <<= 1) {
                int t = __shfl_up(incl, off, 64);
                if (lane >= off) incl += t;
            }
            sbs[c + lane] = incl - v + carry;
            carry += __shfl(incl, 63, 64);
        }
    }
    __syncthreads();
    if (tid < NB) bstart[tid] = sbs[tid];
    if (tid == 0) { bstart[NB] = E; *ofsN = E; }
    // per-bucket exclusive scan over blocks, + bucket start (in place)
    for (int bin = wid; bin < NB; bin += 16) {
        int carry = sbs[bin];
        int* p = bhist + (size_t)bin * nbl;
        for (int c = 0; c < nbl; c += 64) {
            int idx = c + lane;
            int v = (idx < nbl) ? p[idx] : 0;
            int incl = v;
            #pragma unroll
            for (int off = 1; off < 64; off <<= 1) {
                int t = __shfl_up(incl, off, 64);
                if (lane >= off) incl += t;
            }
            if (idx < nbl) p[idx] = incl - v + carry;
            carry += __shfl(incl, 63, 64);
        }
    }
}

// pass C: scatter (src,dst) pairs into coarse-bucket-grouped ebuf via LDS cursors
__global__ __launch_bounds__(256) void bucket_scatter(
        const int* __restrict__ src, const int* __restrict__ dst,
        const int* __restrict__ bhist, uint2* __restrict__ ebuf,
        int NB, int nbl, int E) {
    __shared__ int lc[256];
    int tid = threadIdx.x;
    if (tid < NB) lc[tid] = bhist[(size_t)tid * nbl + blockIdx.x];
    __syncthreads();
    int base = blockIdx.x * EPB;
    int lim = E - base; if (lim > EPB) lim = EPB;
    for (int k = tid; k < lim; k += 256) {
        int d = dst[base + k];
        int s = src[base + k];
        int pos = atomicAdd(&lc[(unsigned)d >> 8], 1);
        ebuf[pos] = make_uint2((unsigned)s, (unsigned)d);
    }
}

// pass D: one block per bucket -> fine hist (deg), scan (ofs), LDS-cursor scatter (sperm), cnts
__global__ __launch_bounds__(256) void bucket_csr(
        const uint2* __restrict__ ebuf, const int* __restrict__ bstart,
        const int* __restrict__ batch, float* __restrict__ cnts,
        int* __restrict__ ofs, int* __restrict__ sperm, int N) {
    __shared__ int fh[256];
    __shared__ int wtot[4];
    __shared__ int lc[256];
    int bin = blockIdx.x;
    int tid = threadIdx.x, lane = tid & 63, wid = tid >> 6;
    int ebeg = bstart[bin], eend = bstart[bin + 1];
    fh[tid] = 0;
    __syncthreads();
    for (int i = ebeg + tid; i < eend; i += 256)
        atomicAdd(&fh[ebuf[i].y & 255], 1);
    __syncthreads();
    // exclusive scan of fh (256 values, 4 waves)
    int v = fh[tid];
    int incl = v;
    #pragma unroll
    for (int off = 1; off < 64; off <<= 1) {
        int t = __shfl_up(incl, off, 64);
        if (lane >= off) incl += t;
    }
    if (lane == 63) wtot[wid] = incl;
    __syncthreads();
    int woff = 0;
    #pragma unroll
    for (int w = 0; w < 4; ++w) if (w < wid) woff += wtot[w];
    int excl = incl - v + woff;
    int d = (bin << 8) + tid;
    if (d < N) ofs[d] = ebeg + excl;
    lc[tid] = excl;
    // graph node-counts (batch sorted; ballot trick, contiguous node range)
    if (d < N) {
        int b = batch[d];
        int b0 = __shfl(b, 0, 64);
        if (__all(b == b0)) {
            unsigned long long m = __ballot(1);
            if (lane == 0) atomicAdd(&cnts[b], (float)__popcll(m));
        } else {
            atomicAdd(&cnts[b], 1.f);
        }
    }
    __syncthreads();
    for (int i = ebeg + tid; i < eend; i += 256) {
        uint2 e = ebuf[i];
        int pos = atomicAdd(&lc[e.y & 255], 1);
        sperm[ebeg + pos] = (int)e.x;
    }
}

// ---------------- fused fc0 + GAT layer1 transform (8 nodes/block; W1 in LDS; h1 -> fp8) ----------------
__global__ __launch_bounds__(256) void fused_t1(
        const float* __restrict__ x, const float* __restrict__ w0,
        const float* __restrict__ b0, const float* __restrict__ W1,
        const float* __restrict__ wa1, const float* __restrict__ wd1,
        unsigned char* __restrict__ h1, float* __restrict__ es, float* __restrict__ ed, int N) {
    __shared__ float xs[8 * 16];
    __shared__ float hs[8 * 32];
    __shared__ float ws[4096];       // W1 (2*32*64 floats = 16KB)
    __shared__ float hs2[8 * 128];   // h1 staging for fp8 pack
    int n0 = blockIdx.x * 8;
    int tid = threadIdx.x;
    {   // stage W1 once per block (coalesced float4)
        const float4* wv4 = reinterpret_cast<const float4*>(W1);
        float4* ws4 = reinterpret_cast<float4*>(ws);
        #pragma unroll
        for (int i = 0; i < 4; ++i) ws4[tid + i * 256] = wv4[tid + i * 256];
    }
    if (tid < 128) {
        int gi = n0 * 16 + tid;
        xs[tid] = (gi < N * 16) ? x[gi] : 0.f;
    }
    __syncthreads();
    {
        int j = tid >> 5, o = tid & 31;
        float acc = b0[o];
        #pragma unroll
        for (int c = 0; c < 16; ++c) acc = fmaf(xs[j * 16 + c], w0[c * 32 + o], acc);
        hs[j * 32 + o] = elu_f(acc);
    }
    __syncthreads();
    int o = tid & 63, h = (tid >> 6) & 1, nh = tid >> 7;
    float acc[4];
    #pragma unroll
    for (int j = 0; j < 4; ++j) acc[j] = 0.f;
    const float* wp = ws + h * 2048 + o;
    #pragma unroll
    for (int c = 0; c < 32; ++c) {
        float wv = wp[c * 64];
        #pragma unroll
        for (int j = 0; j < 4; ++j) acc[j] = fmaf(hs[(nh * 4 + j) * 32 + c], wv, acc[j]);
    }
    #pragma unroll
    for (int j = 0; j < 4; ++j)
        hs2[(nh * 4 + j) * 128 + 2 * o + h] = acc[j];
    if (tid < 32) {
        int n = tid >> 2, r = tid & 3, hh = r >> 1, isd = r & 1;
        const float* wv = (isd ? wd1 : wa1) + hh * 32;
        float s = 0.f;
        #pragma unroll
        for (int c = 0; c < 32; ++c) s = fmaf(hs[n * 32 + c], wv[c], s);
        int nn = n0 + n;
        if (nn < N) { if (isd) ed[nn * 2 + hh] = s; else es[nn * 2 + hh] = s; }
    }
    __syncthreads();
    if (tid < 128) {   // pack 8 nodes x 128 ch to fp8, coalesced uint2 stores
        int nloc = tid >> 4, cg = tid & 15;
        int n = n0 + nloc;
        if (n < N) {
            const float* p = hs2 + nloc * 128 + cg * 8;
            uint2 pk;
            pk.x = pack_fp8x4(p[0], p[1], p[2], p[3]);
            pk.y = pack_fp8x4(p[4], p[5], p[6], p[7]);
            *reinterpret_cast<uint2*>(h1 + (size_t)n * 128 + cg * 8) = pk;
        }
    }
}

// ---------------- GAT layer2 transform: MFMA GEMM [N x 64] @ [64 x 256], fp8 output ----------------
// Output h8[node][pos] fp8, PERMUTED: pos = r*16+nf holds channel col = nf*16+r.
__global__ __launch_bounds__(256) void t2_mfma(
        const __half* __restrict__ g1h,   // [Npad][64] fp16
        const __half* __restrict__ w2t,   // [256][64] fp16
        unsigned char* __restrict__ h8, int N) {
    __shared__ __half sbuf[16384];   // 32KB: B operand, XOR-swizzled
    int tid = threadIdx.x;
    {   // stage B: 2048 uint4, XOR-swizzled (row = 128B = 8 uint4)
        const uint4* srcv = reinterpret_cast<const uint4*>(w2t);
        #pragma unroll
        for (int i = 0; i < 8; ++i) {
            int idx = tid + i * 256;
            int row = idx >> 3;
            int byteoff = (idx * 16) ^ ((row & 7) << 4);
            *reinterpret_cast<uint4*>(reinterpret_cast<char*>(sbuf) + byteoff) = srcv[idx];
        }
    }
    __syncthreads();
    int w = tid >> 6, lane = tid & 63;
    int r = lane & 15, kg = lane >> 4;
    int nodei = blockIdx.x * 64 + w * 16 + r;
    const half8* ap = reinterpret_cast<const half8*>(
        reinterpret_cast<const _Float16*>(g1h) + (size_t)nodei * 64 + kg * 8);

    f32x4 acc[16];
    #pragma unroll
    for (int nf = 0; nf < 16; ++nf) acc[nf] = f32x4{0.f, 0.f, 0.f, 0.f};
    half8 az = {};
    #pragma unroll
    for (int ks = 0; ks < 2; ++ks) {
        half8 a = (nodei < N) ? ap[ks * 4] : az;
        #pragma unroll
        for (int nf = 0; nf < 16; ++nf) {
            int brow = nf * 16 + r;
            int bbyte = (brow * 128 + ks * 64 + kg * 16) ^ ((brow & 7) << 4);
            half8 b = *reinterpret_cast<const half8*>(reinterpret_cast<const char*>(sbuf) + bbyte);
            acc[nf] = __builtin_amdgcn_mfma_f32_16x16x32_f16(a, b, acc[nf], 0, 0, 0);
        }
    }
    #pragma unroll
    for (int q = 0; q < 4; ++q) {
        int n = blockIdx.x * 64 + w * 16 + kg * 4 + q;
        if (n < N) {
            uint4 pk;
            pk.x = pack_fp8x4(acc[0][q],  acc[1][q],  acc[2][q],  acc[3][q]);
            pk.y = pack_fp8x4(acc[4][q],  acc[5][q],  acc[6][q],  acc[7][q]);
            pk.z = pack_fp8x4(acc[8][q],  acc[9][q],  acc[10][q], acc[11][q]);
            pk.w = pack_fp8x4(acc[12][q], acc[13][q], acc[14][q], acc[15][q]);
            *reinterpret_cast<uint4*>(h8 + (size_t)n * 256 + r * 16) = pk;
        }
    }
}

// ---------------- aggregation layer1: one QUARTER-WAVE (16 lanes) per dst node, fp8 uint2 loads ----------------
__global__ __launch_bounds__(256) void gat_agg1(
        const int* __restrict__ ofs, const int* __restrict__ sperm,
        const float* __restrict__ es, const float* __restrict__ ed,
        const uint2* __restrict__ h1v, const float* __restrict__ b1,
        const float* __restrict__ wa2, const float* __restrict__ wd2,
        uint2* __restrict__ g1h, float* __restrict__ es2, float* __restrict__ ed2, int N) {
    __shared__ uint2 meta[16][32];
    int q = threadIdx.x >> 4;            // 0..15
    int d = blockIdx.x * 16 + q;
    int lane = threadIdx.x & 15;
    bool active = d < N;                 // uniform per quarter
    if (!active) return;                 // no block-wide barrier in this kernel
    float2 edv = *reinterpret_cast<const float2*>(ed + (size_t)d * 2);
    int beg = ofs[d], end = ofs[d + 1];
    int deg = end - beg;
    int jmax = deg < 32 ? deg : 32;

    int s0i = 0, s1i = 0;
    float ex00 = 0.f, ex01 = 0.f, ex10 = 0.f, ex11 = 0.f;
    int i0 = beg + lane, i1 = beg + lane + 16;
    if (i0 < end) {
        s0i = sperm[i0];
        float2 e = *reinterpret_cast<const float2*>(es + (size_t)s0i * 2);
        ex00 = __expf(lrelu_f(e.x + edv.x));
        ex01 = __expf(lrelu_f(e.y + edv.y));
    }
    if (i1 < end) {
        s1i = sperm[i1];
        float2 e = *reinterpret_cast<const float2*>(es + (size_t)s1i * 2);
        ex10 = __expf(lrelu_f(e.x + edv.x));
        ex11 = __expf(lrelu_f(e.y + edv.y));
    }
    float s0 = ex00 + ex10, s1 = ex01 + ex11;
    for (int i = i0 + 32; i < end; i += 16) {   // rare: deg > 32
        int s = sperm[i];
        float2 e = *reinterpret_cast<const float2*>(es + (size_t)s * 2);
        s0 += __expf(lrelu_f(e.x + edv.x));
        s1 += __expf(lrelu_f(e.y + edv.y));
    }
    s0 = quarterReduceSum(s0);
    s1 = quarterReduceSum(s1);
    float r0 = 0.5f / (s0 + GAT_EPS), r1 = 0.5f / (s1 + GAT_EPS);
    if (lane < jmax)
        meta[q][lane] = make_uint2((unsigned int)s0i, pack_half2(ex00 * r0, ex01 * r1));
    if (lane + 16 < jmax)
        meta[q][lane + 16] = make_uint2((unsigned int)s1i, pack_half2(ex10 * r0, ex11 * r1));

    // lane covers output channels 4*lane .. 4*lane+3 (heads combined inside acc8_fp8)
    float a0 = 0.f, a1 = 0.f, a2 = 0.f, a3 = 0.f;
    int j = 0;
    for (; j + 8 <= jmax; j += 8) {
        uint2 vv[8];
        #pragma unroll
        for (int k = 0; k < 8; ++k) vv[k] = h1v[(size_t)meta[q][j + k].x * 16 + lane];
        #pragma unroll
        for (int k = 0; k < 8; ++k) {
            float2 af = __half22float2(__builtin_bit_cast(__half2, meta[q][j + k].y));
            acc8_fp8(vv[k], af.x, af.y, a0, a1, a2, a3);
        }
    }
    for (; j + 4 <= jmax; j += 4) {
        uint2 vv[4];
        #pragma unroll
        for (int k = 0; k < 4; ++k) vv[k] = h1v[(size_t)meta[q][j + k].x * 16 + lane];
        #pragma unroll
        for (int k = 0; k < 4; ++k) {
            float2 af = __half22float2(__builtin_bit_cast(__half2, meta[q][j + k].y));
            acc8_fp8(vv[k], af.x, af.y, a0, a1, a2, a3);
        }
    }
    for (; j < jmax; ++j) {
        uint2 m = meta[q][j];
        float2 af = __half22float2(__builtin_bit_cast(__half2, m.y));
        acc8_fp8(h1v[(size_t)m.x * 16 + lane], af.x, af.y, a0, a1, a2, a3);
    }
    for (int i = beg + 32; i < end; ++i) {      // rare: deg > 32
        int s = sperm[i];
        float2 e = *reinterpret_cast<const float2*>(es + (size_t)s * 2);
        float w0 = __expf(lrelu_f(e.x + edv.x)) * r0;
        float w1 = __expf(lrelu_f(e.y + edv.y)) * r1;
        acc8_fp8(h1v[(size_t)s * 16 + lane], w0, w1, a0, a1, a2, a3);
    }
    float4 bv = reinterpret_cast<const float4*>(b1)[lane];
    float o0 = elu_f(a0 + bv.x);
    float o1 = elu_f(a1 + bv.y);
    float o2 = elu_f(a2 + bv.z);
    float o3 = elu_f(a3 + bv.w);
    g1h[(size_t)d * 16 + lane] = make_uint2(pack_half2(o0, o1), pack_half2(o2, o3));
    float4 wa0 = reinterpret_cast<const float4*>(wa2)[lane];
    float4 wa1v = reinterpret_cast<const float4*>(wa2)[16 + lane];
    float4 wd0 = reinterpret_cast<const float4*>(wd2)[lane];
    float4 wd1v = reinterpret_cast<const float4*>(wd2)[16 + lane];
    float p0 = o0 * wa0.x + o1 * wa0.y + o2 * wa0.z + o3 * wa0.w;
    float p1 = o0 * wa1v.x + o1 * wa1v.y + o2 * wa1v.z + o3 * wa1v.w;
    float q0 = o0 * wd0.x + o1 * wd0.y + o2 * wd0.z + o3 * wd0.w;
    float q1 = o0 * wd1v.x + o1 * wd1v.y + o2 * wd1v.z + o3 * wd1v.w;
    p0 = quarterReduceSum(p0);
    p1 = quarterReduceSum(p1);
    q0 = quarterReduceSum(q0);
    q1 = quarterReduceSum(q1);
    if (lane == 0) {
        es2[(size_t)d * 2]     = p0;
        es2[(size_t)d * 2 + 1] = p1;
        ed2[(size_t)d * 2]     = q0;
        ed2[(size_t)d * 2 + 1] = q1;
    }
}

// ---------------- aggregation layer2 (fp8 h2, permuted rows) + fused block-level pool ----------------
__global__ __launch_bounds__(256) void gat_agg2(
        const int* __restrict__ ofs, const int* __restrict__ sperm,
        const float* __restrict__ es, const float* __restrict__ ed,
        const uint2* __restrict__ h8v, const float* __restrict__ b2,
        const int* __restrict__ batch, float* __restrict__ sums, int N) {
    __shared__ uint2 meta[8][32];
    __shared__ float louts[8 * 128];
    __shared__ int lbat[8];
    int half = threadIdx.x >> 5;
    int d = blockIdx.x * 8 + half;
    int lane = threadIdx.x & 31;
    bool active = d < N;                 // uniform per half; NO early return (barrier below)
    int beg = 0, end = 0;
    if (active) {
        beg = ofs[d]; end = ofs[d + 1];
        if (lane == 0) lbat[half] = batch[d];
    } else if (lane == 0) {
        lbat[half] = -1;
    }
    float2 edv = active ? *reinterpret_cast<const float2*>(ed + (size_t)d * 2)
                        : make_float2(0.f, 0.f);
    int deg = end - beg;
    int jmax = deg < 32 ? deg : 32;

    int s_f = 0;
    float ex0 = 0.f, ex1 = 0.f;
    int i0 = beg + lane;
    if (i0 < end) {
        s_f = sperm[i0];
        float2 esv = *reinterpret_cast<const float2*>(es + (size_t)s_f * 2);
        ex0 = __expf(lrelu_f(esv.x + edv.x));
        ex1 = __expf(lrelu_f(esv.y + edv.y));
    }
    float s0 = ex0, s1 = ex1;
    for (int i = i0 + 32; i < end; i += 32) {  // rare: deg > 32
        int s = sperm[i];
        float2 esv = *reinterpret_cast<const float2*>(es + (size_t)s * 2);
        s0 += __expf(lrelu_f(esv.x + edv.x));
        s1 += __expf(lrelu_f(esv.y + edv.y));
    }
    s0 = halfReduceSum(s0);
    s1 = halfReduceSum(s1);
    float r0 = 0.5f / (s0 + GAT_EPS), r1 = 0.5f / (s1 + GAT_EPS);
    if (lane < jmax)
        meta[half][lane] = make_uint2((unsigned int)s_f, pack_half2(ex0 * r0, ex1 * r1));

    int head = (lane >> 1) & 1;          // fixed per lane under the permuted layout
    float acc[8];
    #pragma unroll
    for (int i = 0; i < 8; ++i) acc[i] = 0.f;

    int j = 0;
    for (; j + 8 <= jmax; j += 8) {
        uint2 vv[8];
        #pragma unroll
        for (int k = 0; k < 8; ++k) vv[k] = h8v[(size_t)meta[half][j + k].x * 32 + lane];
        #pragma unroll
        for (int k = 0; k < 8; ++k) {
            __half2 ah = __builtin_bit_cast(__half2, meta[half][j + k].y);
            float2 af = __half22float2(ah);
            float av = head ? af.y : af.x;
            f32x2 f01 = fp8x2_to_f32<false>(vv[k].x);
            f32x2 f23 = fp8x2_to_f32<true>(vv[k].x);
            f32x2 f45 = fp8x2_to_f32<false>(vv[k].y);
            f32x2 f67 = fp8x2_to_f32<true>(vv[k].y);
            acc[0] = fmaf(av, f01[0], acc[0]);
            acc[1] = fmaf(av, f01[1], acc[1]);
            acc[2] = fmaf(av, f23[0], acc[2]);
            acc[3] = fmaf(av, f23[1], acc[3]);
            acc[4] = fmaf(av, f45[0], acc[4]);
            acc[5] = fmaf(av, f45[1], acc[5]);
            acc[6] = fmaf(av, f67[0], acc[6]);
            acc[7] = fmaf(av, f67[1], acc[7]);
        }
    }
    for (; j < jmax; ++j) {
        uint2 v = h8v[(size_t)meta[half][j].x * 32 + lane];
        __half2 ah = __builtin_bit_cast(__half2, meta[half][j].y);
        float2 af = __half22float2(ah);
        float av = head ? af.y : af.x;
        f32x2 f01 = fp8x2_to_f32<false>(v.x);
        f32x2 f23 = fp8x2_to_f32<true>(v.x);
        f32x2 f45 = fp8x2_to_f32<false>(v.y);
        f32x2 f67 = fp8x2_to_f32<true>(v.y);
        acc[0] = fmaf(av, f01[0], acc[0]);
        acc[1] = fmaf(av, f01[1], acc[1]);
        acc[2] = fmaf(av, f23[0], acc[2]);
        acc[3] = fmaf(av, f23[1], acc[3]);
        acc[4] = fmaf(av, f45[0], acc[4]);
        acc[5] = fmaf(av, f45[1], acc[5]);
        acc[6] = fmaf(av, f67[0], acc[6]);
        acc[7] = fmaf(av, f67[1], acc[7]);
    }
    for (int i = beg + 32; i < end; ++i) {  // rare: deg > 32
        int s = sperm[i];
        float2 esv = *reinterpret_cast<const float2*>(es + (size_t)s * 2);
        float a0 = __expf(lrelu_f(esv.x + edv.x)) * r0;
        float a1 = __expf(lrelu_f(esv.y + edv.y)) * r1;
        float av = head ? a1 : a0;
        uint2 v = h8v[(size_t)s * 32 + lane];
        f32x2 f01 = fp8x2_to_f32<false>(v.x);
        f32x2 f23 = fp8x2_to_f32<true>(v.x);
        f32x2 f45 = fp8x2_to_f32<false>(v.y);
        f32x2 f67 = fp8x2_to_f32<true>(v.y);
        acc[0] = fmaf(av, f01[0], acc[0]);
        acc[1] = fmaf(av, f01[1], acc[1]);
        acc[2] = fmaf(av, f23[0], acc[2]);
        acc[3] = fmaf(av, f23[1], acc[3]);
        acc[4] = fmaf(av, f45[0], acc[4]);
        acc[5] = fmaf(av, f45[1], acc[5]);
        acc[6] = fmaf(av, f67[0], acc[6]);
        acc[7] = fmaf(av, f67[1], acc[7]);
    }
    // head-combine: lane^2 holds the other head of the same o-channels
    #pragma unroll
    for (int i = 0; i < 8; ++i) acc[i] += __shfl_xor(acc[i], 2, 64);
    if (head == 0) {
        int jch = lane >> 2;             // 0..7
        int nfb = (lane & 1) * 8;
        #pragma unroll
        for (int i = 0; i < 8; ++i) {
            int o = (nfb + i) * 8 + jch;
            louts[half * 128 + o] = active ? elu_f(acc[i] + b2[o]) : 0.f;
        }
    }
    __syncthreads();
    // run-length merge of the block's 8 nodes (batch sorted -> 1-2 runs/block)
    if (threadIdx.x < 128) {
        int c = threadIdx.x;
        int cur = lbat[0];
        float a = 0.f;
        #pragma unroll
        for (int n = 0; n < 8; ++n) {
            int b = lbat[n];
            if (b != cur) {
                if (cur >= 0) atomicAdd(&sums[(size_t)cur * 128 + c], a);
                a = 0.f; cur = b;
            }
            a += louts[n * 128 + c];
        }
        if (cur >= 0) atomicAdd(&sums[(size_t)cur * 128 + c], a);
    }
}

// ---------------- final: out = (sums/cnt) @ lo_w + lo_b ----------------
__global__ void final_kernel(
        const float* __restrict__ sums, const float* __restrict__ cnts,
        const float* __restrict__ w, const float* __restrict__ b,
        float* __restrict__ out, int G) {
    int g = blockIdx.x;
    int k = threadIdx.x;
    if (k >= 24) return;
    float inv = 1.f / fmaxf(cnts[g], 1.f);
    float acc = b[k];
    #pragma unroll
    for (int c = 0; c < 128; ++c) acc = fmaf(sums[g * 128 + c] * inv, w[c * 24 + k], acc);
    out[g * 24 + k] = acc;
}

extern "C" void kernel_launch(void* const* d_in, const int* in_sizes, int n_in,
                              void* d_out, int out_size, void* d_ws, size_t ws_size,
                              hipStream_t stream) {
    const float* x      = (const float*)d_in[0];
    const int*   ei     = (const int*)d_in[1];
    const int*   batch  = (const int*)d_in[2];
    const float* fc0_w  = (const float*)d_in[3];
    const float* fc0_b  = (const float*)d_in[4];
    const float* W1     = (const float*)d_in[5];
    const float* a_src1 = (const float*)d_in[6];
    const float* a_dst1 = (const float*)d_in[7];
    const float* b1     = (const float*)d_in[8];
    const float* W2     = (const float*)d_in[9];
    const float* a_src2 = (const float*)d_in[10];
    const float* a_dst2 = (const float*)d_in[11];
    const float* b2     = (const float*)d_in[12];
    const float* lo_w   = (const float*)d_in[13];
    const float* lo_b   = (const float*)d_in[14];
    float* out = (float*)d_out;

    const int N = in_sizes[0] / 16;
    const int E = in_sizes[1] / 2;
    const int G = out_size / 24;
    const int* src = ei;
    const int* dst = ei + E;
    const int NB  = (N + 255) >> 8;            // coarse buckets (<= 256 for N <= 65536)
    const int nbl = (E + EPB - 1) / EPB;       // bucket-pass blocks

    char* wsb = (char*)d_ws;
    size_t off = 0;
    auto allocf = [&](size_t n) { float* p = (float*)(wsb + off); off += ((n * 4 + 255) & ~(size_t)255); return p; };
    auto alloci = [&](size_t n) { int* p = (int*)(wsb + off); off += ((n * 4 + 255) & ~(size_t)255); return p; };
    auto alloch = [&](size_t n) { __half* p = (__half*)(wsb + off); off += ((n * 2 + 255) & ~(size_t)255); return p; };
    __half* hbuf  = alloch((size_t)N * 256);        // h1 (fp8): first N*128 B; h8 (fp8): first N*256 B
    __half* g1h   = alloch((size_t)(N + 64) * 64);  // fp16 g1 (padded for 64-node GEMM blocks)
    __half* w2t   = alloch(16384);                  // W2 transposed [256][64] fp16
    float*  es    = allocf((size_t)N * 2);
    float*  ed    = allocf((size_t)N * 2);
    float*  es2   = allocf((size_t)N * 2);
    float*  ed2   = allocf((size_t)N * 2);
    float*  sums  = allocf((size_t)G * 128);
    float*  cnts  = allocf((size_t)G);
    float*  wa1   = allocf(64);
    float*  wd1   = allocf(64);
    float*  wa2   = allocf(128);
    float*  wd2   = allocf(128);
    int* ofs     = alloci((size_t)N + 1);
    int* sperm   = alloci((size_t)E);
    int* bhist   = alloci((size_t)NB * nbl);
    int* bstart  = alloci((size_t)NB + 1);
    uint2* ebuf  = (uint2*)alloci((size_t)E * 2);
    (void)ws_size;

    // init (+ W2T build + folded attention vectors)
    init_kernel<<<(N + 255) / 256, 256, 0, stream>>>(sums, cnts, N, G,
            W1, a_src1, a_dst1, W2, a_src2, a_dst2, wa1, wd1, wa2, wd2, w2t);
    // CSR build: all heavy atomics in LDS
    bucket_hist<<<nbl, 256, 0, stream>>>(dst, bhist, NB, nbl, E);
    bucket_scan<<<1, 1024, 0, stream>>>(bhist, bstart, ofs + N, NB, nbl, E);
    bucket_scatter<<<nbl, 256, 0, stream>>>(src, dst, bhist, ebuf, NB, nbl, E);
    bucket_csr<<<NB, 256, 0, stream>>>(ebuf, bstart, batch, cnts, ofs, sperm, N);

    // ---- GAT layer 1 (fc0 fused into transform; h1 fp8; layer-2 attn scalars fused into agg) ----
    fused_t1<<<(N + 7) / 8, 256, 0, stream>>>(x, fc0_w, fc0_b, W1, wa1, wd1,
            (unsigned char*)hbuf, es, ed, N);
    gat_agg1<<<(N + 15) / 16, 256, 0, stream>>>(ofs, sperm, es, ed, (const uint2*)hbuf, b1,
            wa2, wd2, (uint2*)g1h, es2, ed2, N);

    // ---- GAT layer 2 (MFMA transform -> fp8 permuted h2; pool fused into aggregation) ----
    t2_mfma<<<(N + 63) / 64, 256, 0, stream>>>(g1h, w2t, (unsigned char*)hbuf, N);
    gat_agg2<<<(N + 7) / 8, 256, 0, stream>>>(ofs, sperm, es2, ed2, (const uint2*)hbuf, b2,
            batch, sums, N);

    // ---- final linear ----
    final_kernel<<<G, 32, 0, stream>>>(sums, cnts, lo_w, lo_b, out, G);
}

// Round 11
// 240.917 us; speedup vs baseline: 1.9739x; 1.0991x over previous
//
#include <hip/hip_runtime.h>
#include <hip/hip_fp16.h>
#include <math.h>

#define NEG_SLOPE 0.2f
#define GAT_EPS 1e-16f
#define EPB 8192   // edges per block in bucket passes

__device__ __forceinline__ float elu_f(float x) { return x > 0.f ? x : expm1f(x); }
__device__ __forceinline__ float lrelu_f(float x) { return x > 0.f ? x : NEG_SLOPE * x; }

typedef _Float16 half2v __attribute__((ext_vector_type(2)));
typedef _Float16 half8 __attribute__((ext_vector_type(8)));
typedef float f32x4 __attribute__((ext_vector_type(4)));
typedef float f32x2 __attribute__((ext_vector_type(2)));

__device__ __forceinline__ unsigned int pack_half2(float a, float b) {
    __half2 h = __floats2half2_rn(a, b);
    return __builtin_bit_cast(unsigned int, h);
}

// ---- fp8 e4m3 (gfx950 HW converts; slow software fallback for other targets) ----
#if __has_builtin(__builtin_amdgcn_cvt_pk_fp8_f32) && __has_builtin(__builtin_amdgcn_cvt_pk_f32_fp8)
#define HW_FP8 1
#endif

__device__ __forceinline__ unsigned int pack_fp8x4(float a, float b, float c, float d) {
#ifdef HW_FP8
    int r = 0;
    r = __builtin_amdgcn_cvt_pk_fp8_f32(a, b, r, false);
    r = __builtin_amdgcn_cvt_pk_fp8_f32(c, d, r, true);
    return (unsigned int)r;
#else
    auto enc = [](float x) -> unsigned int {
        if (x != x) return 0x7f;
        float ax = fabsf(x);
        unsigned int s = x < 0.f ? 0x80u : 0u;
        if (ax < 0.001953125f) {
            int m = (int)(ax * 512.f + 0.5f);
            if (m > 7) m = 7;
            return s | (unsigned int)m;
        }
        if (ax >= 448.f) return s | 0x7e;
        int e; float fr = frexpf(ax, &e);
        int m = (int)(fr * 16.f + 0.5f);
        if (m == 16) { m = 8; e += 1; }
        return s | ((unsigned int)(e + 6) << 3) | (unsigned int)(m - 8);
    };
    return enc(a) | (enc(b) << 8) | (enc(c) << 16) | (enc(d) << 24);
#endif
}

template <bool HI>
__device__ __forceinline__ f32x2 fp8x2_to_f32(unsigned int v) {
#ifdef HW_FP8
    return __builtin_amdgcn_cvt_pk_f32_fp8((int)v, HI);
#else
    auto dec = [](unsigned int b) -> float {
        float s = (b & 0x80) ? -1.f : 1.f;
        int e = (b >> 3) & 0xF, m = b & 7;
        if (e == 0) return s * (float)m * 0.001953125f;
        return s * (8.f + (float)m) * exp2f((float)(e - 10));
    };
    unsigned int sh = HI ? 16 : 0;
    f32x2 r;
    r[0] = dec((v >> sh) & 0xFF);
    r[1] = dec((v >> (sh + 8)) & 0xFF);
    return r;
#endif
}

// decode 8 fp8 channels and packed-accumulate into 4 f32x2 accumulators (v_pk_fma_f32)
__device__ __forceinline__ void acc8_pk(uint2 v, f32x2 w01,
        f32x2& c0, f32x2& c1, f32x2& c2, f32x2& c3) {
    c0 = __builtin_elementwise_fma(w01, fp8x2_to_f32<false>(v.x), c0);
    c1 = __builtin_elementwise_fma(w01, fp8x2_to_f32<true >(v.x), c1);
    c2 = __builtin_elementwise_fma(w01, fp8x2_to_f32<false>(v.y), c2);
    c3 = __builtin_elementwise_fma(w01, fp8x2_to_f32<true >(v.y), c3);
}

__device__ __forceinline__ float halfReduceSum(float v) {
    #pragma unroll
    for (int off = 16; off > 0; off >>= 1) v += __shfl_xor(v, off, 64);
    return v;
}
__device__ __forceinline__ float quarterReduceSum(float v) {
    #pragma unroll
    for (int off = 8; off > 0; off >>= 1) v += __shfl_xor(v, off, 64);
    return v;
}

// ---------------- K1: init (zero sums/cnts, W2T, attn folds) co-launched with bucket_hist ----------------
__global__ __launch_bounds__(256) void init_hist(
        float* sums, float* cnts, int N, int G,
        const float* __restrict__ W1, const float* __restrict__ as1, const float* __restrict__ ad1,
        const float* __restrict__ W2, const float* __restrict__ as2, const float* __restrict__ ad2,
        float* __restrict__ wa1, float* __restrict__ wd1,
        float* __restrict__ wa2, float* __restrict__ wd2,
        __half* __restrict__ w2t,
        const int* __restrict__ dst, int* __restrict__ bhist,
        int NB, int nbl, int E, int nInit) {
    if ((int)blockIdx.x >= nInit) {
        // ---- bucket_hist part ----
        __shared__ int lh[256];
        int bid = blockIdx.x - nInit;
        int tid = threadIdx.x;
        lh[tid] = 0;
        __syncthreads();
        int base = bid * EPB;
        int lim = E - base; if (lim > EPB) lim = EPB;
        for (int k = tid; k < lim; k += 256)
            atomicAdd(&lh[(unsigned)dst[base + k] >> 8], 1);
        __syncthreads();
        if (tid < NB) bhist[(size_t)tid * nbl + bid] = lh[tid];   // bin-major
        return;
    }
    // ---- init part ----
    int bid = blockIdx.x;
    int i = bid * 256 + threadIdx.x;
    if (i < G * 128) sums[i] = 0.f;
    if (i < G) cnts[i] = 0.f;
    if (bid == 1) {
        // W2T[c2][k] = W2[h=c2&1][k][o=c2>>1], fp16, [256][64]
        for (int idx = threadIdx.x; idx < 16384; idx += 256) {
            int c2 = idx >> 6, k = idx & 63;
            w2t[idx] = __float2half(W2[(c2 & 1) * 8192 + k * 128 + (c2 >> 1)]);
        }
    }
    if (bid == nInit - 1) {
        int t = threadIdx.x;
        {   // layer1: idx = t>>2 (0..63), part = t&3 covers 16 of 64 elems
            int idx = t >> 2, part = t & 3;
            int h = idx >> 5, c = idx & 31;
            const float* w = W1 + (h * 32 + c) * 64;
            float sa = 0.f, sd = 0.f;
            #pragma unroll
            for (int o = part * 16; o < part * 16 + 16; ++o) {
                sa = fmaf(w[o], as1[h * 64 + o], sa);
                sd = fmaf(w[o], ad1[h * 64 + o], sd);
            }
            sa += __shfl_xor(sa, 1, 64); sa += __shfl_xor(sa, 2, 64);
            sd += __shfl_xor(sd, 1, 64); sd += __shfl_xor(sd, 2, 64);
            if (part == 0) { wa1[idx] = sa; wd1[idx] = sd; }
        }
        {   // layer2: idx = t>>1 (0..127), part = t&1 covers 64 of 128 elems
            int idx = t >> 1, part = t & 1;
            int h = idx >> 6, c = idx & 63;
            const float* w = W2 + (h * 64 + c) * 128;
            float sa = 0.f, sd = 0.f;
            for (int o = part * 64; o < part * 64 + 64; ++o) {
                sa = fmaf(w[o], as2[h * 128 + o], sa);
                sd = fmaf(w[o], ad2[h * 128 + o], sd);
            }
            sa += __shfl_xor(sa, 1, 64);
            sd += __shfl_xor(sd, 1, 64);
            if (part == 0) { wa2[idx] = sa; wd2[idx] = sd; }
        }
    }
}

// ---------------- K2: bucket scatter (with inline redundant scan) co-launched with fused_t1 ----------------
// Scatter blocks come FIRST in the grid (critical path for pass D).
__global__ __launch_bounds__(256) void t1_scatter(
        // scatter args
        const int* __restrict__ srcI, const int* __restrict__ dstI,
        const int* __restrict__ bhist, int* __restrict__ bstart, int* __restrict__ ofsN,
        uint2* __restrict__ ebuf, int NB, int nbl, int E,
        // t1 args
        const float* __restrict__ x, const float* __restrict__ w0,
        const float* __restrict__ b0, const float* __restrict__ W1,
        const float* __restrict__ wa1, const float* __restrict__ wd1,
        unsigned char* __restrict__ h1, float* __restrict__ es, float* __restrict__ ed, int N) {
    if ((int)blockIdx.x < nbl) {
        // ---- scatter part: per-block redundant scan of bhist, then LDS-cursor scatter ----
        __shared__ int lbase[256];
        __shared__ int wtot4[4];
        int j = blockIdx.x;
        int tid = threadIdx.x, lane = tid & 63, wid = tid >> 6;
        int rowsum = 0, pref = 0;
        if (tid < NB) {
            const int* p = bhist + (size_t)tid * nbl;
            for (int k = 0; k < nbl; ++k) {
                int v = p[k];
                rowsum += v;
                pref += (k < j) ? v : 0;
            }
        }
        // exclusive scan over 256 bins of rowsum
        int incl = rowsum;
        #pragma unroll
        for (int off = 1; off < 64; off <<= 1) {
            int t = __shfl_up(incl, off, 64);
            if (lane >= off) incl += t;
        }
        if (lane == 63) wtot4[wid] = incl;
        __syncthreads();
        int woff = 0;
        #pragma unroll
        for (int w = 0; w < 4; ++w) if (w < wid) woff += wtot4[w];
        int excl = incl - rowsum + woff;
        if (j == 0) {
            if (tid < NB) bstart[tid] = excl;
            if (tid == 0) { bstart[NB] = E; *ofsN = E; }
        }
        lbase[tid] = excl + pref;
        __syncthreads();
        int base = j * EPB;
        int lim = E - base; if (lim > EPB) lim = EPB;
        for (int k = tid; k < lim; k += 256) {
            int d = dstI[base + k];
            int s = srcI[base + k];
            int pos = atomicAdd(&lbase[(unsigned)d >> 8], 1);
            ebuf[pos] = make_uint2((unsigned)s, (unsigned)d);
        }
        return;
    }
    // ---- fused_t1 part: fc0 + GAT layer1 transform (8 nodes/block; W1 in LDS; h1 -> fp8) ----
    __shared__ float xs[8 * 16];
    __shared__ float hs[8 * 32];
    __shared__ float ws[4096];       // W1 (2*32*64 floats = 16KB)
    __shared__ float hs2[8 * 128];   // h1 staging for fp8 pack
    int n0 = (blockIdx.x - nbl) * 8;
    int tid = threadIdx.x;
    {   // stage W1 once per block (coalesced float4)
        const float4* wv4 = reinterpret_cast<const float4*>(W1);
        float4* ws4 = reinterpret_cast<float4*>(ws);
        #pragma unroll
        for (int i = 0; i < 4; ++i) ws4[tid + i * 256] = wv4[tid + i * 256];
    }
    if (tid < 128) {
        int gi = n0 * 16 + tid;
        xs[tid] = (gi < N * 16) ? x[gi] : 0.f;
    }
    __syncthreads();
    {
        int j = tid >> 5, o = tid & 31;
        float acc = b0[o];
        #pragma unroll
        for (int c = 0; c < 16; ++c) acc = fmaf(xs[j * 16 + c], w0[c * 32 + o], acc);
        hs[j * 32 + o] = elu_f(acc);
    }
    __syncthreads();
    int o = tid & 63, h = (tid >> 6) & 1, nh = tid >> 7;
    float acc[4];
    #pragma unroll
    for (int j = 0; j < 4; ++j) acc[j] = 0.f;
    const float* wp = ws + h * 2048 + o;
    #pragma unroll
    for (int c = 0; c < 32; ++c) {
        float wv = wp[c * 64];
        #pragma unroll
        for (int j = 0; j < 4; ++j) acc[j] = fmaf(hs[(nh * 4 + j) * 32 + c], wv, acc[j]);
    }
    #pragma unroll
    for (int j = 0; j < 4; ++j)
        hs2[(nh * 4 + j) * 128 + 2 * o + h] = acc[j];
    if (tid < 32) {
        int n = tid >> 2, r = tid & 3, hh = r >> 1, isd = r & 1;
        const float* wv = (isd ? wd1 : wa1) + hh * 32;
        float s = 0.f;
        #pragma unroll
        for (int c = 0; c < 32; ++c) s = fmaf(hs[n * 32 + c], wv[c], s);
        int nn = n0 + n;
        if (nn < N) { if (isd) ed[nn * 2 + hh] = s; else es[nn * 2 + hh] = s; }
    }
    __syncthreads();
    if (tid < 128) {   // pack 8 nodes x 128 ch to fp8, coalesced uint2 stores
        int nloc = tid >> 4, cg = tid & 15;
        int n = n0 + nloc;
        if (n < N) {
            const float* p = hs2 + nloc * 128 + cg * 8;
            uint2 pk;
            pk.x = pack_fp8x4(p[0], p[1], p[2], p[3]);
            pk.y = pack_fp8x4(p[4], p[5], p[6], p[7]);
            *reinterpret_cast<uint2*>(h1 + (size_t)n * 128 + cg * 8) = pk;
        }
    }
}

// ---------------- pass D: one block per bucket -> fine hist, scan (ofs), LDS-cursor scatter (sperm), cnts ----------------
__global__ __launch_bounds__(256) void bucket_csr(
        const uint2* __restrict__ ebuf, const int* __restrict__ bstart,
        const int* __restrict__ batch, float* __restrict__ cnts,
        int* __restrict__ ofs, int* __restrict__ sperm, int N) {
    __shared__ int fh[256];
    __shared__ int wtot[4];
    __shared__ int lc[256];
    int bin = blockIdx.x;
    int tid = threadIdx.x, lane = tid & 63, wid = tid >> 6;
    int ebeg = bstart[bin], eend = bstart[bin + 1];
    fh[tid] = 0;
    __syncthreads();
    for (int i = ebeg + tid; i < eend; i += 256)
        atomicAdd(&fh[ebuf[i].y & 255], 1);
    __syncthreads();
    // exclusive scan of fh (256 values, 4 waves)
    int v = fh[tid];
    int incl = v;
    #pragma unroll
    for (int off = 1; off < 64; off <<= 1) {
        int t = __shfl_up(incl, off, 64);
        if (lane >= off) incl += t;
    }
    if (lane == 63) wtot[wid] = incl;
    __syncthreads();
    int woff = 0;
    #pragma unroll
    for (int w = 0; w < 4; ++w) if (w < wid) woff += wtot[w];
    int excl = incl - v + woff;
    int d = (bin << 8) + tid;
    if (d < N) ofs[d] = ebeg + excl;
    lc[tid] = excl;
    // graph node-counts (batch sorted; ballot trick, contiguous node range)
    if (d < N) {
        int b = batch[d];
        int b0 = __shfl(b, 0, 64);
        if (__all(b == b0)) {
            unsigned long long m = __ballot(1);
            if (lane == 0) atomicAdd(&cnts[b], (float)__popcll(m));
        } else {
            atomicAdd(&cnts[b], 1.f);
        }
    }
    __syncthreads();
    for (int i = ebeg + tid; i < eend; i += 256) {
        uint2 e = ebuf[i];
        int pos = atomicAdd(&lc[e.y & 255], 1);
        sperm[ebeg + pos] = (int)e.x;
    }
}

// ---------------- GAT layer2 transform: MFMA GEMM [N x 64] @ [64 x 256], fp8 output ----------------
// Output h8[node][pos] fp8, PERMUTED: pos = r*16+nf holds channel col = nf*16+r.
__global__ __launch_bounds__(256) void t2_mfma(
        const __half* __restrict__ g1h,   // [Npad][64] fp16
        const __half* __restrict__ w2t,   // [256][64] fp16
        unsigned char* __restrict__ h8, int N) {
    __shared__ __half sbuf[16384];   // 32KB: B operand, XOR-swizzled
    int tid = threadIdx.x;
    {   // stage B: 2048 uint4, XOR-swizzled (row = 128B = 8 uint4)
        const uint4* srcv = reinterpret_cast<const uint4*>(w2t);
        #pragma unroll
        for (int i = 0; i < 8; ++i) {
            int idx = tid + i * 256;
            int row = idx >> 3;
            int byteoff = (idx * 16) ^ ((row & 7) << 4);
            *reinterpret_cast<uint4*>(reinterpret_cast<char*>(sbuf) + byteoff) = srcv[idx];
        }
    }
    __syncthreads();
    int w = tid >> 6, lane = tid & 63;
    int r = lane & 15, kg = lane >> 4;
    int nodei = blockIdx.x * 64 + w * 16 + r;
    const half8* ap = reinterpret_cast<const half8*>(
        reinterpret_cast<const _Float16*>(g1h) + (size_t)nodei * 64 + kg * 8);

    f32x4 acc[16];
    #pragma unroll
    for (int nf = 0; nf < 16; ++nf) acc[nf] = f32x4{0.f, 0.f, 0.f, 0.f};
    half8 az = {};
    #pragma unroll
    for (int ks = 0; ks < 2; ++ks) {
        half8 a = (nodei < N) ? ap[ks * 4] : az;
        #pragma unroll
        for (int nf = 0; nf < 16; ++nf) {
            int brow = nf * 16 + r;
            int bbyte = (brow * 128 + ks * 64 + kg * 16) ^ ((brow & 7) << 4);
            half8 b = *reinterpret_cast<const half8*>(reinterpret_cast<const char*>(sbuf) + bbyte);
            acc[nf] = __builtin_amdgcn_mfma_f32_16x16x32_f16(a, b, acc[nf], 0, 0, 0);
        }
    }
    #pragma unroll
    for (int q = 0; q < 4; ++q) {
        int n = blockIdx.x * 64 + w * 16 + kg * 4 + q;
        if (n < N) {
            uint4 pk;
            pk.x = pack_fp8x4(acc[0][q],  acc[1][q],  acc[2][q],  acc[3][q]);
            pk.y = pack_fp8x4(acc[4][q],  acc[5][q],  acc[6][q],  acc[7][q]);
            pk.z = pack_fp8x4(acc[8][q],  acc[9][q],  acc[10][q], acc[11][q]);
            pk.w = pack_fp8x4(acc[12][q], acc[13][q], acc[14][q], acc[15][q]);
            *reinterpret_cast<uint4*>(h8 + (size_t)n * 256 + r * 16) = pk;
        }
    }
}

// ---------------- aggregation layer1: one QUARTER-WAVE (16 lanes) per dst node, fp8 uint2 loads ----------------
__global__ __launch_bounds__(256) void gat_agg1(
        const int* __restrict__ ofs, const int* __restrict__ sperm,
        const float* __restrict__ es, const float* __restrict__ ed,
        const uint2* __restrict__ h1v, const float* __restrict__ b1,
        const float* __restrict__ wa2, const float* __restrict__ wd2,
        uint2* __restrict__ g1h, float* __restrict__ es2, float* __restrict__ ed2, int N) {
    __shared__ uint2 meta[16][32];
    int q = threadIdx.x >> 4;            // 0..15
    int d = blockIdx.x * 16 + q;
    int lane = threadIdx.x & 15;
    bool active = d < N;                 // uniform per quarter
    if (!active) return;                 // no block-wide barrier in this kernel
    float2 edv = *reinterpret_cast<const float2*>(ed + (size_t)d * 2);
    int beg = ofs[d], end = ofs[d + 1];
    int deg = end - beg;
    int jmax = deg < 32 ? deg : 32;

    int s0i = 0, s1i = 0;
    float ex00 = 0.f, ex01 = 0.f, ex10 = 0.f, ex11 = 0.f;
    int i0 = beg + lane, i1 = beg + lane + 16;
    if (i0 < end) {
        s0i = sperm[i0];
        float2 e = *reinterpret_cast<const float2*>(es + (size_t)s0i * 2);
        ex00 = __expf(lrelu_f(e.x + edv.x));
        ex01 = __expf(lrelu_f(e.y + edv.y));
    }
    if (i1 < end) {
        s1i = sperm[i1];
        float2 e = *reinterpret_cast<const float2*>(es + (size_t)s1i * 2);
        ex10 = __expf(lrelu_f(e.x + edv.x));
        ex11 = __expf(lrelu_f(e.y + edv.y));
    }
    float s0 = ex00 + ex10, s1 = ex01 + ex11;
    for (int i = i0 + 32; i < end; i += 16) {   // rare: deg > 32
        int s = sperm[i];
        float2 e = *reinterpret_cast<const float2*>(es + (size_t)s * 2);
        s0 += __expf(lrelu_f(e.x + edv.x));
        s1 += __expf(lrelu_f(e.y + edv.y));
    }
    s0 = quarterReduceSum(s0);
    s1 = quarterReduceSum(s1);
    float r0 = 0.5f / (s0 + GAT_EPS), r1 = 0.5f / (s1 + GAT_EPS);
    if (lane < jmax)
        meta[q][lane] = make_uint2((unsigned int)s0i, pack_half2(ex00 * r0, ex01 * r1));
    if (lane + 16 < jmax)
        meta[q][lane + 16] = make_uint2((unsigned int)s1i, pack_half2(ex10 * r0, ex11 * r1));

    // lane covers output channels 4*lane .. 4*lane+3; per-channel head pair packed-accumulated
    f32x2 c0{0.f, 0.f}, c1{0.f, 0.f}, c2{0.f, 0.f}, c3{0.f, 0.f};
    int j = 0;
    for (; j + 8 <= jmax; j += 8) {
        uint2 vv[8];
        #pragma unroll
        for (int k = 0; k < 8; ++k) vv[k] = h1v[(size_t)meta[q][j + k].x * 16 + lane];
        #pragma unroll
        for (int k = 0; k < 8; ++k) {
            float2 af = __half22float2(__builtin_bit_cast(__half2, meta[q][j + k].y));
            acc8_pk(vv[k], f32x2{af.x, af.y}, c0, c1, c2, c3);
        }
    }
    for (; j + 4 <= jmax; j += 4) {
        uint2 vv[4];
        #pragma unroll
        for (int k = 0; k < 4; ++k) vv[k] = h1v[(size_t)meta[q][j + k].x * 16 + lane];
        #pragma unroll
        for (int k = 0; k < 4; ++k) {
            float2 af = __half22float2(__builtin_bit_cast(__half2, meta[q][j + k].y));
            acc8_pk(vv[k], f32x2{af.x, af.y}, c0, c1, c2, c3);
        }
    }
    for (; j < jmax; ++j) {
        uint2 m = meta[q][j];
        float2 af = __half22float2(__builtin_bit_cast(__half2, m.y));
        acc8_pk(h1v[(size_t)m.x * 16 + lane], f32x2{af.x, af.y}, c0, c1, c2, c3);
    }
    for (int i = beg + 32; i < end; ++i) {      // rare: deg > 32
        int s = sperm[i];
        float2 e = *reinterpret_cast<const float2*>(es + (size_t)s * 2);
        float w0 = __expf(lrelu_f(e.x + edv.x)) * r0;
        float w1 = __expf(lrelu_f(e.y + edv.y)) * r1;
        acc8_pk(h1v[(size_t)s * 16 + lane], f32x2{w0, w1}, c0, c1, c2, c3);
    }
    float a0 = c0[0] + c0[1], a1 = c1[0] + c1[1];
    float a2 = c2[0] + c2[1], a3 = c3[0] + c3[1];
    float4 bv = reinterpret_cast<const float4*>(b1)[lane];
    float o0 = elu_f(a0 + bv.x);
    float o1 = elu_f(a1 + bv.y);
    float o2 = elu_f(a2 + bv.z);
    float o3 = elu_f(a3 + bv.w);
    g1h[(size_t)d * 16 + lane] = make_uint2(pack_half2(o0, o1), pack_half2(o2, o3));
    float4 wa0 = reinterpret_cast<const float4*>(wa2)[lane];
    float4 wa1v = reinterpret_cast<const float4*>(wa2)[16 + lane];
    float4 wd0 = reinterpret_cast<const float4*>(wd2)[lane];
    float4 wd1v = reinterpret_cast<const float4*>(wd2)[16 + lane];
    float p0 = o0 * wa0.x + o1 * wa0.y + o2 * wa0.z + o3 * wa0.w;
    float p1 = o0 * wa1v.x + o1 * wa1v.y + o2 * wa1v.z + o3 * wa1v.w;
    float q0 = o0 * wd0.x + o1 * wd0.y + o2 * wd0.z + o3 * wd0.w;
    float q1 = o0 * wd1v.x + o1 * wd1v.y + o2 * wd1v.z + o3 * wd1v.w;
    p0 = quarterReduceSum(p0);
    p1 = quarterReduceSum(p1);
    q0 = quarterReduceSum(q0);
    q1 = quarterReduceSum(q1);
    if (lane == 0) {
        es2[(size_t)d * 2]     = p0;
        es2[(size_t)d * 2 + 1] = p1;
        ed2[(size_t)d * 2]     = q0;
        ed2[(size_t)d * 2 + 1] = q1;
    }
}

// ---------------- aggregation layer2 (fp8 h2, permuted rows) + fused block-level pool ----------------
__global__ __launch_bounds__(256) void gat_agg2(
        const int* __restrict__ ofs, const int* __restrict__ sperm,
        const float* __restrict__ es, const float* __restrict__ ed,
        const uint2* __restrict__ h8v, const float* __restrict__ b2,
        const int* __restrict__ batch, float* __restrict__ sums, int N) {
    __shared__ uint2 meta[8][32];
    __shared__ float louts[8 * 128];
    __shared__ int lbat[8];
    int half = threadIdx.x >> 5;
    int d = blockIdx.x * 8 + half;
    int lane = threadIdx.x & 31;
    bool active = d < N;                 // uniform per half; NO early return (barrier below)
    int beg = 0, end = 0;
    if (active) {
        beg = ofs[d]; end = ofs[d + 1];
        if (lane == 0) lbat[half] = batch[d];
    } else if (lane == 0) {
        lbat[half] = -1;
    }
    float2 edv = active ? *reinterpret_cast<const float2*>(ed + (size_t)d * 2)
                        : make_float2(0.f, 0.f);
    int deg = end - beg;
    int jmax = deg < 32 ? deg : 32;

    int s_f = 0;
    float ex0 = 0.f, ex1 = 0.f;
    int i0 = beg + lane;
    if (i0 < end) {
        s_f = sperm[i0];
        float2 esv = *reinterpret_cast<const float2*>(es + (size_t)s_f * 2);
        ex0 = __expf(lrelu_f(esv.x + edv.x));
        ex1 = __expf(lrelu_f(esv.y + edv.y));
    }
    float s0 = ex0, s1 = ex1;
    for (int i = i0 + 32; i < end; i += 32) {  // rare: deg > 32
        int s = sperm[i];
        float2 esv = *reinterpret_cast<const float2*>(es + (size_t)s * 2);
        s0 += __expf(lrelu_f(esv.x + edv.x));
        s1 += __expf(lrelu_f(esv.y + edv.y));
    }
    s0 = halfReduceSum(s0);
    s1 = halfReduceSum(s1);
    float r0 = 0.5f / (s0 + GAT_EPS), r1 = 0.5f / (s1 + GAT_EPS);
    if (lane < jmax)
        meta[half][lane] = make_uint2((unsigned int)s_f, pack_half2(ex0 * r0, ex1 * r1));

    int head = (lane >> 1) & 1;          // fixed per lane under the permuted layout
    f32x2 c0{0.f, 0.f}, c1{0.f, 0.f}, c2{0.f, 0.f}, c3{0.f, 0.f};

    int j = 0;
    for (; j + 8 <= jmax; j += 8) {
        uint2 vv[8];
        #pragma unroll
        for (int k = 0; k < 8; ++k) vv[k] = h8v[(size_t)meta[half][j + k].x * 32 + lane];
        #pragma unroll
        for (int k = 0; k < 8; ++k) {
            float2 af = __half22float2(__builtin_bit_cast(__half2, meta[half][j + k].y));
            float av = head ? af.y : af.x;
            acc8_pk(vv[k], f32x2{av, av}, c0, c1, c2, c3);
        }
    }
    for (; j < jmax; ++j) {
        uint2 v = h8v[(size_t)meta[half][j].x * 32 + lane];
        float2 af = __half22float2(__builtin_bit_cast(__half2, meta[half][j].y));
        float av = head ? af.y : af.x;
        acc8_pk(v, f32x2{av, av}, c0, c1, c2, c3);
    }
    for (int i = beg + 32; i < end; ++i) {  // rare: deg > 32
        int s = sperm[i];
        float2 esv = *reinterpret_cast<const float2*>(es + (size_t)s * 2);
        float a0 = __expf(lrelu_f(esv.x + edv.x)) * r0;
        float a1 = __expf(lrelu_f(esv.y + edv.y)) * r1;
        float av = head ? a1 : a0;
        acc8_pk(h8v[(size_t)s * 32 + lane], f32x2{av, av}, c0, c1, c2, c3);
    }
    float acc[8] = { c0[0], c0[1], c1[0], c1[1], c2[0], c2[1], c3[0], c3[1] };
    // head-combine: lane^2 holds the other head of the same o-channels
    #pragma unroll
    for (int i = 0; i < 8; ++i) acc[i] += __shfl_xor(acc[i], 2, 64);
    if (head == 0) {
        int jch = lane >> 2;             // 0..7
        int nfb = (lane & 1) * 8;
        #pragma unroll
        for (int i = 0; i < 8; ++i) {
            int o = (nfb + i) * 8 + jch;
            louts[half * 128 + o] = active ? elu_f(acc[i] + b2[o]) : 0.f;
        }
    }
    __syncthreads();
    // run-length merge of the block's 8 nodes (batch sorted -> 1-2 runs/block)
    if (threadIdx.x < 128) {
        int c = threadIdx.x;
        int cur = lbat[0];
        float a = 0.f;
        #pragma unroll
        for (int n = 0; n < 8; ++n) {
            int b = lbat[n];
            if (b != cur) {
                if (cur >= 0) atomicAdd(&sums[(size_t)cur * 128 + c], a);
                a = 0.f; cur = b;
            }
            a += louts[n * 128 + c];
        }
        if (cur >= 0) atomicAdd(&sums[(size_t)cur * 128 + c], a);
    }
}

// ---------------- final: out = (sums/cnt) @ lo_w + lo_b ----------------
__global__ void final_kernel(
        const float* __restrict__ sums, const float* __restrict__ cnts,
        const float* __restrict__ w, const float* __restrict__ b,
        float* __restrict__ out, int G) {
    int g = blockIdx.x;
    int k = threadIdx.x;
    if (k >= 24) return;
    float inv = 1.f / fmaxf(cnts[g], 1.f);
    float acc = b[k];
    #pragma unroll
    for (int c = 0; c < 128; ++c) acc = fmaf(sums[g * 128 + c] * inv, w[c * 24 + k], acc);
    out[g * 24 + k] = acc;
}

extern "C" void kernel_launch(void* const* d_in, const int* in_sizes, int n_in,
                              void* d_out, int out_size, void* d_ws, size_t ws_size,
                              hipStream_t stream) {
    const float* x      = (const float*)d_in[0];
    const int*   ei     = (const int*)d_in[1];
    const int*   batch  = (const int*)d_in[2];
    const float* fc0_w  = (const float*)d_in[3];
    const float* fc0_b  = (const float*)d_in[4];
    const float* W1     = (const float*)d_in[5];
    const float* a_src1 = (const float*)d_in[6];
    const float* a_dst1 = (const float*)d_in[7];
    const float* b1     = (const float*)d_in[8];
    const float* W2     = (const float*)d_in[9];
    const float* a_src2 = (const float*)d_in[10];
    const float* a_dst2 = (const float*)d_in[11];
    const float* b2     = (const float*)d_in[12];
    const float* lo_w   = (const float*)d_in[13];
    const float* lo_b   = (const float*)d_in[14];
    float* out = (float*)d_out;

    const int N = in_sizes[0] / 16;
    const int E = in_sizes[1] / 2;
    const int G = out_size / 24;
    const int* src = ei;
    const int* dst = ei + E;
    const int NB  = (N + 255) >> 8;            // coarse buckets (<= 256 for N <= 65536)
    const int nbl = (E + EPB - 1) / EPB;       // bucket-pass blocks
    const int nInit = (N + 255) / 256;
    const int nT1 = (N + 7) / 8;

    char* wsb = (char*)d_ws;
    size_t off = 0;
    auto allocf = [&](size_t n) { float* p = (float*)(wsb + off); off += ((n * 4 + 255) & ~(size_t)255); return p; };
    auto alloci = [&](size_t n) { int* p = (int*)(wsb + off); off += ((n * 4 + 255) & ~(size_t)255); return p; };
    auto alloch = [&](size_t n) { __half* p = (__half*)(wsb + off); off += ((n * 2 + 255) & ~(size_t)255); return p; };
    __half* hbuf  = alloch((size_t)N * 256);        // h1 (fp8): first N*128 B; h8 (fp8): first N*256 B
    __half* g1h   = alloch((size_t)(N + 64) * 64);  // fp16 g1 (padded for 64-node GEMM blocks)
    __half* w2t   = alloch(16384);                  // W2 transposed [256][64] fp16
    float*  es    = allocf((size_t)N * 2);
    float*  ed    = allocf((size_t)N * 2);
    float*  es2   = allocf((size_t)N * 2);
    float*  ed2   = allocf((size_t)N * 2);
    float*  sums  = allocf((size_t)G * 128);
    float*  cnts  = allocf((size_t)G);
    float*  wa1   = allocf(64);
    float*  wd1   = allocf(64);
    float*  wa2   = allocf(128);
    float*  wd2   = allocf(128);
    int* ofs     = alloci((size_t)N + 1);
    int* sperm   = alloci((size_t)E);
    int* bhist   = alloci((size_t)NB * nbl);
    int* bstart  = alloci((size_t)NB + 1);
    uint2* ebuf  = (uint2*)alloci((size_t)E * 2);
    (void)ws_size;

    // K1: init (zero sums/cnts, W2T, attn folds) || coarse histogram
    init_hist<<<nInit + nbl, 256, 0, stream>>>(sums, cnts, N, G,
            W1, a_src1, a_dst1, W2, a_src2, a_dst2, wa1, wd1, wa2, wd2, w2t,
            dst, bhist, NB, nbl, E, nInit);
    // K2: bucket scatter (inline scan) || fused fc0+layer1 transform
    t1_scatter<<<nbl + nT1, 256, 0, stream>>>(
            src, dst, bhist, bstart, ofs + N, ebuf, NB, nbl, E,
            x, fc0_w, fc0_b, W1, wa1, wd1, (unsigned char*)hbuf, es, ed, N);
    // K3: per-bucket fine CSR (ofs, sperm, cnts)
    bucket_csr<<<NB, 256, 0, stream>>>(ebuf, bstart, batch, cnts, ofs, sperm, N);

    // K4: GAT layer 1 aggregation (fp8 h1; layer-2 attn scalars fused)
    gat_agg1<<<(N + 15) / 16, 256, 0, stream>>>(ofs, sperm, es, ed, (const uint2*)hbuf, b1,
            wa2, wd2, (uint2*)g1h, es2, ed2, N);
    // K5: GAT layer 2 MFMA transform -> fp8 permuted h2
    t2_mfma<<<(N + 63) / 64, 256, 0, stream>>>(g1h, w2t, (unsigned char*)hbuf, N);
    // K6: GAT layer 2 aggregation + fused pool
    gat_agg2<<<(N + 7) / 8, 256, 0, stream>>>(ofs, sperm, es2, ed2, (const uint2*)hbuf, b2,
            batch, sums, N);
    // K7: final linear
    final_kernel<<<G, 32, 0, stream>>>(sums, cnts, lo_w, lo_b, out, G);
}